// Round 5
// baseline (1682.181 us; speedup 1.0000x reference)
//
#include <hip/hip_runtime.h>
#include <math.h>

#define TT 2048   // tokens
#define NP 2048   // num params (N)
#define BB 8      // batch
#define DD 512    // d_model = kdim = vdim

#define LOG_A (-7.6246189861593985f)  // -log(2048)

// ---------------------------------------------------------------------------
// Generic NN GEMM: C[M,N] = A[M,K] @ B[K,N], all fp32 row-major.
// 128x128 tile, BK=16, 256 threads, 8x8 micro-tile.
// ---------------------------------------------------------------------------
__global__ __launch_bounds__(256) void gemm_nn(
    const float* __restrict__ A, const float* __restrict__ B,
    float* __restrict__ C, int M, int N, int K)
{
    __shared__ float As[16][132];
    __shared__ float Bs[16][132];
    const int tid = threadIdx.x;
    const int tx = tid & 15;
    const int ty = tid >> 4;
    const int row0 = blockIdx.y * 128;
    const int col0 = blockIdx.x * 128;
    float acc[8][8] = {};

    for (int k0 = 0; k0 < K; k0 += 16) {
        #pragma unroll
        for (int i = tid; i < 512; i += 256) {
            int r = i >> 2;
            int c = (i & 3) << 2;
            float4 av = *reinterpret_cast<const float4*>(
                &A[(size_t)(row0 + r) * K + k0 + c]);
            As[c + 0][r] = av.x; As[c + 1][r] = av.y;
            As[c + 2][r] = av.z; As[c + 3][r] = av.w;
        }
        #pragma unroll
        for (int i = tid; i < 512; i += 256) {
            int r = i >> 5;
            int c = (i & 31) << 2;
            *reinterpret_cast<float4*>(&Bs[r][c]) =
                *reinterpret_cast<const float4*>(&B[(size_t)(k0 + r) * N + col0 + c]);
        }
        __syncthreads();
        #pragma unroll
        for (int kk = 0; kk < 16; ++kk) {
            float a[8], bf[8];
            #pragma unroll
            for (int i = 0; i < 8; ++i) a[i] = As[kk][ty * 8 + i];
            #pragma unroll
            for (int j = 0; j < 8; ++j) bf[j] = Bs[kk][tx * 8 + j];
            #pragma unroll
            for (int i = 0; i < 8; ++i)
                #pragma unroll
                for (int j = 0; j < 8; ++j)
                    acc[i][j] = fmaf(a[i], bf[j], acc[i][j]);
        }
        __syncthreads();
    }
    #pragma unroll
    for (int i = 0; i < 8; ++i) {
        float* crow = &C[(size_t)(row0 + ty * 8 + i) * N + col0 + tx * 8];
        *reinterpret_cast<float4*>(crow) =
            make_float4(acc[i][0], acc[i][1], acc[i][2], acc[i][3]);
        *reinterpret_cast<float4*>(crow + 4) =
            make_float4(acc[i][4], acc[i][5], acc[i][6], acc[i][7]);
    }
}

// ---------------------------------------------------------------------------
// Row squared-norm: out[r] = sum_d X[r][d]^2. One wave (64 lanes) per row.
// ---------------------------------------------------------------------------
__global__ __launch_bounds__(256) void rownorm(
    const float* __restrict__ X, float* __restrict__ o, int rows)
{
    int w = blockIdx.x * 4 + (threadIdx.x >> 6);
    int lane = threadIdx.x & 63;
    if (w >= rows) return;
    const float* xr = X + (size_t)w * DD;
    float s = 0.f;
    #pragma unroll
    for (int i = lane; i < DD; i += 64) { float x = xr[i]; s = fmaf(x, x, s); }
    #pragma unroll
    for (int off = 32; off; off >>= 1) s += __shfl_down(s, off, 64);
    if (lane == 0) o[w] = s;
}

// ---------------------------------------------------------------------------
// NT GEMM + cost epilogue:
//   S[t,n] = dot(QP[t,:], KP[b,n,:])
//   Kmat[b,t,n] = -sqrt(max(q2[t] + k2[b,n] - 2 S, 0))
// ---------------------------------------------------------------------------
__global__ __launch_bounds__(256) void gemm_nt_cost(
    const float* __restrict__ QP, const float* __restrict__ KP,
    const float* __restrict__ q2, const float* __restrict__ k2,
    float* __restrict__ Kmat)
{
    const int b = blockIdx.z;
    const float* Bb  = KP + (size_t)b * NP * DD;
    const float* k2b = k2 + (size_t)b * NP;
    float* Kb = Kmat + (size_t)b * TT * NP;

    __shared__ float As[16][132];
    __shared__ float Bs[16][132];
    const int tid = threadIdx.x;
    const int tx = tid & 15;
    const int ty = tid >> 4;
    const int row0 = blockIdx.y * 128;   // t tile
    const int col0 = blockIdx.x * 128;   // n tile
    float acc[8][8] = {};

    for (int k0 = 0; k0 < DD; k0 += 16) {
        #pragma unroll
        for (int i = tid; i < 512; i += 256) {
            int r = i >> 2;
            int c = (i & 3) << 2;
            float4 av = *reinterpret_cast<const float4*>(
                &QP[(size_t)(row0 + r) * DD + k0 + c]);
            As[c + 0][r] = av.x; As[c + 1][r] = av.y;
            As[c + 2][r] = av.z; As[c + 3][r] = av.w;
        }
        #pragma unroll
        for (int i = tid; i < 512; i += 256) {
            int r = i >> 2;
            int c = (i & 3) << 2;
            float4 bv = *reinterpret_cast<const float4*>(
                &Bb[(size_t)(col0 + r) * DD + k0 + c]);
            Bs[c + 0][r] = bv.x; Bs[c + 1][r] = bv.y;
            Bs[c + 2][r] = bv.z; Bs[c + 3][r] = bv.w;
        }
        __syncthreads();
        #pragma unroll
        for (int kk = 0; kk < 16; ++kk) {
            float a[8], bf[8];
            #pragma unroll
            for (int i = 0; i < 8; ++i) a[i] = As[kk][ty * 8 + i];
            #pragma unroll
            for (int j = 0; j < 8; ++j) bf[j] = Bs[kk][tx * 8 + j];
            #pragma unroll
            for (int i = 0; i < 8; ++i)
                #pragma unroll
                for (int j = 0; j < 8; ++j)
                    acc[i][j] = fmaf(a[i], bf[j], acc[i][j]);
        }
        __syncthreads();
    }
    #pragma unroll
    for (int i = 0; i < 8; ++i) {
        int r = row0 + ty * 8 + i;
        float qq = q2[r];
        float tmp[8];
        #pragma unroll
        for (int j = 0; j < 8; ++j) {
            int cc = col0 + tx * 8 + j;
            float sq = qq + k2b[cc] - 2.f * acc[i][j];
            tmp[j] = -sqrtf(fmaxf(sq, 0.f));
        }
        float* orow = &Kb[(size_t)r * NP + col0 + tx * 8];
        *reinterpret_cast<float4*>(orow)     = make_float4(tmp[0], tmp[1], tmp[2], tmp[3]);
        *reinterpret_cast<float4*>(orow + 4) = make_float4(tmp[4], tmp[5], tmp[6], tmp[7]);
    }
}

// ---------------------------------------------------------------------------
// u update: u[b,n] = LOG_A - LSE_t( Kmat[b,t,n] + v[b,t] )
// Block = 256 threads = 64 columns x 4 T-phases (keeps exp chain short).
// Grid: (NP/64, BB).
// ---------------------------------------------------------------------------
__global__ __launch_bounds__(256) void u_update(
    const float* __restrict__ Kmat, const float* __restrict__ vv,
    float* __restrict__ uu)
{
    const int b = blockIdx.y;
    const int c = threadIdx.x & 63;
    const int p = threadIdx.x >> 6;
    const int n = blockIdx.x * 64 + c;
    const float* Kb = Kmat + (size_t)b * TT * NP + n;
    const float* vb = vv + (size_t)b * TT;

    float m = -INFINITY, s = 0.f;
    const int t0 = p * (TT / 4);
    for (int tt = 0; tt < TT / 4; ++tt) {
        int t = t0 + tt;
        float x = Kb[(size_t)t * NP] + vb[t];
        float nm = fmaxf(m, x);
        s = s * __expf(m - nm) + __expf(x - nm);
        m = nm;
    }
    __shared__ float sm[4][64], ss[4][64];
    sm[p][c] = m; ss[p][c] = s;
    __syncthreads();
    if (p == 0) {
        #pragma unroll
        for (int q = 1; q < 4; ++q) {
            float m2 = sm[q][c], s2 = ss[q][c];
            float nm = fmaxf(m, m2);
            s = s * __expf(m - nm) + s2 * __expf(m2 - nm);
            m = nm;
        }
        uu[(size_t)b * NP + n] = LOG_A - (m + __logf(s));
    }
}

// ---------------------------------------------------------------------------
// v update: v[b,t] = -LSE_n( Kmat[b,t,n] + u[b,n] )   (log_b = 0)
// One block (256 threads) per row.
// ---------------------------------------------------------------------------
__global__ __launch_bounds__(256) void v_update(
    const float* __restrict__ Kmat, const float* __restrict__ uu,
    float* __restrict__ vv)
{
    const int b = blockIdx.y;
    const int t = blockIdx.x;
    const float* Kb = Kmat + ((size_t)b * TT + t) * NP;
    const float* ub = uu + (size_t)b * NP;
    const int tid = threadIdx.x;

    float m = -INFINITY, s = 0.f;
    #pragma unroll
    for (int n = tid; n < NP; n += 256) {
        float x = Kb[n] + ub[n];
        float nm = fmaxf(m, x);
        s = s * __expf(m - nm) + __expf(x - nm);
        m = nm;
    }
    __shared__ float sm[256], ss[256];
    sm[tid] = m; ss[tid] = s;
    __syncthreads();
    for (int off = 128; off; off >>= 1) {
        if (tid < off) {
            float m1 = sm[tid], s1 = ss[tid];
            float m2 = sm[tid + off], s2 = ss[tid + off];
            float nm = fmaxf(m1, m2);
            ss[tid] = s1 * __expf(m1 - nm) + s2 * __expf(m2 - nm);
            sm[tid] = nm;
        }
        __syncthreads();
    }
    if (tid == 0) vv[(size_t)b * TT + t] = -(sm[0] + __logf(ss[0]));
}

// ---------------------------------------------------------------------------
// Fused pi @ vp:  out[b,t,d] = sum_n exp(Kmat[b,t,n]+u[b,n]+v[b,t]) * vp[b,n,d]
// NN GEMM, M=TT, N=DD, K=NP; exp applied on A-tile load.
// ---------------------------------------------------------------------------
__global__ __launch_bounds__(256) void gemm_pi(
    const float* __restrict__ Kmat, const float* __restrict__ uu,
    const float* __restrict__ vv, const float* __restrict__ VP,
    float* __restrict__ out)
{
    const int b = blockIdx.z;
    const float* Kb = Kmat + (size_t)b * TT * NP;
    const float* ub = uu + (size_t)b * NP;
    const float* vb = vv + (size_t)b * TT;
    const float* Bb = VP + (size_t)b * NP * DD;
    float* Ob = out + (size_t)b * TT * DD;

    __shared__ float As[16][132];
    __shared__ float Bs[16][132];
    const int tid = threadIdx.x;
    const int tx = tid & 15;
    const int ty = tid >> 4;
    const int row0 = blockIdx.y * 128;   // t tile
    const int col0 = blockIdx.x * 128;   // d tile
    float acc[8][8] = {};

    for (int k0 = 0; k0 < NP; k0 += 16) {
        #pragma unroll
        for (int i = tid; i < 512; i += 256) {
            int r = i >> 2;
            int c = (i & 3) << 2;
            float4 av = *reinterpret_cast<const float4*>(
                &Kb[(size_t)(row0 + r) * NP + k0 + c]);
            float4 uv = *reinterpret_cast<const float4*>(&ub[k0 + c]);
            float vr = vb[row0 + r];
            As[c + 0][r] = __expf(av.x + uv.x + vr);
            As[c + 1][r] = __expf(av.y + uv.y + vr);
            As[c + 2][r] = __expf(av.z + uv.z + vr);
            As[c + 3][r] = __expf(av.w + uv.w + vr);
        }
        #pragma unroll
        for (int i = tid; i < 512; i += 256) {
            int r = i >> 5;
            int c = (i & 31) << 2;
            *reinterpret_cast<float4*>(&Bs[r][c]) =
                *reinterpret_cast<const float4*>(&Bb[(size_t)(k0 + r) * DD + col0 + c]);
        }
        __syncthreads();
        #pragma unroll
        for (int kk = 0; kk < 16; ++kk) {
            float a[8], bf[8];
            #pragma unroll
            for (int i = 0; i < 8; ++i) a[i] = As[kk][ty * 8 + i];
            #pragma unroll
            for (int j = 0; j < 8; ++j) bf[j] = Bs[kk][tx * 8 + j];
            #pragma unroll
            for (int i = 0; i < 8; ++i)
                #pragma unroll
                for (int j = 0; j < 8; ++j)
                    acc[i][j] = fmaf(a[i], bf[j], acc[i][j]);
        }
        __syncthreads();
    }
    #pragma unroll
    for (int i = 0; i < 8; ++i) {
        float* crow = &Ob[(size_t)(row0 + ty * 8 + i) * DD + col0 + tx * 8];
        *reinterpret_cast<float4*>(crow) =
            make_float4(acc[i][0], acc[i][1], acc[i][2], acc[i][3]);
        *reinterpret_cast<float4*>(crow + 4) =
            make_float4(acc[i][4], acc[i][5], acc[i][6], acc[i][7]);
    }
}

// ---------------------------------------------------------------------------
extern "C" void kernel_launch(void* const* d_in, const int* in_sizes, int n_in,
                              void* d_out, int out_size, void* d_ws, size_t ws_size,
                              hipStream_t stream)
{
    const float* q  = (const float*)d_in[0];
    const float* k  = (const float*)d_in[1];
    const float* v  = (const float*)d_in[2];
    const float* Qw = (const float*)d_in[3];
    const float* Kw = (const float*)d_in[4];
    const float* Vw = (const float*)d_in[5];
    float* out = (float*)d_out;

    // Workspace layout (~196.2 MiB total)
    char* p = (char*)d_ws;
    float* qp = (float*)p; p += (size_t)TT * DD * 4;        //   4 MiB
    float* kp = (float*)p; p += (size_t)BB * NP * DD * 4;   //  32 MiB
    float* vp = (float*)p; p += (size_t)BB * NP * DD * 4;   //  32 MiB
    float* q2 = (float*)p; p += (size_t)TT * 4;
    float* k2 = (float*)p; p += (size_t)BB * NP * 4;
    float* uu = (float*)p; p += (size_t)BB * NP * 4;
    float* vv = (float*)p; p += (size_t)BB * TT * 4;
    float* Km = (float*)p;                                   // 128 MiB

    dim3 blk(256);

    // Projections
    gemm_nn<<<dim3(DD / 128, TT / 128), blk, 0, stream>>>(q, Qw, qp, TT, DD, DD);
    gemm_nn<<<dim3(DD / 128, (BB * NP) / 128), blk, 0, stream>>>(k, Kw, kp, BB * NP, DD, DD);
    gemm_nn<<<dim3(DD / 128, (BB * NP) / 128), blk, 0, stream>>>(v, Vw, vp, BB * NP, DD, DD);

    // Squared norms
    rownorm<<<dim3(TT / 4), blk, 0, stream>>>(qp, q2, TT);
    rownorm<<<dim3((BB * NP) / 4), blk, 0, stream>>>(kp, k2, BB * NP);

    // Cost matrix -> Kmat
    gemm_nt_cost<<<dim3(NP / 128, TT / 128, BB), blk, 0, stream>>>(qp, kp, q2, k2, Km);

    // Sinkhorn iterations (v starts at 0)
    hipMemsetAsync(vv, 0, (size_t)BB * TT * 4, stream);
    for (int it = 0; it < 5; ++it) {
        u_update<<<dim3(NP / 64, BB), blk, 0, stream>>>(Km, vv, uu);
        v_update<<<dim3(TT, BB), blk, 0, stream>>>(Km, uu, vv);
    }

    // out = exp(Kmat+u+v) @ vp (fused)
    gemm_pi<<<dim3(DD / 128, TT / 128, BB), blk, 0, stream>>>(Km, uu, vv, vp, out);
}

// Round 6
// 934.976 us; speedup vs baseline: 1.7992x; 1.7992x over previous
//
#include <hip/hip_runtime.h>
#include <math.h>

#define TT 2048   // tokens
#define NP 2048   // num params (N)
#define BB 8      // batch
#define DD 512    // d_model = kdim = vdim

#define LOG_A (-7.6246189861593985f)  // -log(2048)

typedef __attribute__((ext_vector_type(8))) short bf16x8;
typedef __attribute__((ext_vector_type(4))) float f32x4;

#define MFMA16(a, b, c) __builtin_amdgcn_mfma_f32_16x16x32_bf16((a), (b), (c), 0, 0, 0)

// ---------------------------------------------------------------------------
// bf16 helpers (round-to-nearest-even) + hi/lo split
// ---------------------------------------------------------------------------
__device__ __forceinline__ unsigned short f2bf_rn(float x) {
    union { float f; unsigned u; } v; v.f = x;
    unsigned r = v.u + 0x7fffu + ((v.u >> 16) & 1u);
    return (unsigned short)(r >> 16);
}
__device__ __forceinline__ float bf2f(unsigned short h) {
    union { unsigned u; float f; } v; v.u = ((unsigned)h) << 16;
    return v.f;
}

// async global->LDS, 16B per lane (wave-uniform LDS base + lane*16, per-lane src)
__device__ __forceinline__ void gload16(const void* g, void* l) {
    __builtin_amdgcn_global_load_lds(
        (const __attribute__((address_space(1))) void*)g,
        (__attribute__((address_space(3))) void*)l, 16, 0, 0);
}

// ---------------------------------------------------------------------------
// Shared MFMA inner step. LDS tiles are "k-group-major": tile[s][r][8 bf16],
// s = k-subgroup (0..3, 8 bf16 each => BK=32), r = row (0..127). Byte offset
// = s*2048 + r*16. Fragment reads are stride-1 across 16-lane groups ->
// conflict-free ds_read_b128.
// A-frag (16x16x32): lane holds A[m=lane%16][k=(lane/16)*8+j]
// B-frag:            lane holds B[k=(lane/16)*8+j][n=lane%16]  (B stored [N][K])
// C/D:               col=lane&15, row=(lane>>4)*4+reg   [m89-verified]
// ---------------------------------------------------------------------------
__device__ __forceinline__ void frag_mfma_step(
    const short* sAh, const short* sAl, const short* sBh, const short* sBl,
    int lane, int wm, int wn, f32x4 acc[4][4])
{
    const int sb = (lane >> 4) << 11;
    const int rl = (lane & 15) << 4;
    bf16x8 ah[4], al[4], bh[4], bl[4];
    #pragma unroll
    for (int i = 0; i < 4; ++i) {
        int ra = sb + ((wm + i * 16) << 4) + rl;
        ah[i] = *(const bf16x8*)((const char*)sAh + ra);
        al[i] = *(const bf16x8*)((const char*)sAl + ra);
        int rb = sb + ((wn + i * 16) << 4) + rl;
        bh[i] = *(const bf16x8*)((const char*)sBh + rb);
        bl[i] = *(const bf16x8*)((const char*)sBl + rb);
    }
    #pragma unroll
    for (int i = 0; i < 4; ++i)
        #pragma unroll
        for (int j = 0; j < 4; ++j) {
            acc[i][j] = MFMA16(ah[i], bh[j], acc[i][j]);
            acc[i][j] = MFMA16(ah[i], bl[j], acc[i][j]);
            acc[i][j] = MFMA16(al[i], bh[j], acc[i][j]);
        }
}

__device__ __forceinline__ void zero_acc(f32x4 acc[4][4]) {
    #pragma unroll
    for (int i = 0; i < 4; ++i)
        #pragma unroll
        for (int j = 0; j < 4; ++j)
            acc[i][j] = (f32x4){0.f, 0.f, 0.f, 0.f};
}

__device__ __forceinline__ void store_plain(
    float* C, int N, int row0, int col0, int lane, int wm, int wn, f32x4 acc[4][4])
{
    #pragma unroll
    for (int i = 0; i < 4; ++i)
        #pragma unroll
        for (int j = 0; j < 4; ++j) {
            int colg = col0 + wn + j * 16 + (lane & 15);
            int rowb = row0 + wm + i * 16 + ((lane >> 4) << 2);
            #pragma unroll
            for (int r = 0; r < 4; ++r)
                C[(size_t)(rowb + r) * N + colg] = acc[i][j][r];
        }
}

// ---------------------------------------------------------------------------
// Transpose + hi/lo bf16 convert: X[z][R][C] fp32 -> out[z][C][R] bf16 hi/lo.
// Used for weights (R=C=512, z=1) and vp (R=2048, C=512, z=8).
// ---------------------------------------------------------------------------
__global__ __launch_bounds__(256) void transpose_hilo(
    const float* __restrict__ X, short* __restrict__ hiT, short* __restrict__ loT,
    int R, int C)
{
    const size_t zoff = (size_t)blockIdx.z * R * C;
    const float* Xb = X + zoff;
    short* hb = hiT + zoff;
    short* lb = loT + zoff;
    __shared__ float t[64][65];
    const int bx = blockIdx.x * 64;  // C base
    const int by = blockIdx.y * 64;  // R base
    const int tx = threadIdx.x & 63, ty = threadIdx.x >> 6;
    #pragma unroll
    for (int r = ty; r < 64; r += 4)
        t[r][tx] = Xb[(size_t)(by + r) * C + bx + tx];
    __syncthreads();
    #pragma unroll
    for (int r = ty; r < 64; r += 4) {
        float xv = t[tx][r];                       // X[by+tx][bx+r]
        unsigned short h = f2bf_rn(xv);
        size_t oo = (size_t)(bx + r) * R + by + tx;
        hb[oo] = (short)h;
        lb[oo] = (short)f2bf_rn(xv - bf2f(h));
    }
}

// ---------------------------------------------------------------------------
// Straight hi/lo convert (no transpose), 8 elems per thread-iter.
// ---------------------------------------------------------------------------
__global__ __launch_bounds__(256) void convert_hilo(
    const float* __restrict__ x, short* __restrict__ hi, short* __restrict__ lo, int n8)
{
    for (int g = blockIdx.x * 256 + threadIdx.x; g < n8; g += gridDim.x * 256) {
        float4 a = ((const float4*)x)[2 * g];
        float4 b = ((const float4*)x)[2 * g + 1];
        float xs[8] = {a.x, a.y, a.z, a.w, b.x, b.y, b.z, b.w};
        short hs[8], ls[8];
        #pragma unroll
        for (int j = 0; j < 8; ++j) {
            unsigned short h = f2bf_rn(xs[j]);
            hs[j] = (short)h;
            ls[j] = (short)f2bf_rn(xs[j] - bf2f(h));
        }
        ((bf16x8*)hi)[g] = *(bf16x8*)hs;
        ((bf16x8*)lo)[g] = *(bf16x8*)ls;
    }
}

// ---------------------------------------------------------------------------
// Projection GEMM (NT, split bf16): C[M,N] = A[M,K] @ Bt[N,K]^T, fp32 out.
// A fp32 reg-staged -> hi/lo -> ds_write; B pre-converted hi/lo via gload_lds.
// ---------------------------------------------------------------------------
__global__ __launch_bounds__(256) void gemm_nt_f32A(
    const float* __restrict__ A, const short* __restrict__ Bh,
    const short* __restrict__ Bl, float* __restrict__ C,
    int M, int N, int K)
{
    __shared__ __attribute__((aligned(16))) short sAh[4096], sAl[4096], sBh[4096], sBl[4096];
    const int tid = threadIdx.x;
    const int lane = tid & 63;
    const int row0 = blockIdx.y * 128;
    const int col0 = blockIdx.x * 128;
    const int wm = ((tid >> 7) & 1) * 64;
    const int wn = ((tid >> 6) & 1) * 64;
    f32x4 acc[4][4];
    zero_acc(acc);

    for (int k0 = 0; k0 < K; k0 += 32) {
        __syncthreads();
        #pragma unroll
        for (int q = 0; q < 2; ++q) {
            int o = (tid + (q << 8)) << 4;     // byte offset in bf16 tile
            int s = o >> 11;
            int r = (o & 2047) >> 4;
            size_t gb = (size_t)(col0 + r) * K + k0 + s * 8;
            gload16(Bh + gb, (char*)sBh + o);
            gload16(Bl + gb, (char*)sBl + o);
            const float* src = A + (size_t)(row0 + r) * K + k0 + s * 8;
            float4 f0 = *(const float4*)src;
            float4 f1 = *(const float4*)(src + 4);
            float xs[8] = {f0.x, f0.y, f0.z, f0.w, f1.x, f1.y, f1.z, f1.w};
            short hs[8], ls[8];
            #pragma unroll
            for (int j = 0; j < 8; ++j) {
                unsigned short h = f2bf_rn(xs[j]);
                hs[j] = (short)h;
                ls[j] = (short)f2bf_rn(xs[j] - bf2f(h));
            }
            *(bf16x8*)((char*)sAh + o) = *(bf16x8*)hs;
            *(bf16x8*)((char*)sAl + o) = *(bf16x8*)ls;
        }
        __syncthreads();
        frag_mfma_step(sAh, sAl, sBh, sBl, lane, wm, wn, acc);
    }
    store_plain(C, N, row0, col0, lane, wm, wn, acc);
}

// ---------------------------------------------------------------------------
// Cost GEMM (NT, split bf16): S = qp @ kp^T per batch, epilogue
//   Km[b,t,n] = -sqrt(max(q2[t] + k2[b,n] - 2 S, 0))
// ---------------------------------------------------------------------------
__global__ __launch_bounds__(256) void gemm_cost_mfma(
    const short* __restrict__ Ah, const short* __restrict__ Al,
    const short* __restrict__ Bh, const short* __restrict__ Bl,
    const float* __restrict__ q2, const float* __restrict__ k2,
    float* __restrict__ Km)
{
    const int b = blockIdx.z;
    const short* Bhb = Bh + (size_t)b * NP * DD;
    const short* Blb = Bl + (size_t)b * NP * DD;
    const float* k2b = k2 + (size_t)b * NP;
    float* Cb = Km + (size_t)b * TT * NP;

    __shared__ __attribute__((aligned(16))) short sAh[4096], sAl[4096], sBh[4096], sBl[4096];
    const int tid = threadIdx.x;
    const int lane = tid & 63;
    const int row0 = blockIdx.y * 128;   // t
    const int col0 = blockIdx.x * 128;   // n
    const int wm = ((tid >> 7) & 1) * 64;
    const int wn = ((tid >> 6) & 1) * 64;
    f32x4 acc[4][4];
    zero_acc(acc);

    for (int k0 = 0; k0 < DD; k0 += 32) {
        __syncthreads();
        #pragma unroll
        for (int q = 0; q < 2; ++q) {
            int o = (tid + (q << 8)) << 4;
            int s = o >> 11;
            int r = (o & 2047) >> 4;
            size_t ga = (size_t)(row0 + r) * DD + k0 + s * 8;
            gload16(Ah + ga, (char*)sAh + o);
            gload16(Al + ga, (char*)sAl + o);
            size_t gb = (size_t)(col0 + r) * DD + k0 + s * 8;
            gload16(Bhb + gb, (char*)sBh + o);
            gload16(Blb + gb, (char*)sBl + o);
        }
        __syncthreads();
        frag_mfma_step(sAh, sAl, sBh, sBl, lane, wm, wn, acc);
    }
    #pragma unroll
    for (int i = 0; i < 4; ++i)
        #pragma unroll
        for (int j = 0; j < 4; ++j) {
            int colg = col0 + wn + j * 16 + (lane & 15);
            float k2v = k2b[colg];
            int rowb = row0 + wm + i * 16 + ((lane >> 4) << 2);
            #pragma unroll
            for (int r = 0; r < 4; ++r) {
                float sq = q2[rowb + r] + k2v - 2.f * acc[i][j][r];
                Cb[(size_t)(rowb + r) * NP + colg] = -sqrtf(fmaxf(sq, 0.f));
            }
        }
}

// ---------------------------------------------------------------------------
// pi GEMM (NT, split bf16): out[b,t,d] = sum_n exp(Km+u+v) * vpT[b,d,n]
// A = exp(Km[t,n]+u[n]+v[t]) computed in regs -> hi/lo -> ds_write.
// B = vpT hi/lo [D][NP] via gload_lds. M=TT, N=DD, K=NP.
// ---------------------------------------------------------------------------
__global__ __launch_bounds__(256) void gemm_pi_mfma(
    const float* __restrict__ Km, const float* __restrict__ uu,
    const float* __restrict__ vv, const short* __restrict__ Bh,
    const short* __restrict__ Bl, float* __restrict__ out)
{
    const int b = blockIdx.z;
    const float* Kb = Km + (size_t)b * TT * NP;
    const float* ub = uu + (size_t)b * NP;
    const float* vb = vv + (size_t)b * TT;
    const short* Bhb = Bh + (size_t)b * DD * NP;
    const short* Blb = Bl + (size_t)b * DD * NP;
    float* Cb = out + (size_t)b * TT * DD;

    __shared__ __attribute__((aligned(16))) short sAh[4096], sAl[4096], sBh[4096], sBl[4096];
    const int tid = threadIdx.x;
    const int lane = tid & 63;
    const int row0 = blockIdx.y * 128;   // t
    const int col0 = blockIdx.x * 128;   // d
    const int wm = ((tid >> 7) & 1) * 64;
    const int wn = ((tid >> 6) & 1) * 64;
    f32x4 acc[4][4];
    zero_acc(acc);

    for (int k0 = 0; k0 < NP; k0 += 32) {
        __syncthreads();
        #pragma unroll
        for (int q = 0; q < 2; ++q) {
            int o = (tid + (q << 8)) << 4;
            int s = o >> 11;
            int r = (o & 2047) >> 4;
            size_t gb = (size_t)(col0 + r) * NP + k0 + s * 8;
            gload16(Bhb + gb, (char*)sBh + o);
            gload16(Blb + gb, (char*)sBl + o);
            const float* src = Kb + (size_t)(row0 + r) * NP + k0 + s * 8;
            const float* us = ub + k0 + s * 8;
            float vr = vb[row0 + r];
            float4 f0 = *(const float4*)src;
            float4 f1 = *(const float4*)(src + 4);
            float4 u0 = *(const float4*)us;
            float4 u1 = *(const float4*)(us + 4);
            float xs[8] = {f0.x + u0.x, f0.y + u0.y, f0.z + u0.z, f0.w + u0.w,
                           f1.x + u1.x, f1.y + u1.y, f1.z + u1.z, f1.w + u1.w};
            short hs[8], ls[8];
            #pragma unroll
            for (int j = 0; j < 8; ++j) {
                float e = __expf(xs[j] + vr);
                unsigned short h = f2bf_rn(e);
                hs[j] = (short)h;
                ls[j] = (short)f2bf_rn(e - bf2f(h));
            }
            *(bf16x8*)((char*)sAh + o) = *(bf16x8*)hs;
            *(bf16x8*)((char*)sAl + o) = *(bf16x8*)ls;
        }
        __syncthreads();
        frag_mfma_step(sAh, sAl, sBh, sBl, lane, wm, wn, acc);
    }
    store_plain(Cb, DD, row0, col0, lane, wm, wn, acc);
}

// ---------------------------------------------------------------------------
// Row squared-norm: out[r] = sum_d X[r][d]^2. One wave per row.
// ---------------------------------------------------------------------------
__global__ __launch_bounds__(256) void rownorm(
    const float* __restrict__ X, float* __restrict__ o, int rows)
{
    int w = blockIdx.x * 4 + (threadIdx.x >> 6);
    int lane = threadIdx.x & 63;
    if (w >= rows) return;
    const float* xr = X + (size_t)w * DD;
    float s = 0.f;
    #pragma unroll
    for (int i = lane; i < DD; i += 64) { float x = xr[i]; s = fmaf(x, x, s); }
    #pragma unroll
    for (int off = 32; off; off >>= 1) s += __shfl_down(s, off, 64);
    if (lane == 0) o[w] = s;
}

// ---------------------------------------------------------------------------
// u update: u[b,n] = LOG_A - LSE_t( Kmat[b,t,n] + v[b,t] )
// ---------------------------------------------------------------------------
__global__ __launch_bounds__(256) void u_update(
    const float* __restrict__ Kmat, const float* __restrict__ vv,
    float* __restrict__ uu)
{
    const int b = blockIdx.y;
    const int c = threadIdx.x & 63;
    const int p = threadIdx.x >> 6;
    const int n = blockIdx.x * 64 + c;
    const float* Kb = Kmat + (size_t)b * TT * NP + n;
    const float* vb = vv + (size_t)b * TT;

    float m = -INFINITY, s = 0.f;
    const int t0 = p * (TT / 4);
    for (int tt = 0; tt < TT / 4; ++tt) {
        int t = t0 + tt;
        float x = Kb[(size_t)t * NP] + vb[t];
        float nm = fmaxf(m, x);
        s = s * __expf(m - nm) + __expf(x - nm);
        m = nm;
    }
    __shared__ float sm[4][64], ss[4][64];
    sm[p][c] = m; ss[p][c] = s;
    __syncthreads();
    if (p == 0) {
        #pragma unroll
        for (int q = 1; q < 4; ++q) {
            float m2 = sm[q][c], s2 = ss[q][c];
            float nm = fmaxf(m, m2);
            s = s * __expf(m - nm) + s2 * __expf(m2 - nm);
            m = nm;
        }
        uu[(size_t)b * NP + n] = LOG_A - (m + __logf(s));
    }
}

// ---------------------------------------------------------------------------
// v update: v[b,t] = -LSE_n( Kmat[b,t,n] + u[b,n] )
// ---------------------------------------------------------------------------
__global__ __launch_bounds__(256) void v_update(
    const float* __restrict__ Kmat, const float* __restrict__ uu,
    float* __restrict__ vv)
{
    const int b = blockIdx.y;
    const int t = blockIdx.x;
    const float* Kb = Kmat + ((size_t)b * TT + t) * NP;
    const float* ub = uu + (size_t)b * NP;
    const int tid = threadIdx.x;

    float m = -INFINITY, s = 0.f;
    #pragma unroll
    for (int n = tid; n < NP; n += 256) {
        float x = Kb[n] + ub[n];
        float nm = fmaxf(m, x);
        s = s * __expf(m - nm) + __expf(x - nm);
        m = nm;
    }
    __shared__ float sm[256], ss[256];
    sm[tid] = m; ss[tid] = s;
    __syncthreads();
    for (int off = 128; off; off >>= 1) {
        if (tid < off) {
            float m1 = sm[tid], s1 = ss[tid];
            float m2 = sm[tid + off], s2 = ss[tid + off];
            float nm = fmaxf(m1, m2);
            ss[tid] = s1 * __expf(m1 - nm) + s2 * __expf(m2 - nm);
            sm[tid] = nm;
        }
        __syncthreads();
    }
    if (tid == 0) vv[(size_t)b * TT + t] = -(sm[0] + __logf(ss[0]));
}

// ---------------------------------------------------------------------------
extern "C" void kernel_launch(void* const* d_in, const int* in_sizes, int n_in,
                              void* d_out, int out_size, void* d_ws, size_t ws_size,
                              hipStream_t stream)
{
    const float* q  = (const float*)d_in[0];
    const float* k  = (const float*)d_in[1];
    const float* v  = (const float*)d_in[2];
    const float* Qw = (const float*)d_in[3];
    const float* Kw = (const float*)d_in[4];
    const float* Vw = (const float*)d_in[5];
    float* out = (float*)d_out;

    // ---- workspace: 196.2 MiB total (same footprint as previous round) ----
    char* base = (char*)d_ws;
    float* Km = (float*)base;                                  // 128 MiB @ 0
    char* p2 = base + (size_t)BB * TT * NP * 4;
    short* qph = (short*)p2; p2 += (size_t)TT * DD * 2;        // 2 MiB
    short* qpl = (short*)p2; p2 += (size_t)TT * DD * 2;
    short* kph = (short*)p2; p2 += (size_t)BB * NP * DD * 2;   // 16 MiB
    short* kpl = (short*)p2; p2 += (size_t)BB * NP * DD * 2;
    short* vph = (short*)p2; p2 += (size_t)BB * NP * DD * 2;   // vpT hi
    short* vpl = (short*)p2; p2 += (size_t)BB * NP * DD * 2;   // vpT lo
    float* q2 = (float*)p2; p2 += (size_t)TT * 4;
    float* k2 = (float*)p2; p2 += (size_t)BB * NP * 4;
    float* uu = (float*)p2; p2 += (size_t)BB * NP * 4;
    float* vv = (float*)p2; p2 += (size_t)BB * TT * 4;

    // temporaries aliased INSIDE the Km region (dead before Km is written):
    float* qp = (float*)base;                                  // 4 MiB
    float* kp = (float*)(base + (size_t)4194304);              // 32 MiB
    float* vp = (float*)(base + (size_t)37748736);             // 32 MiB
    short* wqh = (short*)(base + (size_t)71303168);            // 6 x 0.5 MiB
    short* wql = wqh + 262144;
    short* wkh = wql + 262144;
    short* wkl = wkh + 262144;
    short* wvh = wkl + 262144;
    short* wvl = wvh + 262144;

    dim3 blk(256);

    // Weights: transpose + hi/lo convert ([K][N] -> [N][K])
    transpose_hilo<<<dim3(8, 8, 1), blk, 0, stream>>>(Qw, wqh, wql, 512, 512);
    transpose_hilo<<<dim3(8, 8, 1), blk, 0, stream>>>(Kw, wkh, wkl, 512, 512);
    transpose_hilo<<<dim3(8, 8, 1), blk, 0, stream>>>(Vw, wvh, wvl, 512, 512);

    // Projections (split-bf16 MFMA, fp32 A reg-staged)
    gemm_nt_f32A<<<dim3(4, 16, 1), blk, 0, stream>>>(q, wqh, wql, qp, TT, DD, DD);
    gemm_nt_f32A<<<dim3(4, 128, 1), blk, 0, stream>>>(k, wkh, wkl, kp, BB * NP, DD, DD);
    gemm_nt_f32A<<<dim3(4, 128, 1), blk, 0, stream>>>(v, wvh, wvl, vp, BB * NP, DD, DD);

    // Squared norms (fp32)
    rownorm<<<dim3(TT / 4), blk, 0, stream>>>(qp, q2, TT);
    rownorm<<<dim3((BB * NP) / 4), blk, 0, stream>>>(kp, k2, BB * NP);

    // qp/kp -> hi/lo bf16; vp -> transposed hi/lo bf16
    convert_hilo<<<dim3(512), blk, 0, stream>>>(qp, qph, qpl, TT * DD / 8);
    convert_hilo<<<dim3(2048), blk, 0, stream>>>(kp, kph, kpl, BB * NP * DD / 8);
    transpose_hilo<<<dim3(DD / 64, NP / 64, BB), blk, 0, stream>>>(vp, vph, vpl, NP, DD);

    // Cost matrix -> Km (overwrites all temporaries; they are dead now)
    gemm_cost_mfma<<<dim3(NP / 128, TT / 128, BB), blk, 0, stream>>>(
        qph, qpl, kph, kpl, q2, k2, Km);

    // Sinkhorn iterations (v starts at 0)
    hipMemsetAsync(vv, 0, (size_t)BB * TT * 4, stream);
    for (int it = 0; it < 5; ++it) {
        u_update<<<dim3(NP / 64, BB), blk, 0, stream>>>(Km, vv, uu);
        v_update<<<dim3(TT, BB), blk, 0, stream>>>(Km, uu, vv);
    }

    // out = exp(Km+u+v) @ vp (fused, split-bf16 MFMA)
    gemm_pi_mfma<<<dim3(DD / 128, TT / 128, BB), blk, 0, stream>>>(
        Km, uu, vv, vph, vpl, out);
}

// Round 7
// 886.443 us; speedup vs baseline: 1.8977x; 1.0547x over previous
//
#include <hip/hip_runtime.h>
#include <math.h>

#define TT 2048   // tokens
#define NP 2048   // num params (N)
#define BB 8      // batch
#define DD 512    // d_model = kdim = vdim

#define LOG_A (-7.6246189861593985f)  // -log(2048)
#define INV1024 (9.765625e-4f)

typedef __attribute__((ext_vector_type(8))) short bf16x8;
typedef __attribute__((ext_vector_type(4))) float f32x4;

#define MFMA16(a, b, c) __builtin_amdgcn_mfma_f32_16x16x32_bf16((a), (b), (c), 0, 0, 0)

// ---------------------------------------------------------------------------
// bf16 helpers (round-to-nearest-even) + hi/lo split
// ---------------------------------------------------------------------------
__device__ __forceinline__ unsigned short f2bf_rn(float x) {
    union { float f; unsigned u; } v; v.f = x;
    unsigned r = v.u + 0x7fffu + ((v.u >> 16) & 1u);
    return (unsigned short)(r >> 16);
}
__device__ __forceinline__ float bf2f(unsigned short h) {
    union { unsigned u; float f; } v; v.u = ((unsigned)h) << 16;
    return v.f;
}

// async global->LDS, 16B per lane (wave-uniform LDS base + lane*16, per-lane src)
__device__ __forceinline__ void gload16(const void* g, void* l) {
    __builtin_amdgcn_global_load_lds(
        (const __attribute__((address_space(1))) void*)g,
        (__attribute__((address_space(3))) void*)l, 16, 0, 0);
}

// ---------------------------------------------------------------------------
// Shared MFMA inner step. LDS tiles "k-group-major": tile[s][r][8 bf16],
// s = k-subgroup (0..3 => BK=32), r = row (0..127). Byte off = s*2048 + r*16.
// A-frag (16x16x32): lane holds A[m=lane%16][k=(lane/16)*8+j]
// B-frag:            lane holds B[k=(lane/16)*8+j][n=lane%16]  (B stored [N][K])
// C/D:               col=lane&15, row=(lane>>4)*4+reg   [m89-verified]
// ---------------------------------------------------------------------------
__device__ __forceinline__ void frag_mfma_step(
    const short* sAh, const short* sAl, const short* sBh, const short* sBl,
    int lane, int wm, int wn, f32x4 acc[4][4])
{
    const int sb = (lane >> 4) << 11;
    const int rl = (lane & 15) << 4;
    bf16x8 ah[4], al[4], bh[4], bl[4];
    #pragma unroll
    for (int i = 0; i < 4; ++i) {
        int ra = sb + ((wm + i * 16) << 4) + rl;
        ah[i] = *(const bf16x8*)((const char*)sAh + ra);
        al[i] = *(const bf16x8*)((const char*)sAl + ra);
        int rb = sb + ((wn + i * 16) << 4) + rl;
        bh[i] = *(const bf16x8*)((const char*)sBh + rb);
        bl[i] = *(const bf16x8*)((const char*)sBl + rb);
    }
    #pragma unroll
    for (int i = 0; i < 4; ++i)
        #pragma unroll
        for (int j = 0; j < 4; ++j) {
            acc[i][j] = MFMA16(ah[i], bh[j], acc[i][j]);
            acc[i][j] = MFMA16(ah[i], bl[j], acc[i][j]);
            acc[i][j] = MFMA16(al[i], bh[j], acc[i][j]);
        }
}

__device__ __forceinline__ void zero_acc(f32x4 acc[4][4]) {
    #pragma unroll
    for (int i = 0; i < 4; ++i)
        #pragma unroll
        for (int j = 0; j < 4; ++j)
            acc[i][j] = (f32x4){0.f, 0.f, 0.f, 0.f};
}

__device__ __forceinline__ void store_plain(
    float* C, int N, int row0, int col0, int lane, int wm, int wn, f32x4 acc[4][4])
{
    #pragma unroll
    for (int i = 0; i < 4; ++i)
        #pragma unroll
        for (int j = 0; j < 4; ++j) {
            int colg = col0 + wn + j * 16 + (lane & 15);
            int rowb = row0 + wm + i * 16 + ((lane >> 4) << 2);
            #pragma unroll
            for (int r = 0; r < 4; ++r)
                C[(size_t)(rowb + r) * N + colg] = acc[i][j][r];
        }
}

// ---------------------------------------------------------------------------
// Transpose + hi/lo bf16 convert: X[z][R][C] fp32 -> out[z][C][R] bf16 hi/lo.
// ---------------------------------------------------------------------------
__global__ __launch_bounds__(256) void transpose_hilo(
    const float* __restrict__ X, short* __restrict__ hiT, short* __restrict__ loT,
    int R, int C)
{
    const size_t zoff = (size_t)blockIdx.z * R * C;
    const float* Xb = X + zoff;
    short* hb = hiT + zoff;
    short* lb = loT + zoff;
    __shared__ float t[64][65];
    const int bx = blockIdx.x * 64;  // C base
    const int by = blockIdx.y * 64;  // R base
    const int tx = threadIdx.x & 63, ty = threadIdx.x >> 6;
    #pragma unroll
    for (int r = ty; r < 64; r += 4)
        t[r][tx] = Xb[(size_t)(by + r) * C + bx + tx];
    __syncthreads();
    #pragma unroll
    for (int r = ty; r < 64; r += 4) {
        float xv = t[tx][r];                       // X[by+tx][bx+r]
        unsigned short h = f2bf_rn(xv);
        size_t oo = (size_t)(bx + r) * R + by + tx;
        hb[oo] = (short)h;
        lb[oo] = (short)f2bf_rn(xv - bf2f(h));
    }
}

// ---------------------------------------------------------------------------
// Projection GEMM (NT, split bf16): C = A[M,K] @ Bt[N,K]^T.
// HL=true: write hi/lo bf16 outputs. HL=false: write fp32.
// ---------------------------------------------------------------------------
template<bool HL>
__global__ __launch_bounds__(256) void gemm_nt_f32A(
    const float* __restrict__ A, const short* __restrict__ Bh,
    const short* __restrict__ Bl, float* __restrict__ Cf,
    short* __restrict__ Ch, short* __restrict__ Cl,
    int M, int N, int K)
{
    __shared__ __attribute__((aligned(16))) short sAh[4096], sAl[4096], sBh[4096], sBl[4096];
    const int tid = threadIdx.x;
    const int lane = tid & 63;
    const int row0 = blockIdx.y * 128;
    const int col0 = blockIdx.x * 128;
    const int wm = ((tid >> 7) & 1) * 64;
    const int wn = ((tid >> 6) & 1) * 64;
    f32x4 acc[4][4];
    zero_acc(acc);

    for (int k0 = 0; k0 < K; k0 += 32) {
        __syncthreads();
        #pragma unroll
        for (int q = 0; q < 2; ++q) {
            int o = (tid + (q << 8)) << 4;     // byte offset in bf16 tile
            int s = o >> 11;
            int r = (o & 2047) >> 4;
            size_t gb = (size_t)(col0 + r) * K + k0 + s * 8;
            gload16(Bh + gb, (char*)sBh + o);
            gload16(Bl + gb, (char*)sBl + o);
            const float* src = A + (size_t)(row0 + r) * K + k0 + s * 8;
            float4 f0 = *(const float4*)src;
            float4 f1 = *(const float4*)(src + 4);
            float xs[8] = {f0.x, f0.y, f0.z, f0.w, f1.x, f1.y, f1.z, f1.w};
            short hs[8], ls[8];
            #pragma unroll
            for (int j = 0; j < 8; ++j) {
                unsigned short h = f2bf_rn(xs[j]);
                hs[j] = (short)h;
                ls[j] = (short)f2bf_rn(xs[j] - bf2f(h));
            }
            *(bf16x8*)((char*)sAh + o) = *(bf16x8*)hs;
            *(bf16x8*)((char*)sAl + o) = *(bf16x8*)ls;
        }
        __syncthreads();
        frag_mfma_step(sAh, sAl, sBh, sBl, lane, wm, wn, acc);
    }
    #pragma unroll
    for (int i = 0; i < 4; ++i)
        #pragma unroll
        for (int j = 0; j < 4; ++j) {
            int colg = col0 + wn + j * 16 + (lane & 15);
            int rowb = row0 + wm + i * 16 + ((lane >> 4) << 2);
            #pragma unroll
            for (int r = 0; r < 4; ++r) {
                size_t oo = (size_t)(rowb + r) * N + colg;
                float x = acc[i][j][r];
                if (HL) {
                    unsigned short h = f2bf_rn(x);
                    Ch[oo] = (short)h;
                    Cl[oo] = (short)f2bf_rn(x - bf2f(h));
                } else {
                    Cf[oo] = x;
                }
            }
        }
}

// ---------------------------------------------------------------------------
// Row squared-norm from hi/lo bf16: out[r] = sum_d (hi+lo)^2. One wave/row.
// ---------------------------------------------------------------------------
__global__ __launch_bounds__(256) void rownorm_hl(
    const short* __restrict__ hi, const short* __restrict__ lo,
    float* __restrict__ o, int rows)
{
    int w = blockIdx.x * 4 + (threadIdx.x >> 6);
    int lane = threadIdx.x & 63;
    if (w >= rows) return;
    bf16x8 hv = *(const bf16x8*)(hi + (size_t)w * DD + lane * 8);
    bf16x8 lv = *(const bf16x8*)(lo + (size_t)w * DD + lane * 8);
    float s = 0.f;
    #pragma unroll
    for (int j = 0; j < 8; ++j) {
        float x = bf2f((unsigned short)hv[j]) + bf2f((unsigned short)lv[j]);
        s = fmaf(x, x, s);
    }
    #pragma unroll
    for (int off = 32; off; off >>= 1) s += __shfl_down(s, off, 64);
    if (lane == 0) o[w] = s;
}

// ---------------------------------------------------------------------------
// Cost GEMM (NT, split bf16): S = qp @ kp^T per batch, epilogue quantizes
//   dist = sqrt(max(q2[t] + k2[b,n] - 2 S, 0));  Kq = round(dist*1024) uint16
// (Kmat = -dist = -Kq/1024; dist ~ 32 +- 2, far below the 64 overflow bound.)
// ---------------------------------------------------------------------------
__global__ __launch_bounds__(256) void gemm_cost_mfma(
    const short* __restrict__ Ah, const short* __restrict__ Al,
    const short* __restrict__ Bh, const short* __restrict__ Bl,
    const float* __restrict__ q2, const float* __restrict__ k2,
    unsigned short* __restrict__ Kq)
{
    const int b = blockIdx.z;
    const short* Bhb = Bh + (size_t)b * NP * DD;
    const short* Blb = Bl + (size_t)b * NP * DD;
    const float* k2b = k2 + (size_t)b * NP;
    unsigned short* Cb = Kq + (size_t)b * TT * NP;

    __shared__ __attribute__((aligned(16))) short sAh[4096], sAl[4096], sBh[4096], sBl[4096];
    const int tid = threadIdx.x;
    const int lane = tid & 63;
    const int row0 = blockIdx.y * 128;   // t
    const int col0 = blockIdx.x * 128;   // n
    const int wm = ((tid >> 7) & 1) * 64;
    const int wn = ((tid >> 6) & 1) * 64;
    f32x4 acc[4][4];
    zero_acc(acc);

    for (int k0 = 0; k0 < DD; k0 += 32) {
        __syncthreads();
        #pragma unroll
        for (int q = 0; q < 2; ++q) {
            int o = (tid + (q << 8)) << 4;
            int s = o >> 11;
            int r = (o & 2047) >> 4;
            size_t ga = (size_t)(row0 + r) * DD + k0 + s * 8;
            gload16(Ah + ga, (char*)sAh + o);
            gload16(Al + ga, (char*)sAl + o);
            size_t gb = (size_t)(col0 + r) * DD + k0 + s * 8;
            gload16(Bhb + gb, (char*)sBh + o);
            gload16(Blb + gb, (char*)sBl + o);
        }
        __syncthreads();
        frag_mfma_step(sAh, sAl, sBh, sBl, lane, wm, wn, acc);
    }
    #pragma unroll
    for (int i = 0; i < 4; ++i)
        #pragma unroll
        for (int j = 0; j < 4; ++j) {
            int colg = col0 + wn + j * 16 + (lane & 15);
            float k2v = k2b[colg];
            int rowb = row0 + wm + i * 16 + ((lane >> 4) << 2);
            #pragma unroll
            for (int r = 0; r < 4; ++r) {
                float sq = q2[rowb + r] + k2v - 2.f * acc[i][j][r];
                float dist = sqrtf(fmaxf(sq, 0.f));
                Cb[(size_t)(rowb + r) * NP + colg] =
                    (unsigned short)(fminf(dist, 63.9f) * 1024.f + 0.5f);
            }
        }
}

// ---------------------------------------------------------------------------
// u update: u[b,n] = LOG_A - LSE_t( -dist[b,t,n] + v[b,t] )
// Block = 256 thr = 64 lanes x 4 t-phases; lane handles 2 columns (uint load
// = 2 ushorts -> 256 B coalesced per wave per row). Grid (NP/128, BB).
// ---------------------------------------------------------------------------
__global__ __launch_bounds__(256) void u_update_q(
    const unsigned short* __restrict__ Kq, const float* __restrict__ vv,
    float* __restrict__ uu)
{
    const int b = blockIdx.y;
    const int lane = threadIdx.x & 63;
    const int p = threadIdx.x >> 6;
    const int n0 = blockIdx.x * 128;
    const unsigned* Kb = (const unsigned*)(Kq + (size_t)b * TT * NP + n0);
    const float* vb = vv + (size_t)b * TT;

    float m0 = -INFINITY, m1 = -INFINITY, s0 = 0.f, s1 = 0.f;
    const int t0 = p * (TT / 4);
    for (int tt = 0; tt < TT / 4; ++tt) {
        int t = t0 + tt;
        unsigned w = Kb[(size_t)t * (NP / 2) + lane];
        float vt = vb[t];
        float x0 = fmaf((float)(w & 0xFFFFu), -INV1024, vt);
        float x1 = fmaf((float)(w >> 16),     -INV1024, vt);
        float nm0 = fmaxf(m0, x0);
        s0 = s0 * __expf(m0 - nm0) + __expf(x0 - nm0); m0 = nm0;
        float nm1 = fmaxf(m1, x1);
        s1 = s1 * __expf(m1 - nm1) + __expf(x1 - nm1); m1 = nm1;
    }
    __shared__ float sm[4][128], ss[4][128];
    sm[p][2 * lane] = m0; sm[p][2 * lane + 1] = m1;
    ss[p][2 * lane] = s0; ss[p][2 * lane + 1] = s1;
    __syncthreads();
    if (p == 0) {
        #pragma unroll
        for (int q = 1; q < 4; ++q) {
            float a0 = sm[q][2 * lane], c0 = ss[q][2 * lane];
            float nm = fmaxf(m0, a0);
            s0 = s0 * __expf(m0 - nm) + c0 * __expf(a0 - nm); m0 = nm;
            float a1 = sm[q][2 * lane + 1], c1 = ss[q][2 * lane + 1];
            float nm1 = fmaxf(m1, a1);
            s1 = s1 * __expf(m1 - nm1) + c1 * __expf(a1 - nm1); m1 = nm1;
        }
        uu[(size_t)b * NP + n0 + 2 * lane]     = LOG_A - (m0 + __logf(s0));
        uu[(size_t)b * NP + n0 + 2 * lane + 1] = LOG_A - (m1 + __logf(s1));
    }
}

// ---------------------------------------------------------------------------
// v update: v[b,t] = -LSE_n( -dist[b,t,n] + u[b,n] )
// One block per row; thread reads uint4 (8 ushorts) -> whole 4 KB row covered.
// ---------------------------------------------------------------------------
__global__ __launch_bounds__(256) void v_update_q(
    const unsigned short* __restrict__ Kq, const float* __restrict__ uu,
    float* __restrict__ vv)
{
    const int b = blockIdx.y;
    const int t = blockIdx.x;
    const uint4* Kb = (const uint4*)(Kq + ((size_t)b * TT + t) * NP);
    const float* ub = uu + (size_t)b * NP;
    const int tid = threadIdx.x;

    uint4 w = Kb[tid];
    const int n0 = tid * 8;
    float4 u0 = *(const float4*)(ub + n0);
    float4 u1 = *(const float4*)(ub + n0 + 4);
    float x[8];
    x[0] = fmaf((float)(w.x & 0xFFFFu), -INV1024, u0.x);
    x[1] = fmaf((float)(w.x >> 16),     -INV1024, u0.y);
    x[2] = fmaf((float)(w.y & 0xFFFFu), -INV1024, u0.z);
    x[3] = fmaf((float)(w.y >> 16),     -INV1024, u0.w);
    x[4] = fmaf((float)(w.z & 0xFFFFu), -INV1024, u1.x);
    x[5] = fmaf((float)(w.z >> 16),     -INV1024, u1.y);
    x[6] = fmaf((float)(w.w & 0xFFFFu), -INV1024, u1.z);
    x[7] = fmaf((float)(w.w >> 16),     -INV1024, u1.w);
    float m = x[0];
    #pragma unroll
    for (int j = 1; j < 8; ++j) m = fmaxf(m, x[j]);
    float s = 0.f;
    #pragma unroll
    for (int j = 0; j < 8; ++j) s += __expf(x[j] - m);

    __shared__ float sm[256], ss[256];
    sm[tid] = m; ss[tid] = s;
    __syncthreads();
    for (int off = 128; off; off >>= 1) {
        if (tid < off) {
            float m1 = sm[tid], s1 = ss[tid];
            float m2 = sm[tid + off], s2 = ss[tid + off];
            float nm = fmaxf(m1, m2);
            ss[tid] = s1 * __expf(m1 - nm) + s2 * __expf(m2 - nm);
            sm[tid] = nm;
        }
        __syncthreads();
    }
    if (tid == 0) vv[(size_t)b * TT + t] = -(sm[0] + __logf(ss[0]));
}

// ---------------------------------------------------------------------------
// pi GEMM (NT, split bf16): out[b,t,d] = sum_n exp(u+v-dist) * vpT[b,d,n]
// A = exp(...) decoded from uint16 Kq in regs -> hi/lo -> ds_write.
// B = vpT hi/lo [D][NP] via gload_lds. M=TT, N=DD, K=NP.
// ---------------------------------------------------------------------------
__global__ __launch_bounds__(256) void gemm_pi_mfma(
    const unsigned short* __restrict__ Kq, const float* __restrict__ uu,
    const float* __restrict__ vv, const short* __restrict__ Bh,
    const short* __restrict__ Bl, float* __restrict__ out)
{
    const int b = blockIdx.z;
    const unsigned short* Kb = Kq + (size_t)b * TT * NP;
    const float* ub = uu + (size_t)b * NP;
    const float* vb = vv + (size_t)b * TT;
    const short* Bhb = Bh + (size_t)b * DD * NP;
    const short* Blb = Bl + (size_t)b * DD * NP;
    float* Cb = out + (size_t)b * TT * DD;

    __shared__ __attribute__((aligned(16))) short sAh[4096], sAl[4096], sBh[4096], sBl[4096];
    const int tid = threadIdx.x;
    const int lane = tid & 63;
    const int row0 = blockIdx.y * 128;   // t
    const int col0 = blockIdx.x * 128;   // d
    const int wm = ((tid >> 7) & 1) * 64;
    const int wn = ((tid >> 6) & 1) * 64;
    f32x4 acc[4][4];
    zero_acc(acc);

    for (int k0 = 0; k0 < NP; k0 += 32) {
        __syncthreads();
        #pragma unroll
        for (int q = 0; q < 2; ++q) {
            int o = (tid + (q << 8)) << 4;
            int s = o >> 11;
            int r = (o & 2047) >> 4;
            size_t gb = (size_t)(col0 + r) * NP + k0 + s * 8;
            gload16(Bhb + gb, (char*)sBh + o);
            gload16(Blb + gb, (char*)sBl + o);
            uint4 w = *(const uint4*)(Kb + (size_t)(row0 + r) * NP + k0 + s * 8);
            const float* us = ub + k0 + s * 8;
            float vr = vb[row0 + r];
            float4 u0 = *(const float4*)us;
            float4 u1 = *(const float4*)(us + 4);
            float xs[8];
            xs[0] = fmaf((float)(w.x & 0xFFFFu), -INV1024, u0.x + vr);
            xs[1] = fmaf((float)(w.x >> 16),     -INV1024, u0.y + vr);
            xs[2] = fmaf((float)(w.y & 0xFFFFu), -INV1024, u0.z + vr);
            xs[3] = fmaf((float)(w.y >> 16),     -INV1024, u0.w + vr);
            xs[4] = fmaf((float)(w.z & 0xFFFFu), -INV1024, u1.x + vr);
            xs[5] = fmaf((float)(w.z >> 16),     -INV1024, u1.y + vr);
            xs[6] = fmaf((float)(w.w & 0xFFFFu), -INV1024, u1.z + vr);
            xs[7] = fmaf((float)(w.w >> 16),     -INV1024, u1.w + vr);
            short hs[8], ls[8];
            #pragma unroll
            for (int j = 0; j < 8; ++j) {
                float e = __expf(xs[j]);
                unsigned short h = f2bf_rn(e);
                hs[j] = (short)h;
                ls[j] = (short)f2bf_rn(e - bf2f(h));
            }
            *(bf16x8*)((char*)sAh + o) = *(bf16x8*)hs;
            *(bf16x8*)((char*)sAl + o) = *(bf16x8*)ls;
        }
        __syncthreads();
        frag_mfma_step(sAh, sAl, sBh, sBl, lane, wm, wn, acc);
    }
    store_plain(Cb, DD, row0, col0, lane, wm, wn, acc);
}

// ---------------------------------------------------------------------------
extern "C" void kernel_launch(void* const* d_in, const int* in_sizes, int n_in,
                              void* d_out, int out_size, void* d_ws, size_t ws_size,
                              hipStream_t stream)
{
    const float* q  = (const float*)d_in[0];
    const float* k  = (const float*)d_in[1];
    const float* v  = (const float*)d_in[2];
    const float* Qw = (const float*)d_in[3];
    const float* Kw = (const float*)d_in[4];
    const float* Vw = (const float*)d_in[5];
    float* out = (float*)d_out;

    // ---- workspace: ~132.2 MiB ----
    char* base = (char*)d_ws;
    unsigned short* Kq = (unsigned short*)base;                // 64 MiB @ 0
    char* p2 = base + (size_t)BB * TT * NP * 2;
    short* qph = (short*)p2; p2 += (size_t)TT * DD * 2;        // 2 MiB
    short* qpl = (short*)p2; p2 += (size_t)TT * DD * 2;
    short* kph = (short*)p2; p2 += (size_t)BB * NP * DD * 2;   // 16 MiB
    short* kpl = (short*)p2; p2 += (size_t)BB * NP * DD * 2;
    short* vph = (short*)p2; p2 += (size_t)BB * NP * DD * 2;   // vpT hi
    short* vpl = (short*)p2; p2 += (size_t)BB * NP * DD * 2;   // vpT lo
    float* q2 = (float*)p2; p2 += (size_t)TT * 4;
    float* k2 = (float*)p2; p2 += (size_t)BB * NP * 4;
    float* uu = (float*)p2; p2 += (size_t)BB * NP * 4;
    float* vv = (float*)p2; p2 += (size_t)BB * TT * 4;

    // temporaries aliased INSIDE the Kq region (dead before Kq is written):
    float* vp  = (float*)base;                                 // 32 MiB (v proj, fp32)
    short* wqh = (short*)(base + (size_t)33554432);            // 6 x 0.5 MiB
    short* wql = wqh + 262144;
    short* wkh = wql + 262144;
    short* wkl = wkh + 262144;
    short* wvh = wkl + 262144;
    short* wvl = wvh + 262144;

    dim3 blk(256);

    // Weights: transpose + hi/lo convert ([K][N] -> [N][K])
    transpose_hilo<<<dim3(8, 8, 1), blk, 0, stream>>>(Qw, wqh, wql, 512, 512);
    transpose_hilo<<<dim3(8, 8, 1), blk, 0, stream>>>(Kw, wkh, wkl, 512, 512);
    transpose_hilo<<<dim3(8, 8, 1), blk, 0, stream>>>(Vw, wvh, wvl, 512, 512);

    // Projections: q,k write hi/lo bf16 directly; v writes fp32 (for transpose)
    gemm_nt_f32A<true><<<dim3(4, 16, 1), blk, 0, stream>>>(
        q, wqh, wql, nullptr, qph, qpl, TT, DD, DD);
    gemm_nt_f32A<true><<<dim3(4, 128, 1), blk, 0, stream>>>(
        k, wkh, wkl, nullptr, kph, kpl, BB * NP, DD, DD);
    gemm_nt_f32A<false><<<dim3(4, 128, 1), blk, 0, stream>>>(
        v, wvh, wvl, vp, nullptr, nullptr, BB * NP, DD, DD);

    // Squared norms from hi/lo
    rownorm_hl<<<dim3(TT / 4), blk, 0, stream>>>(qph, qpl, q2, TT);
    rownorm_hl<<<dim3((BB * NP) / 4), blk, 0, stream>>>(kph, kpl, k2, BB * NP);

    // vp -> transposed hi/lo bf16
    transpose_hilo<<<dim3(DD / 64, NP / 64, BB), blk, 0, stream>>>(vp, vph, vpl, NP, DD);

    // Cost matrix -> Kq uint16 (overwrites aliased temporaries; dead now)
    gemm_cost_mfma<<<dim3(NP / 128, TT / 128, BB), blk, 0, stream>>>(
        qph, qpl, kph, kpl, q2, k2, Kq);

    // Sinkhorn iterations (v starts at 0)
    hipMemsetAsync(vv, 0, (size_t)BB * TT * 4, stream);
    for (int it = 0; it < 5; ++it) {
        u_update_q<<<dim3(NP / 128, BB), blk, 0, stream>>>(Kq, vv, uu);
        v_update_q<<<dim3(TT, BB), blk, 0, stream>>>(Kq, uu, vv);
    }

    // out = exp(u+v-dist) @ vp (fused, split-bf16 MFMA)
    gemm_pi_mfma<<<dim3(DD / 128, TT / 128, BB), blk, 0, stream>>>(
        Kq, uu, vv, vph, vpl, out);
}

// Round 8
// 743.445 us; speedup vs baseline: 2.2627x; 1.1923x over previous
//
#include <hip/hip_runtime.h>
#include <math.h>

#define TT 2048   // tokens
#define NP 2048   // num params (N)
#define BB 8      // batch
#define DD 512    // d_model = kdim = vdim

#define LOG_A (-7.6246189861593985f)  // -log(2048)
#define INV1024 (9.765625e-4f)

typedef __attribute__((ext_vector_type(8))) short bf16x8;
typedef __attribute__((ext_vector_type(8))) _Float16 f16x8;
typedef __attribute__((ext_vector_type(4))) float f32x4;

#define MFMA_BF16(a, b, c) __builtin_amdgcn_mfma_f32_16x16x32_bf16((a), (b), (c), 0, 0, 0)
#define MFMA_F16(a, b, c)  __builtin_amdgcn_mfma_f32_16x16x32_f16((a), (b), (c), 0, 0, 0)

// ---------------------------------------------------------------------------
// bf16 helpers (round-to-nearest-even) + hi/lo split
// ---------------------------------------------------------------------------
__device__ __forceinline__ unsigned short f2bf_rn(float x) {
    union { float f; unsigned u; } v; v.f = x;
    unsigned r = v.u + 0x7fffu + ((v.u >> 16) & 1u);
    return (unsigned short)(r >> 16);
}
__device__ __forceinline__ float bf2f(unsigned short h) {
    union { unsigned u; float f; } v; v.u = ((unsigned)h) << 16;
    return v.f;
}

// async global->LDS, 16B per lane (wave-uniform LDS base + lane*16, per-lane src)
__device__ __forceinline__ void gload16(const void* g, void* l) {
    __builtin_amdgcn_global_load_lds(
        (const __attribute__((address_space(1))) void*)g,
        (__attribute__((address_space(3))) void*)l, 16, 0, 0);
}

// ---------------------------------------------------------------------------
// LDS tile layout (both bf16 and f16 paths), "k-group-major":
// tile[s][r][8 elems], s = k-subgroup (0..3 => BK=32), r = row (0..127).
// Byte offset = s*2048 + r*16. Conflict-free ds_read_b128 fragments.
// A-frag (16x16x32): lane holds A[m=lane%16][k=(lane/16)*8+j]
// B-frag:            lane holds B[k=(lane/16)*8+j][n=lane%16]  (B stored [N][K])
// C/D:               col=lane&15, row=(lane>>4)*4+reg   [m89-verified]
// ---------------------------------------------------------------------------
__device__ __forceinline__ void frag_step_bf16(
    const short* sAh, const short* sAl, const short* sBh, const short* sBl,
    int lane, int wm, int wn, f32x4 acc[4][4])
{
    const int sb = (lane >> 4) << 11;
    const int rl = (lane & 15) << 4;
    bf16x8 ah[4], al[4], bh[4], bl[4];
    #pragma unroll
    for (int i = 0; i < 4; ++i) {
        int ra = sb + ((wm + i * 16) << 4) + rl;
        ah[i] = *(const bf16x8*)((const char*)sAh + ra);
        al[i] = *(const bf16x8*)((const char*)sAl + ra);
        int rb = sb + ((wn + i * 16) << 4) + rl;
        bh[i] = *(const bf16x8*)((const char*)sBh + rb);
        bl[i] = *(const bf16x8*)((const char*)sBl + rb);
    }
    #pragma unroll
    for (int i = 0; i < 4; ++i)
        #pragma unroll
        for (int j = 0; j < 4; ++j) {
            acc[i][j] = MFMA_BF16(ah[i], bh[j], acc[i][j]);
            acc[i][j] = MFMA_BF16(ah[i], bl[j], acc[i][j]);
            acc[i][j] = MFMA_BF16(al[i], bh[j], acc[i][j]);
        }
}

__device__ __forceinline__ void frag_step_f16(
    const _Float16* sA, const _Float16* sB,
    int lane, int wm, int wn, f32x4 acc[4][4])
{
    const int sb = (lane >> 4) << 11;
    const int rl = (lane & 15) << 4;
    f16x8 a[4], b[4];
    #pragma unroll
    for (int i = 0; i < 4; ++i) {
        a[i] = *(const f16x8*)((const char*)sA + sb + ((wm + i * 16) << 4) + rl);
        b[i] = *(const f16x8*)((const char*)sB + sb + ((wn + i * 16) << 4) + rl);
    }
    #pragma unroll
    for (int i = 0; i < 4; ++i)
        #pragma unroll
        for (int j = 0; j < 4; ++j)
            acc[i][j] = MFMA_F16(a[i], b[j], acc[i][j]);
}

__device__ __forceinline__ void zero_acc(f32x4 acc[4][4]) {
    #pragma unroll
    for (int i = 0; i < 4; ++i)
        #pragma unroll
        for (int j = 0; j < 4; ++j)
            acc[i][j] = (f32x4){0.f, 0.f, 0.f, 0.f};
}

__device__ __forceinline__ void store_plain(
    float* C, int N, int row0, int col0, int lane, int wm, int wn, f32x4 acc[4][4])
{
    #pragma unroll
    for (int i = 0; i < 4; ++i)
        #pragma unroll
        for (int j = 0; j < 4; ++j) {
            int colg = col0 + wn + j * 16 + (lane & 15);
            int rowb = row0 + wm + i * 16 + ((lane >> 4) << 2);
            #pragma unroll
            for (int r = 0; r < 4; ++r)
                C[(size_t)(rowb + r) * N + colg] = acc[i][j][r];
        }
}

// ---------------------------------------------------------------------------
// Transpose + hi/lo bf16 convert (weights): X[R][C] fp32 -> [C][R] bf16 hi/lo.
// ---------------------------------------------------------------------------
__global__ __launch_bounds__(256) void transpose_hilo(
    const float* __restrict__ X, short* __restrict__ hiT, short* __restrict__ loT,
    int R, int C)
{
    const size_t zoff = (size_t)blockIdx.z * R * C;
    const float* Xb = X + zoff;
    short* hb = hiT + zoff;
    short* lb = loT + zoff;
    __shared__ float t[64][65];
    const int bx = blockIdx.x * 64;  // C base
    const int by = blockIdx.y * 64;  // R base
    const int tx = threadIdx.x & 63, ty = threadIdx.x >> 6;
    #pragma unroll
    for (int r = ty; r < 64; r += 4)
        t[r][tx] = Xb[(size_t)(by + r) * C + bx + tx];
    __syncthreads();
    #pragma unroll
    for (int r = ty; r < 64; r += 4) {
        float xv = t[tx][r];                       // X[by+tx][bx+r]
        unsigned short h = f2bf_rn(xv);
        size_t oo = (size_t)(bx + r) * R + by + tx;
        hb[oo] = (short)h;
        lb[oo] = (short)f2bf_rn(xv - bf2f(h));
    }
}

// ---------------------------------------------------------------------------
// Transpose to fp16 (vp): X[z][R][C] fp32 -> out[z][C][R] f16.
// ---------------------------------------------------------------------------
__global__ __launch_bounds__(256) void transpose_f16(
    const float* __restrict__ X, _Float16* __restrict__ oT, int R, int C)
{
    const size_t zoff = (size_t)blockIdx.z * R * C;
    const float* Xb = X + zoff;
    _Float16* ob = oT + zoff;
    __shared__ float t[64][65];
    const int bx = blockIdx.x * 64;  // C base
    const int by = blockIdx.y * 64;  // R base
    const int tx = threadIdx.x & 63, ty = threadIdx.x >> 6;
    #pragma unroll
    for (int r = ty; r < 64; r += 4)
        t[r][tx] = Xb[(size_t)(by + r) * C + bx + tx];
    __syncthreads();
    #pragma unroll
    for (int r = ty; r < 64; r += 4)
        ob[(size_t)(bx + r) * R + by + tx] = (_Float16)t[tx][r];
}

// ---------------------------------------------------------------------------
// Projection GEMM (NT, split bf16, fp32-grade): C = A[M,K] @ Bt[N,K]^T.
// OUT=0: fp32 out (vp). OUT=1: fp16 out (qp, kp).
// ---------------------------------------------------------------------------
template<int OUT>
__global__ __launch_bounds__(256) void gemm_nt_f32A(
    const float* __restrict__ A, const short* __restrict__ Bh,
    const short* __restrict__ Bl, float* __restrict__ Cf,
    _Float16* __restrict__ Ch, int M, int N, int K)
{
    __shared__ __attribute__((aligned(16))) short sAh[4096], sAl[4096], sBh[4096], sBl[4096];
    const int tid = threadIdx.x;
    const int lane = tid & 63;
    const int row0 = blockIdx.y * 128;
    const int col0 = blockIdx.x * 128;
    const int wm = ((tid >> 7) & 1) * 64;
    const int wn = ((tid >> 6) & 1) * 64;
    f32x4 acc[4][4];
    zero_acc(acc);

    for (int k0 = 0; k0 < K; k0 += 32) {
        __syncthreads();
        #pragma unroll
        for (int q = 0; q < 2; ++q) {
            int o = (tid + (q << 8)) << 4;     // byte offset in bf16 tile
            int s = o >> 11;
            int r = (o & 2047) >> 4;
            size_t gb = (size_t)(col0 + r) * K + k0 + s * 8;
            gload16(Bh + gb, (char*)sBh + o);
            gload16(Bl + gb, (char*)sBl + o);
            const float* src = A + (size_t)(row0 + r) * K + k0 + s * 8;
            float4 f0 = *(const float4*)src;
            float4 f1 = *(const float4*)(src + 4);
            float xs[8] = {f0.x, f0.y, f0.z, f0.w, f1.x, f1.y, f1.z, f1.w};
            short hs[8], ls[8];
            #pragma unroll
            for (int j = 0; j < 8; ++j) {
                unsigned short h = f2bf_rn(xs[j]);
                hs[j] = (short)h;
                ls[j] = (short)f2bf_rn(xs[j] - bf2f(h));
            }
            *(bf16x8*)((char*)sAh + o) = *(bf16x8*)hs;
            *(bf16x8*)((char*)sAl + o) = *(bf16x8*)ls;
        }
        __syncthreads();
        frag_step_bf16(sAh, sAl, sBh, sBl, lane, wm, wn, acc);
    }
    #pragma unroll
    for (int i = 0; i < 4; ++i)
        #pragma unroll
        for (int j = 0; j < 4; ++j) {
            int colg = col0 + wn + j * 16 + (lane & 15);
            int rowb = row0 + wm + i * 16 + ((lane >> 4) << 2);
            #pragma unroll
            for (int r = 0; r < 4; ++r) {
                size_t oo = (size_t)(rowb + r) * N + colg;
                float x = acc[i][j][r];
                if (OUT == 1) Ch[oo] = (_Float16)x;
                else          Cf[oo] = x;
            }
        }
}

// ---------------------------------------------------------------------------
// Row squared-norm from fp16: out[r] = sum_d x^2. One wave per row.
// (Self-consistent with what the fp16 cost GEMM computes.)
// ---------------------------------------------------------------------------
__global__ __launch_bounds__(256) void rownorm_f16(
    const _Float16* __restrict__ X, float* __restrict__ o, int rows)
{
    int w = blockIdx.x * 4 + (threadIdx.x >> 6);
    int lane = threadIdx.x & 63;
    if (w >= rows) return;
    f16x8 v = *(const f16x8*)(X + (size_t)w * DD + lane * 8);
    float s = 0.f;
    #pragma unroll
    for (int j = 0; j < 8; ++j) {
        float x = (float)v[j];
        s = fmaf(x, x, s);
    }
    #pragma unroll
    for (int off = 32; off; off >>= 1) s += __shfl_down(s, off, 64);
    if (lane == 0) o[w] = s;
}

// ---------------------------------------------------------------------------
// Cost GEMM (NT, fp16 single-product): S = qp @ kp^T per batch, epilogue
//   dist = sqrt(max(q2[t] + k2[b,n] - 2 S, 0));  Kq = round(dist*1024) uint16
// 1-D grid, XCD-chunked swizzle: one batch per XCD (qp+kp_b fit 4MB L2).
// ---------------------------------------------------------------------------
__global__ __launch_bounds__(256) void gemm_cost_f16(
    const _Float16* __restrict__ A, const _Float16* __restrict__ B,
    const float* __restrict__ q2, const float* __restrict__ k2,
    unsigned short* __restrict__ Kq)
{
    // swizzle: XCD j (= bid%8) gets contiguous sid chunk of 256 = one batch
    const int bid = blockIdx.x;
    const int sid = ((bid & 7) << 8) | (bid >> 3);
    const int b  = sid >> 8;
    const int by = (sid >> 4) & 15;
    const int bx = sid & 15;

    const _Float16* Bb = B + (size_t)b * NP * DD;
    const float* k2b = k2 + (size_t)b * NP;
    unsigned short* Cb = Kq + (size_t)b * TT * NP;

    __shared__ __attribute__((aligned(16))) _Float16 sA[4096], sB[4096];
    const int tid = threadIdx.x;
    const int lane = tid & 63;
    const int row0 = by * 128;   // t
    const int col0 = bx * 128;   // n
    const int wm = ((tid >> 7) & 1) * 64;
    const int wn = ((tid >> 6) & 1) * 64;
    f32x4 acc[4][4];
    zero_acc(acc);

    for (int k0 = 0; k0 < DD; k0 += 32) {
        __syncthreads();
        #pragma unroll
        for (int q = 0; q < 2; ++q) {
            int o = (tid + (q << 8)) << 4;
            int s = o >> 11;
            int r = (o & 2047) >> 4;
            gload16(A + (size_t)(row0 + r) * DD + k0 + s * 8, (char*)sA + o);
            gload16(Bb + (size_t)(col0 + r) * DD + k0 + s * 8, (char*)sB + o);
        }
        __syncthreads();
        frag_step_f16(sA, sB, lane, wm, wn, acc);
    }
    #pragma unroll
    for (int i = 0; i < 4; ++i)
        #pragma unroll
        for (int j = 0; j < 4; ++j) {
            int colg = col0 + wn + j * 16 + (lane & 15);
            float k2v = k2b[colg];
            int rowb = row0 + wm + i * 16 + ((lane >> 4) << 2);
            #pragma unroll
            for (int r = 0; r < 4; ++r) {
                float sq = q2[rowb + r] + k2v - 2.f * acc[i][j][r];
                float dist = sqrtf(fmaxf(sq, 0.f));
                Cb[(size_t)(rowb + r) * NP + colg] =
                    (unsigned short)(fminf(dist, 63.9f) * 1024.f + 0.5f);
            }
        }
}

// ---------------------------------------------------------------------------
// u update: u[b,n] = LOG_A - LSE_t( -dist[b,t,n] + v[b,t] )
// ---------------------------------------------------------------------------
__global__ __launch_bounds__(256) void u_update_q(
    const unsigned short* __restrict__ Kq, const float* __restrict__ vv,
    float* __restrict__ uu)
{
    const int b = blockIdx.y;
    const int lane = threadIdx.x & 63;
    const int p = threadIdx.x >> 6;
    const int n0 = blockIdx.x * 128;
    const unsigned* Kb = (const unsigned*)(Kq + (size_t)b * TT * NP + n0);
    const float* vb = vv + (size_t)b * TT;

    float m0 = -INFINITY, m1 = -INFINITY, s0 = 0.f, s1 = 0.f;
    const int t0 = p * (TT / 4);
    for (int tt = 0; tt < TT / 4; ++tt) {
        int t = t0 + tt;
        unsigned w = Kb[(size_t)t * (NP / 2) + lane];
        float vt = vb[t];
        float x0 = fmaf((float)(w & 0xFFFFu), -INV1024, vt);
        float x1 = fmaf((float)(w >> 16),     -INV1024, vt);
        float nm0 = fmaxf(m0, x0);
        s0 = s0 * __expf(m0 - nm0) + __expf(x0 - nm0); m0 = nm0;
        float nm1 = fmaxf(m1, x1);
        s1 = s1 * __expf(m1 - nm1) + __expf(x1 - nm1); m1 = nm1;
    }
    __shared__ float sm[4][128], ss[4][128];
    sm[p][2 * lane] = m0; sm[p][2 * lane + 1] = m1;
    ss[p][2 * lane] = s0; ss[p][2 * lane + 1] = s1;
    __syncthreads();
    if (p == 0) {
        #pragma unroll
        for (int q = 1; q < 4; ++q) {
            float a0 = sm[q][2 * lane], c0 = ss[q][2 * lane];
            float nm = fmaxf(m0, a0);
            s0 = s0 * __expf(m0 - nm) + c0 * __expf(a0 - nm); m0 = nm;
            float a1 = sm[q][2 * lane + 1], c1 = ss[q][2 * lane + 1];
            float nm1 = fmaxf(m1, a1);
            s1 = s1 * __expf(m1 - nm1) + c1 * __expf(a1 - nm1); m1 = nm1;
        }
        uu[(size_t)b * NP + n0 + 2 * lane]     = LOG_A - (m0 + __logf(s0));
        uu[(size_t)b * NP + n0 + 2 * lane + 1] = LOG_A - (m1 + __logf(s1));
    }
}

// ---------------------------------------------------------------------------
// v update: v[b,t] = -LSE_n( -dist[b,t,n] + u[b,n] )
// ---------------------------------------------------------------------------
__global__ __launch_bounds__(256) void v_update_q(
    const unsigned short* __restrict__ Kq, const float* __restrict__ uu,
    float* __restrict__ vv)
{
    const int b = blockIdx.y;
    const int t = blockIdx.x;
    const uint4* Kb = (const uint4*)(Kq + ((size_t)b * TT + t) * NP);
    const float* ub = uu + (size_t)b * NP;
    const int tid = threadIdx.x;

    uint4 w = Kb[tid];
    const int n0 = tid * 8;
    float4 u0 = *(const float4*)(ub + n0);
    float4 u1 = *(const float4*)(ub + n0 + 4);
    float x[8];
    x[0] = fmaf((float)(w.x & 0xFFFFu), -INV1024, u0.x);
    x[1] = fmaf((float)(w.x >> 16),     -INV1024, u0.y);
    x[2] = fmaf((float)(w.y & 0xFFFFu), -INV1024, u0.z);
    x[3] = fmaf((float)(w.y >> 16),     -INV1024, u0.w);
    x[4] = fmaf((float)(w.z & 0xFFFFu), -INV1024, u1.x);
    x[5] = fmaf((float)(w.z >> 16),     -INV1024, u1.y);
    x[6] = fmaf((float)(w.w & 0xFFFFu), -INV1024, u1.z);
    x[7] = fmaf((float)(w.w >> 16),     -INV1024, u1.w);
    float m = x[0];
    #pragma unroll
    for (int j = 1; j < 8; ++j) m = fmaxf(m, x[j]);
    float s = 0.f;
    #pragma unroll
    for (int j = 0; j < 8; ++j) s += __expf(x[j] - m);

    __shared__ float sm[256], ss[256];
    sm[tid] = m; ss[tid] = s;
    __syncthreads();
    for (int off = 128; off; off >>= 1) {
        if (tid < off) {
            float m1 = sm[tid], s1 = ss[tid];
            float m2 = sm[tid + off], s2 = ss[tid + off];
            float nm = fmaxf(m1, m2);
            ss[tid] = s1 * __expf(m1 - nm) + s2 * __expf(m2 - nm);
            sm[tid] = nm;
        }
        __syncthreads();
    }
    if (tid == 0) vv[(size_t)b * TT + t] = -(sm[0] + __logf(ss[0]));
}

// ---------------------------------------------------------------------------
// pi GEMM (NT, fp16 single-product): out[b,t,d] = sum_n exp(u+v-dist)*vpT[b,d,n]
// A = exp(...) decoded from uint16 Kq in regs -> f16 -> ds_write.
// B = vpT f16 [D][NP] via gload_lds. M=TT, N=DD, K=NP.
// 1-D grid, XCD-chunked swizzle: one batch per XCD (vpT_b 2MB L2-resident).
// ---------------------------------------------------------------------------
__global__ __launch_bounds__(256) void gemm_pi_f16(
    const unsigned short* __restrict__ Kq, const float* __restrict__ uu,
    const float* __restrict__ vv, const _Float16* __restrict__ B,
    float* __restrict__ out)
{
    const int bid = blockIdx.x;
    const int sid = ((bid & 7) << 6) | (bid >> 3);   // 512 blocks, 64/XCD
    const int b  = sid >> 6;
    const int by = (sid >> 2) & 15;
    const int bx = sid & 3;

    const unsigned short* Kb = Kq + (size_t)b * TT * NP;
    const float* ub = uu + (size_t)b * NP;
    const float* vb = vv + (size_t)b * TT;
    const _Float16* Bb = B + (size_t)b * DD * NP;
    float* Cb = out + (size_t)b * TT * DD;

    __shared__ __attribute__((aligned(16))) _Float16 sA[4096], sB[4096];
    const int tid = threadIdx.x;
    const int lane = tid & 63;
    const int row0 = by * 128;   // t
    const int col0 = bx * 128;   // d
    const int wm = ((tid >> 7) & 1) * 64;
    const int wn = ((tid >> 6) & 1) * 64;
    f32x4 acc[4][4];
    zero_acc(acc);

    for (int k0 = 0; k0 < NP; k0 += 32) {
        __syncthreads();
        #pragma unroll
        for (int q = 0; q < 2; ++q) {
            int o = (tid + (q << 8)) << 4;
            int s = o >> 11;
            int r = (o & 2047) >> 4;
            gload16(Bb + (size_t)(col0 + r) * NP + k0 + s * 8, (char*)sB + o);
            uint4 w = *(const uint4*)(Kb + (size_t)(row0 + r) * NP + k0 + s * 8);
            const float* us = ub + k0 + s * 8;
            float vr = vb[row0 + r];
            float4 u0 = *(const float4*)us;
            float4 u1 = *(const float4*)(us + 4);
            float xs[8];
            xs[0] = fmaf((float)(w.x & 0xFFFFu), -INV1024, u0.x + vr);
            xs[1] = fmaf((float)(w.x >> 16),     -INV1024, u0.y + vr);
            xs[2] = fmaf((float)(w.y & 0xFFFFu), -INV1024, u0.z + vr);
            xs[3] = fmaf((float)(w.y >> 16),     -INV1024, u0.w + vr);
            xs[4] = fmaf((float)(w.z & 0xFFFFu), -INV1024, u1.x + vr);
            xs[5] = fmaf((float)(w.z >> 16),     -INV1024, u1.y + vr);
            xs[6] = fmaf((float)(w.w & 0xFFFFu), -INV1024, u1.z + vr);
            xs[7] = fmaf((float)(w.w >> 16),     -INV1024, u1.w + vr);
            _Float16 hs[8];
            #pragma unroll
            for (int j = 0; j < 8; ++j) hs[j] = (_Float16)__expf(xs[j]);
            *(f16x8*)((char*)sA + o) = *(f16x8*)hs;
        }
        __syncthreads();
        frag_step_f16(sA, sB, lane, wm, wn, acc);
    }
    store_plain(Cb, DD, row0, col0, lane, wm, wn, acc);
}

// ---------------------------------------------------------------------------
extern "C" void kernel_launch(void* const* d_in, const int* in_sizes, int n_in,
                              void* d_out, int out_size, void* d_ws, size_t ws_size,
                              hipStream_t stream)
{
    const float* q  = (const float*)d_in[0];
    const float* k  = (const float*)d_in[1];
    const float* v  = (const float*)d_in[2];
    const float* Qw = (const float*)d_in[3];
    const float* Kw = (const float*)d_in[4];
    const float* Vw = (const float*)d_in[5];
    float* out = (float*)d_out;

    // ---- workspace: ~98.2 MiB ----
    char* base = (char*)d_ws;
    unsigned short* Kq = (unsigned short*)base;                // 64 MiB @ 0
    char* p2 = base + (size_t)BB * TT * NP * 2;
    _Float16* qpf = (_Float16*)p2; p2 += (size_t)TT * DD * 2;       //  2 MiB
    _Float16* kpf = (_Float16*)p2; p2 += (size_t)BB * NP * DD * 2;  // 16 MiB
    _Float16* vpt = (_Float16*)p2; p2 += (size_t)BB * DD * NP * 2;  // 16 MiB (vpT)
    float* q2 = (float*)p2; p2 += (size_t)TT * 4;
    float* k2 = (float*)p2; p2 += (size_t)BB * NP * 4;
    float* uu = (float*)p2; p2 += (size_t)BB * NP * 4;
    float* vv = (float*)p2; p2 += (size_t)BB * TT * 4;

    // temporaries aliased INSIDE the Kq region (dead before Kq is written):
    float* vp  = (float*)base;                                 // 32 MiB (v proj, fp32)
    short* wqh = (short*)(base + (size_t)33554432);            // 6 x 0.5 MiB
    short* wql = wqh + 262144;
    short* wkh = wql + 262144;
    short* wkl = wkh + 262144;
    short* wvh = wkl + 262144;
    short* wvl = wvh + 262144;

    dim3 blk(256);

    // Weights: transpose + hi/lo convert ([K][N] -> [N][K])
    transpose_hilo<<<dim3(8, 8, 1), blk, 0, stream>>>(Qw, wqh, wql, 512, 512);
    transpose_hilo<<<dim3(8, 8, 1), blk, 0, stream>>>(Kw, wkh, wkl, 512, 512);
    transpose_hilo<<<dim3(8, 8, 1), blk, 0, stream>>>(Vw, wvh, wvl, 512, 512);

    // Projections (split-bf16 core): q,k -> fp16; v -> fp32 (for transpose)
    gemm_nt_f32A<1><<<dim3(4, 16, 1), blk, 0, stream>>>(
        q, wqh, wql, nullptr, qpf, TT, DD, DD);
    gemm_nt_f32A<1><<<dim3(4, 128, 1), blk, 0, stream>>>(
        k, wkh, wkl, nullptr, kpf, BB * NP, DD, DD);
    gemm_nt_f32A<0><<<dim3(4, 128, 1), blk, 0, stream>>>(
        v, wvh, wvl, vp, nullptr, BB * NP, DD, DD);

    // Squared norms from fp16 (self-consistent with cost GEMM operands)
    rownorm_f16<<<dim3(TT / 4), blk, 0, stream>>>(qpf, q2, TT);
    rownorm_f16<<<dim3((BB * NP) / 4), blk, 0, stream>>>(kpf, k2, BB * NP);

    // vp -> transposed fp16
    transpose_f16<<<dim3(DD / 64, NP / 64, BB), blk, 0, stream>>>(vp, vpt, NP, DD);

    // Cost matrix -> Kq uint16 (overwrites aliased temporaries; dead now)
    gemm_cost_f16<<<dim3(2048), blk, 0, stream>>>(qpf, kpf, q2, k2, Kq);

    // Sinkhorn iterations (v starts at 0)
    hipMemsetAsync(vv, 0, (size_t)BB * TT * 4, stream);
    for (int it = 0; it < 5; ++it) {
        u_update_q<<<dim3(NP / 128, BB), blk, 0, stream>>>(Kq, vv, uu);
        v_update_q<<<dim3(TT, BB), blk, 0, stream>>>(Kq, uu, vv);
    }

    // out = exp(u+v-dist) @ vp (fused, fp16 single-product MFMA)
    gemm_pi_f16<<<dim3(512), blk, 0, stream>>>(Kq, uu, vv, vpt, out);
}

// Round 9
// 517.094 us; speedup vs baseline: 3.2531x; 1.4377x over previous
//
#include <hip/hip_runtime.h>
#include <math.h>

#define TT 2048   // tokens
#define NP 2048   // num params (N)
#define BB 8      // batch
#define DD 512    // d_model = kdim = vdim
#define TCH 8     // u-update T chunks

#define LOG_A (-7.6246189861593985f)  // -log(2048)
#define INV1024 (9.765625e-4f)

typedef __attribute__((ext_vector_type(8))) short bf16x8;
typedef __attribute__((ext_vector_type(8))) _Float16 f16x8;
typedef __attribute__((ext_vector_type(4))) float f32x4;

#define MFMA_BF16(a, b, c) __builtin_amdgcn_mfma_f32_16x16x32_bf16((a), (b), (c), 0, 0, 0)
#define MFMA_F16(a, b, c)  __builtin_amdgcn_mfma_f32_16x16x32_f16((a), (b), (c), 0, 0, 0)

// ---------------------------------------------------------------------------
// bf16 helpers (round-to-nearest-even) + hi/lo split
// ---------------------------------------------------------------------------
__device__ __forceinline__ unsigned short f2bf_rn(float x) {
    union { float f; unsigned u; } v; v.f = x;
    unsigned r = v.u + 0x7fffu + ((v.u >> 16) & 1u);
    return (unsigned short)(r >> 16);
}
__device__ __forceinline__ float bf2f(unsigned short h) {
    union { unsigned u; float f; } v; v.u = ((unsigned)h) << 16;
    return v.f;
}

// async global->LDS, 16B per lane (wave-uniform LDS base + lane*16, per-lane src)
__device__ __forceinline__ void gload16(const void* g, void* l) {
    __builtin_amdgcn_global_load_lds(
        (const __attribute__((address_space(1))) void*)g,
        (__attribute__((address_space(3))) void*)l, 16, 0, 0);
}

// ---------------------------------------------------------------------------
// LDS tile layout, "k-group-major": tile[s][r][8 elems], s = k-subgroup
// (0..3 => BK=32), r = row (0..127). Byte off = s*2048 + r*16.
// Conflict-free ds_read_b128 fragments.
// A-frag (16x16x32): lane holds A[m=lane%16][k=(lane/16)*8+j]
// B-frag:            lane holds B[k=(lane/16)*8+j][n=lane%16]  (B stored [N][K])
// C/D:               col=lane&15, row=(lane>>4)*4+reg   [m89-verified]
// ---------------------------------------------------------------------------
__device__ __forceinline__ void frag_step_bf16(
    const short* sAh, const short* sAl, const short* sBh, const short* sBl,
    int lane, int wm, int wn, f32x4 acc[4][4])
{
    const int sb = (lane >> 4) << 11;
    const int rl = (lane & 15) << 4;
    bf16x8 ah[4], al[4], bh[4], bl[4];
    #pragma unroll
    for (int i = 0; i < 4; ++i) {
        int ra = sb + ((wm + i * 16) << 4) + rl;
        ah[i] = *(const bf16x8*)((const char*)sAh + ra);
        al[i] = *(const bf16x8*)((const char*)sAl + ra);
        int rb = sb + ((wn + i * 16) << 4) + rl;
        bh[i] = *(const bf16x8*)((const char*)sBh + rb);
        bl[i] = *(const bf16x8*)((const char*)sBl + rb);
    }
    #pragma unroll
    for (int i = 0; i < 4; ++i)
        #pragma unroll
        for (int j = 0; j < 4; ++j) {
            acc[i][j] = MFMA_BF16(ah[i], bh[j], acc[i][j]);
            acc[i][j] = MFMA_BF16(ah[i], bl[j], acc[i][j]);
            acc[i][j] = MFMA_BF16(al[i], bh[j], acc[i][j]);
        }
}

__device__ __forceinline__ void frag_step_f16(
    const _Float16* sA, const _Float16* sB,
    int lane, int wm, int wn, f32x4 acc[4][4])
{
    const int sb = (lane >> 4) << 11;
    const int rl = (lane & 15) << 4;
    f16x8 a[4], b[4];
    #pragma unroll
    for (int i = 0; i < 4; ++i) {
        a[i] = *(const f16x8*)((const char*)sA + sb + ((wm + i * 16) << 4) + rl);
        b[i] = *(const f16x8*)((const char*)sB + sb + ((wn + i * 16) << 4) + rl);
    }
    #pragma unroll
    for (int i = 0; i < 4; ++i)
        #pragma unroll
        for (int j = 0; j < 4; ++j)
            acc[i][j] = MFMA_F16(a[i], b[j], acc[i][j]);
}

__device__ __forceinline__ void zero_acc(f32x4 acc[4][4]) {
    #pragma unroll
    for (int i = 0; i < 4; ++i)
        #pragma unroll
        for (int j = 0; j < 4; ++j)
            acc[i][j] = (f32x4){0.f, 0.f, 0.f, 0.f};
}

__device__ __forceinline__ void store_plain(
    float* C, int N, int row0, int col0, int lane, int wm, int wn, f32x4 acc[4][4])
{
    #pragma unroll
    for (int i = 0; i < 4; ++i)
        #pragma unroll
        for (int j = 0; j < 4; ++j) {
            int colg = col0 + wn + j * 16 + (lane & 15);
            int rowb = row0 + wm + i * 16 + ((lane >> 4) << 2);
            #pragma unroll
            for (int r = 0; r < 4; ++r)
                C[(size_t)(rowb + r) * N + colg] = acc[i][j][r];
        }
}

// ---------------------------------------------------------------------------
// Transpose + hi/lo bf16 convert (weights): X[R][C] fp32 -> [C][R] bf16 hi/lo.
// ---------------------------------------------------------------------------
__global__ __launch_bounds__(256) void transpose_hilo(
    const float* __restrict__ X, short* __restrict__ hiT, short* __restrict__ loT,
    int R, int C)
{
    const size_t zoff = (size_t)blockIdx.z * R * C;
    const float* Xb = X + zoff;
    short* hb = hiT + zoff;
    short* lb = loT + zoff;
    __shared__ float t[64][65];
    const int bx = blockIdx.x * 64;  // C base
    const int by = blockIdx.y * 64;  // R base
    const int tx = threadIdx.x & 63, ty = threadIdx.x >> 6;
    #pragma unroll
    for (int r = ty; r < 64; r += 4)
        t[r][tx] = Xb[(size_t)(by + r) * C + bx + tx];
    __syncthreads();
    #pragma unroll
    for (int r = ty; r < 64; r += 4) {
        float xv = t[tx][r];                       // X[by+tx][bx+r]
        unsigned short h = f2bf_rn(xv);
        size_t oo = (size_t)(bx + r) * R + by + tx;
        hb[oo] = (short)h;
        lb[oo] = (short)f2bf_rn(xv - bf2f(h));
    }
}

// ---------------------------------------------------------------------------
// Transpose to fp16 (vp): X[z][R][C] fp32 -> out[z][C][R] f16.
// ---------------------------------------------------------------------------
__global__ __launch_bounds__(256) void transpose_f16(
    const float* __restrict__ X, _Float16* __restrict__ oT, int R, int C)
{
    const size_t zoff = (size_t)blockIdx.z * R * C;
    const float* Xb = X + zoff;
    _Float16* ob = oT + zoff;
    __shared__ float t[64][65];
    const int bx = blockIdx.x * 64;  // C base
    const int by = blockIdx.y * 64;  // R base
    const int tx = threadIdx.x & 63, ty = threadIdx.x >> 6;
    #pragma unroll
    for (int r = ty; r < 64; r += 4)
        t[r][tx] = Xb[(size_t)(by + r) * C + bx + tx];
    __syncthreads();
    #pragma unroll
    for (int r = ty; r < 64; r += 4)
        ob[(size_t)(bx + r) * R + by + tx] = (_Float16)t[tx][r];
}

// ---------------------------------------------------------------------------
// Projection GEMM (NT, split bf16, fp32-grade): C = A[M,K] @ Bt[N,K]^T.
// OUT=0: fp32 out (vp). OUT=1: fp16 out (qp, kp).
// ---------------------------------------------------------------------------
template<int OUT>
__global__ __launch_bounds__(256) void gemm_nt_f32A(
    const float* __restrict__ A, const short* __restrict__ Bh,
    const short* __restrict__ Bl, float* __restrict__ Cf,
    _Float16* __restrict__ Ch, int M, int N, int K)
{
    __shared__ __attribute__((aligned(16))) short sAh[4096], sAl[4096], sBh[4096], sBl[4096];
    const int tid = threadIdx.x;
    const int lane = tid & 63;
    const int row0 = blockIdx.y * 128;
    const int col0 = blockIdx.x * 128;
    const int wm = ((tid >> 7) & 1) * 64;
    const int wn = ((tid >> 6) & 1) * 64;
    f32x4 acc[4][4];
    zero_acc(acc);

    for (int k0 = 0; k0 < K; k0 += 32) {
        __syncthreads();
        #pragma unroll
        for (int q = 0; q < 2; ++q) {
            int o = (tid + (q << 8)) << 4;     // byte offset in bf16 tile
            int s = o >> 11;
            int r = (o & 2047) >> 4;
            size_t gb = (size_t)(col0 + r) * K + k0 + s * 8;
            gload16(Bh + gb, (char*)sBh + o);
            gload16(Bl + gb, (char*)sBl + o);
            const float* src = A + (size_t)(row0 + r) * K + k0 + s * 8;
            float4 f0 = *(const float4*)src;
            float4 f1 = *(const float4*)(src + 4);
            float xs[8] = {f0.x, f0.y, f0.z, f0.w, f1.x, f1.y, f1.z, f1.w};
            short hs[8], ls[8];
            #pragma unroll
            for (int j = 0; j < 8; ++j) {
                unsigned short h = f2bf_rn(xs[j]);
                hs[j] = (short)h;
                ls[j] = (short)f2bf_rn(xs[j] - bf2f(h));
            }
            *(bf16x8*)((char*)sAh + o) = *(bf16x8*)hs;
            *(bf16x8*)((char*)sAl + o) = *(bf16x8*)ls;
        }
        __syncthreads();
        frag_step_bf16(sAh, sAl, sBh, sBl, lane, wm, wn, acc);
    }
    #pragma unroll
    for (int i = 0; i < 4; ++i)
        #pragma unroll
        for (int j = 0; j < 4; ++j) {
            int colg = col0 + wn + j * 16 + (lane & 15);
            int rowb = row0 + wm + i * 16 + ((lane >> 4) << 2);
            #pragma unroll
            for (int r = 0; r < 4; ++r) {
                size_t oo = (size_t)(rowb + r) * N + colg;
                float x = acc[i][j][r];
                if (OUT == 1) Ch[oo] = (_Float16)x;
                else          Cf[oo] = x;
            }
        }
}

// ---------------------------------------------------------------------------
// Row squared-norm from fp16: out[r] = sum_d x^2. One wave per row.
// ---------------------------------------------------------------------------
__global__ __launch_bounds__(256) void rownorm_f16(
    const _Float16* __restrict__ X, float* __restrict__ o, int rows)
{
    int w = blockIdx.x * 4 + (threadIdx.x >> 6);
    int lane = threadIdx.x & 63;
    if (w >= rows) return;
    f16x8 v = *(const f16x8*)(X + (size_t)w * DD + lane * 8);
    float s = 0.f;
    #pragma unroll
    for (int j = 0; j < 8; ++j) {
        float x = (float)v[j];
        s = fmaf(x, x, s);
    }
    #pragma unroll
    for (int off = 32; off; off >>= 1) s += __shfl_down(s, off, 64);
    if (lane == 0) o[w] = s;
}

// ---------------------------------------------------------------------------
// Cost GEMM (NT, fp16, 2-phase prefetch): S = qp @ kp^T per batch, epilogue
//   dist = sqrt(max(q2[t] + k2[b,n] - 2 S, 0));  Kq = round(dist*1024) uint16
// 1-D grid, XCD-chunked swizzle: one batch per XCD.
// ---------------------------------------------------------------------------
__global__ __launch_bounds__(256) void gemm_cost_f16(
    const _Float16* __restrict__ A, const _Float16* __restrict__ B,
    const float* __restrict__ q2, const float* __restrict__ k2,
    unsigned short* __restrict__ Kq)
{
    const int bid = blockIdx.x;
    const int sid = ((bid & 7) << 8) | (bid >> 3);
    const int b  = sid >> 8;
    const int by = (sid >> 4) & 15;
    const int bx = sid & 15;

    const _Float16* Bb = B + (size_t)b * NP * DD;
    const float* k2b = k2 + (size_t)b * NP;
    unsigned short* Cb = Kq + (size_t)b * TT * NP;

    __shared__ __attribute__((aligned(16))) _Float16 sA[2][4096], sB[2][4096];
    const int tid = threadIdx.x;
    const int lane = tid & 63;
    const int row0 = by * 128;   // t
    const int col0 = bx * 128;   // n
    const int wm = ((tid >> 7) & 1) * 64;
    const int wn = ((tid >> 6) & 1) * 64;
    f32x4 acc[4][4];
    zero_acc(acc);

    auto STAGE = [&](int buf, int k0) {
        #pragma unroll
        for (int q = 0; q < 2; ++q) {
            int o = (tid + (q << 8)) << 4;
            int s = o >> 11;
            int r = (o & 2047) >> 4;
            gload16(A + (size_t)(row0 + r) * DD + k0 + s * 8, (char*)&sA[buf][0] + o);
            gload16(Bb + (size_t)(col0 + r) * DD + k0 + s * 8, (char*)&sB[buf][0] + o);
        }
    };

    STAGE(0, 0);
    __syncthreads();                 // drains prologue stage (vmcnt 0)
    int cur = 0;
    for (int k0 = 0; k0 < DD; k0 += 32) {
        if (k0 + 32 < DD) STAGE(cur ^ 1, k0 + 32);   // prefetch next tile
        frag_step_f16(&sA[cur][0], &sB[cur][0], lane, wm, wn, acc);
        __syncthreads();             // waits vmcnt(0): prefetched tile landed
        cur ^= 1;
    }
    #pragma unroll
    for (int i = 0; i < 4; ++i)
        #pragma unroll
        for (int j = 0; j < 4; ++j) {
            int colg = col0 + wn + j * 16 + (lane & 15);
            float k2v = k2b[colg];
            int rowb = row0 + wm + i * 16 + ((lane >> 4) << 2);
            #pragma unroll
            for (int r = 0; r < 4; ++r) {
                float sq = q2[rowb + r] + k2v - 2.f * acc[i][j][r];
                float dist = sqrtf(fmaxf(sq, 0.f));
                Cb[(size_t)(rowb + r) * NP + colg] =
                    (unsigned short)(fminf(dist, 63.9f) * 1024.f + 0.5f);
            }
        }
}

// ---------------------------------------------------------------------------
// u partials: per (n-block, T-chunk, b): online (m,s) over 256 rows.
// Grid (NP/128, TCH, BB) = 1024 blocks (4/CU).
// ---------------------------------------------------------------------------
__global__ __launch_bounds__(256) void u_part(
    const unsigned short* __restrict__ Kq, const float* __restrict__ vv,
    float* __restrict__ pm, float* __restrict__ ps)
{
    const int b = blockIdx.z;
    const int tch = blockIdx.y;
    const int lane = threadIdx.x & 63;
    const int p = threadIdx.x >> 6;
    const int n0 = blockIdx.x * 128;
    const unsigned* Kb = (const unsigned*)(Kq + (size_t)b * TT * NP + n0);
    const float* vb = vv + (size_t)b * TT;

    float m0 = -INFINITY, m1 = -INFINITY, s0 = 0.f, s1 = 0.f;
    const int t0 = tch * (TT / TCH) + p * (TT / TCH / 4);
    for (int tt = 0; tt < TT / TCH / 4; ++tt) {       // 64 rows
        int t = t0 + tt;
        unsigned w = Kb[(size_t)t * (NP / 2) + lane];
        float vt = vb[t];
        float x0 = fmaf((float)(w & 0xFFFFu), -INV1024, vt);
        float x1 = fmaf((float)(w >> 16),     -INV1024, vt);
        float nm0 = fmaxf(m0, x0);
        s0 = s0 * __expf(m0 - nm0) + __expf(x0 - nm0); m0 = nm0;
        float nm1 = fmaxf(m1, x1);
        s1 = s1 * __expf(m1 - nm1) + __expf(x1 - nm1); m1 = nm1;
    }
    __shared__ float smm[4][128], sss[4][128];
    smm[p][2 * lane] = m0; smm[p][2 * lane + 1] = m1;
    sss[p][2 * lane] = s0; sss[p][2 * lane + 1] = s1;
    __syncthreads();
    if (p == 0) {
        #pragma unroll
        for (int q = 1; q < 4; ++q) {
            float a0 = smm[q][2 * lane], c0 = sss[q][2 * lane];
            float nm = fmaxf(m0, a0);
            s0 = s0 * __expf(m0 - nm) + c0 * __expf(a0 - nm); m0 = nm;
            float a1 = smm[q][2 * lane + 1], c1 = sss[q][2 * lane + 1];
            float nm1 = fmaxf(m1, a1);
            s1 = s1 * __expf(m1 - nm1) + c1 * __expf(a1 - nm1); m1 = nm1;
        }
        size_t o = ((size_t)b * TCH + tch) * NP + n0 + 2 * lane;
        pm[o] = m0; ps[o] = s0;
        pm[o + 1] = m1; ps[o + 1] = s1;
    }
}

// ---------------------------------------------------------------------------
// u combine: u[b,n] = LOG_A - merge(TCH partials). 64 blocks.
// ---------------------------------------------------------------------------
__global__ __launch_bounds__(256) void u_combine(
    const float* __restrict__ pm, const float* __restrict__ ps,
    float* __restrict__ uu)
{
    int gid = blockIdx.x * 256 + threadIdx.x;     // over BB*NP
    int b = gid >> 11;
    int n = gid & (NP - 1);
    float m = -INFINITY, s = 0.f;
    #pragma unroll
    for (int c = 0; c < TCH; ++c) {
        size_t o = ((size_t)b * TCH + c) * NP + n;
        float m2 = pm[o], s2 = ps[o];
        float nm = fmaxf(m, m2);
        s = s * __expf(m - nm) + s2 * __expf(m2 - nm);
        m = nm;
    }
    uu[gid] = LOG_A - (m + __logf(s));
}

// ---------------------------------------------------------------------------
// v update: v[b,t] = -LSE_n( -dist[b,t,n] + u[b,n] ).
// WP=true (final iteration): also write P[b,t,n] = exp(x + v) as f16
// (whole decoded row is already in registers).
// ---------------------------------------------------------------------------
template<bool WP>
__global__ __launch_bounds__(256) void v_update_q(
    const unsigned short* __restrict__ Kq, const float* __restrict__ uu,
    float* __restrict__ vv, _Float16* __restrict__ P)
{
    const int b = blockIdx.y;
    const int t = blockIdx.x;
    const uint4* Kb = (const uint4*)(Kq + ((size_t)b * TT + t) * NP);
    const float* ub = uu + (size_t)b * NP;
    const int tid = threadIdx.x;

    uint4 w = Kb[tid];
    const int n0 = tid * 8;
    float4 u0 = *(const float4*)(ub + n0);
    float4 u1 = *(const float4*)(ub + n0 + 4);
    float x[8];
    x[0] = fmaf((float)(w.x & 0xFFFFu), -INV1024, u0.x);
    x[1] = fmaf((float)(w.x >> 16),     -INV1024, u0.y);
    x[2] = fmaf((float)(w.y & 0xFFFFu), -INV1024, u0.z);
    x[3] = fmaf((float)(w.y >> 16),     -INV1024, u0.w);
    x[4] = fmaf((float)(w.z & 0xFFFFu), -INV1024, u1.x);
    x[5] = fmaf((float)(w.z >> 16),     -INV1024, u1.y);
    x[6] = fmaf((float)(w.w & 0xFFFFu), -INV1024, u1.z);
    x[7] = fmaf((float)(w.w >> 16),     -INV1024, u1.w);
    float m = x[0];
    #pragma unroll
    for (int j = 1; j < 8; ++j) m = fmaxf(m, x[j]);
    float s = 0.f;
    #pragma unroll
    for (int j = 0; j < 8; ++j) s += __expf(x[j] - m);

    __shared__ float sm[256], ss[256];
    sm[tid] = m; ss[tid] = s;
    __syncthreads();
    for (int off = 128; off; off >>= 1) {
        if (tid < off) {
            float m1 = sm[tid], s1 = ss[tid];
            float m2 = sm[tid + off], s2 = ss[tid + off];
            float nm = fmaxf(m1, m2);
            ss[tid] = s1 * __expf(m1 - nm) + s2 * __expf(m2 - nm);
            sm[tid] = nm;
        }
        __syncthreads();
    }
    float vt = -(sm[0] + __logf(ss[0]));
    if (tid == 0) vv[(size_t)b * TT + t] = vt;
    if (WP) {
        _Float16 hp[8];
        #pragma unroll
        for (int j = 0; j < 8; ++j) hp[j] = (_Float16)__expf(x[j] + vt);
        *(f16x8*)(P + ((size_t)b * TT + t) * NP + n0) = *(f16x8*)hp;
    }
}

// ---------------------------------------------------------------------------
// pi GEMM (NT, pure fp16, 2-phase prefetch):
//   out[b,t,d] = sum_n P[b,t,n] * vpT[b,d,n]
// M=TT, N=DD, K=NP. 1-D grid, XCD-chunked swizzle (one batch per XCD).
// ---------------------------------------------------------------------------
__global__ __launch_bounds__(256) void gemm_pi_f16(
    const _Float16* __restrict__ P, const _Float16* __restrict__ B,
    float* __restrict__ out)
{
    const int bid = blockIdx.x;
    const int sid = ((bid & 7) << 6) | (bid >> 3);   // 512 blocks, 64/XCD
    const int b  = sid >> 6;
    const int by = (sid >> 2) & 15;
    const int bx = sid & 3;

    const _Float16* Pb = P + (size_t)b * TT * NP;
    const _Float16* Bb = B + (size_t)b * DD * NP;
    float* Cb = out + (size_t)b * TT * DD;

    __shared__ __attribute__((aligned(16))) _Float16 sA[2][4096], sB[2][4096];
    const int tid = threadIdx.x;
    const int lane = tid & 63;
    const int row0 = by * 128;   // t
    const int col0 = bx * 128;   // d
    const int wm = ((tid >> 7) & 1) * 64;
    const int wn = ((tid >> 6) & 1) * 64;
    f32x4 acc[4][4];
    zero_acc(acc);

    auto STAGE = [&](int buf, int k0) {
        #pragma unroll
        for (int q = 0; q < 2; ++q) {
            int o = (tid + (q << 8)) << 4;
            int s = o >> 11;
            int r = (o & 2047) >> 4;
            gload16(Pb + (size_t)(row0 + r) * NP + k0 + s * 8, (char*)&sA[buf][0] + o);
            gload16(Bb + (size_t)(col0 + r) * NP + k0 + s * 8, (char*)&sB[buf][0] + o);
        }
    };

    STAGE(0, 0);
    __syncthreads();
    int cur = 0;
    for (int k0 = 0; k0 < NP; k0 += 32) {
        if (k0 + 32 < NP) STAGE(cur ^ 1, k0 + 32);
        frag_step_f16(&sA[cur][0], &sB[cur][0], lane, wm, wn, acc);
        __syncthreads();
        cur ^= 1;
    }
    store_plain(Cb, DD, row0, col0, lane, wm, wn, acc);
}

// ---------------------------------------------------------------------------
extern "C" void kernel_launch(void* const* d_in, const int* in_sizes, int n_in,
                              void* d_out, int out_size, void* d_ws, size_t ws_size,
                              hipStream_t stream)
{
    const float* q  = (const float*)d_in[0];
    const float* k  = (const float*)d_in[1];
    const float* v  = (const float*)d_in[2];
    const float* Qw = (const float*)d_in[3];
    const float* Kw = (const float*)d_in[4];
    const float* Vw = (const float*)d_in[5];
    float* out = (float*)d_out;

    // ---- workspace: ~131.5 MiB ----
    char* base = (char*)d_ws;
    unsigned short* Kq = (unsigned short*)base;                // 64 MiB @ 0
    char* p2 = base + (size_t)BB * TT * NP * 2;
    _Float16* P   = (_Float16*)p2; p2 += (size_t)BB * TT * NP * 2;  // 32 MiB
    _Float16* qpf = (_Float16*)p2; p2 += (size_t)TT * DD * 2;       //  2 MiB
    _Float16* kpf = (_Float16*)p2; p2 += (size_t)BB * NP * DD * 2;  // 16 MiB
    _Float16* vpt = (_Float16*)p2; p2 += (size_t)BB * DD * NP * 2;  // 16 MiB (vpT)
    float* q2 = (float*)p2; p2 += (size_t)TT * 4;
    float* k2 = (float*)p2; p2 += (size_t)BB * NP * 4;
    float* uu = (float*)p2; p2 += (size_t)BB * NP * 4;
    float* vv = (float*)p2; p2 += (size_t)BB * TT * 4;
    float* pm = (float*)p2; p2 += (size_t)BB * TCH * NP * 4;   // 512 KiB
    float* ps = (float*)p2; p2 += (size_t)BB * TCH * NP * 4;   // 512 KiB

    // temporaries aliased INSIDE the Kq region (dead before Kq is written):
    float* vp  = (float*)base;                                 // 32 MiB (v proj, fp32)
    short* wqh = (short*)(base + (size_t)33554432);            // 6 x 0.5 MiB
    short* wql = wqh + 262144;
    short* wkh = wql + 262144;
    short* wkl = wkh + 262144;
    short* wvh = wkl + 262144;
    short* wvl = wvh + 262144;

    dim3 blk(256);

    // Weights: transpose + hi/lo convert ([K][N] -> [N][K])
    transpose_hilo<<<dim3(8, 8, 1), blk, 0, stream>>>(Qw, wqh, wql, 512, 512);
    transpose_hilo<<<dim3(8, 8, 1), blk, 0, stream>>>(Kw, wkh, wkl, 512, 512);
    transpose_hilo<<<dim3(8, 8, 1), blk, 0, stream>>>(Vw, wvh, wvl, 512, 512);

    // Projections (split-bf16 core): q,k -> fp16; v -> fp32 (for transpose)
    gemm_nt_f32A<1><<<dim3(4, 16, 1), blk, 0, stream>>>(
        q, wqh, wql, nullptr, qpf, TT, DD, DD);
    gemm_nt_f32A<1><<<dim3(4, 128, 1), blk, 0, stream>>>(
        k, wkh, wkl, nullptr, kpf, BB * NP, DD, DD);
    gemm_nt_f32A<0><<<dim3(4, 128, 1), blk, 0, stream>>>(
        v, wvh, wvl, vp, nullptr, BB * NP, DD, DD);

    // Squared norms from fp16 (self-consistent with cost GEMM operands)
    rownorm_f16<<<dim3(TT / 4), blk, 0, stream>>>(qpf, q2, TT);
    rownorm_f16<<<dim3((BB * NP) / 4), blk, 0, stream>>>(kpf, k2, BB * NP);

    // vp -> transposed fp16
    transpose_f16<<<dim3(DD / 64, NP / 64, BB), blk, 0, stream>>>(vp, vpt, NP, DD);

    // Cost matrix -> Kq uint16 (overwrites aliased temporaries; dead now)
    gemm_cost_f16<<<dim3(2048), blk, 0, stream>>>(qpf, kpf, q2, k2, Kq);

    // Sinkhorn iterations (v starts at 0); final v-update also emits P (f16)
    hipMemsetAsync(vv, 0, (size_t)BB * TT * 4, stream);
    for (int it = 0; it < 5; ++it) {
        u_part<<<dim3(NP / 128, TCH, BB), blk, 0, stream>>>(Kq, vv, pm, ps);
        u_combine<<<dim3(BB * NP / 256), blk, 0, stream>>>(pm, ps, uu);
        if (it < 4)
            v_update_q<false><<<dim3(TT, BB), blk, 0, stream>>>(Kq, uu, vv, nullptr);
        else
            v_update_q<true><<<dim3(TT, BB), blk, 0, stream>>>(Kq, uu, vv, P);
    }

    // out = P @ vp (pure fp16 MFMA, 2-phase prefetch)
    gemm_pi_f16<<<dim3(512), blk, 0, stream>>>(P, vpt, out);
}

// Round 10
// 457.994 us; speedup vs baseline: 3.6729x; 1.1290x over previous
//
#include <hip/hip_runtime.h>
#include <math.h>

#define TT 2048   // tokens
#define NP 2048   // num params (N)
#define BB 8      // batch
#define DD 512    // d_model = kdim = vdim
#define TCH 8     // u-update T chunks

#define LOG_A (-7.6246189861593985f)  // -log(2048)
#define CC 30.0f                       // E = exp(CC - dist) shift
#define E30 1.0686475e13f              // exp(30)

typedef __attribute__((ext_vector_type(8))) short bf16x8;
typedef __attribute__((ext_vector_type(8))) _Float16 f16x8;
typedef __attribute__((ext_vector_type(4))) _Float16 f16x4;
typedef __attribute__((ext_vector_type(4))) float f32x4;

#define MFMA_BF16(a, b, c) __builtin_amdgcn_mfma_f32_32x32x16_bf16  // (unused guard)
#undef MFMA_BF16
#define MFMA_BF16(a, b, c) __builtin_amdgcn_mfma_f32_16x16x32_bf16((a), (b), (c), 0, 0, 0)
#define MFMA_F16(a, b, c)  __builtin_amdgcn_mfma_f32_16x16x32_f16((a), (b), (c), 0, 0, 0)

// ---------------------------------------------------------------------------
// helpers
// ---------------------------------------------------------------------------
__device__ __forceinline__ unsigned short f2bf_rn(float x) {
    union { float f; unsigned u; } v; v.f = x;
    unsigned r = v.u + 0x7fffu + ((v.u >> 16) & 1u);
    return (unsigned short)(r >> 16);
}
__device__ __forceinline__ float bf2f(unsigned short h) {
    union { unsigned u; float f; } v; v.u = ((unsigned)h) << 16;
    return v.f;
}
__device__ __forceinline__ float f16u2f(unsigned short u) {
    union { unsigned short s; _Float16 h; } v; v.s = u;
    return (float)v.h;
}

// async global->LDS, 16B per lane (wave-uniform LDS base + lane*16, per-lane src)
__device__ __forceinline__ void gload16(const void* g, void* l) {
    __builtin_amdgcn_global_load_lds(
        (const __attribute__((address_space(1))) void*)g,
        (__attribute__((address_space(3))) void*)l, 16, 0, 0);
}

// ---------------------------------------------------------------------------
// LDS tile layout, "k-group-major": tile[s][r][8 elems], s = k-subgroup
// (0..3 => BK=32), r = row (0..127). Byte off = s*2048 + r*16.
// A-frag (16x16x32): lane holds A[m=lane%16][k=(lane/16)*8+j]
// B-frag:            lane holds B[k=(lane/16)*8+j][n=lane%16]  (B stored [N][K])
// C/D:               col=lane&15, row=(lane>>4)*4+reg   [m89-verified]
// ---------------------------------------------------------------------------
__device__ __forceinline__ void frag_step_bf16(
    const short* sAh, const short* sAl, const short* sBh, const short* sBl,
    int lane, int wm, int wn, f32x4 acc[4][4])
{
    const int sb = (lane >> 4) << 11;
    const int rl = (lane & 15) << 4;
    bf16x8 ah[4], al[4], bh[4], bl[4];
    #pragma unroll
    for (int i = 0; i < 4; ++i) {
        int ra = sb + ((wm + i * 16) << 4) + rl;
        ah[i] = *(const bf16x8*)((const char*)sAh + ra);
        al[i] = *(const bf16x8*)((const char*)sAl + ra);
        int rb = sb + ((wn + i * 16) << 4) + rl;
        bh[i] = *(const bf16x8*)((const char*)sBh + rb);
        bl[i] = *(const bf16x8*)((const char*)sBl + rb);
    }
    #pragma unroll
    for (int i = 0; i < 4; ++i)
        #pragma unroll
        for (int j = 0; j < 4; ++j) {
            acc[i][j] = MFMA_BF16(ah[i], bh[j], acc[i][j]);
            acc[i][j] = MFMA_BF16(ah[i], bl[j], acc[i][j]);
            acc[i][j] = MFMA_BF16(al[i], bh[j], acc[i][j]);
        }
}

__device__ __forceinline__ void frag_step_f16(
    const _Float16* sA, const _Float16* sB,
    int lane, int wm, int wn, f32x4 acc[4][4])
{
    const int sb = (lane >> 4) << 11;
    const int rl = (lane & 15) << 4;
    f16x8 a[4], b[4];
    #pragma unroll
    for (int i = 0; i < 4; ++i) {
        a[i] = *(const f16x8*)((const char*)sA + sb + ((wm + i * 16) << 4) + rl);
        b[i] = *(const f16x8*)((const char*)sB + sb + ((wn + i * 16) << 4) + rl);
    }
    #pragma unroll
    for (int i = 0; i < 4; ++i)
        #pragma unroll
        for (int j = 0; j < 4; ++j)
            acc[i][j] = MFMA_F16(a[i], b[j], acc[i][j]);
}

__device__ __forceinline__ void zero_acc(f32x4 acc[4][4]) {
    #pragma unroll
    for (int i = 0; i < 4; ++i)
        #pragma unroll
        for (int j = 0; j < 4; ++j)
            acc[i][j] = (f32x4){0.f, 0.f, 0.f, 0.f};
}

__device__ __forceinline__ void store_plain(
    float* C, int N, int row0, int col0, int lane, int wm, int wn, f32x4 acc[4][4])
{
    #pragma unroll
    for (int i = 0; i < 4; ++i)
        #pragma unroll
        for (int j = 0; j < 4; ++j) {
            int colg = col0 + wn + j * 16 + (lane & 15);
            int rowb = row0 + wm + i * 16 + ((lane >> 4) << 2);
            #pragma unroll
            for (int r = 0; r < 4; ++r)
                C[(size_t)(rowb + r) * N + colg] = acc[i][j][r];
        }
}

// ---------------------------------------------------------------------------
// Transpose + hi/lo bf16 convert (weights): X[R][C] fp32 -> [C][R] bf16 hi/lo.
// ---------------------------------------------------------------------------
__global__ __launch_bounds__(256) void transpose_hilo(
    const float* __restrict__ X, short* __restrict__ hiT, short* __restrict__ loT,
    int R, int C)
{
    const size_t zoff = (size_t)blockIdx.z * R * C;
    const float* Xb = X + zoff;
    short* hb = hiT + zoff;
    short* lb = loT + zoff;
    __shared__ float t[64][65];
    const int bx = blockIdx.x * 64;  // C base
    const int by = blockIdx.y * 64;  // R base
    const int tx = threadIdx.x & 63, ty = threadIdx.x >> 6;
    #pragma unroll
    for (int r = ty; r < 64; r += 4)
        t[r][tx] = Xb[(size_t)(by + r) * C + bx + tx];
    __syncthreads();
    #pragma unroll
    for (int r = ty; r < 64; r += 4) {
        float xv = t[tx][r];                       // X[by+tx][bx+r]
        unsigned short h = f2bf_rn(xv);
        size_t oo = (size_t)(bx + r) * R + by + tx;
        hb[oo] = (short)h;
        lb[oo] = (short)f2bf_rn(xv - bf2f(h));
    }
}

// ---------------------------------------------------------------------------
// Projection GEMM (NT, split bf16, fp32-grade): C = A[M,K] @ Bt[N,K]^T.
// OUT=1: f16 out, row-major [M][N] (qp, kp).
// OUT=2: f16 out, per-batch transposed [b][N][rows-within-batch] (vpT direct).
// ---------------------------------------------------------------------------
template<int OUT>
__global__ __launch_bounds__(256) void gemm_nt_f32A(
    const float* __restrict__ A, const short* __restrict__ Bh,
    const short* __restrict__ Bl, _Float16* __restrict__ C,
    int M, int N, int K)
{
    __shared__ __attribute__((aligned(16))) short sAh[4096], sAl[4096], sBh[4096], sBl[4096];
    const int tid = threadIdx.x;
    const int lane = tid & 63;
    const int row0 = blockIdx.y * 128;
    const int col0 = blockIdx.x * 128;
    const int wm = ((tid >> 7) & 1) * 64;
    const int wn = ((tid >> 6) & 1) * 64;
    f32x4 acc[4][4];
    zero_acc(acc);

    for (int k0 = 0; k0 < K; k0 += 32) {
        __syncthreads();
        #pragma unroll
        for (int q = 0; q < 2; ++q) {
            int o = (tid + (q << 8)) << 4;     // byte offset in bf16 tile
            int s = o >> 11;
            int r = (o & 2047) >> 4;
            size_t gb = (size_t)(col0 + r) * K + k0 + s * 8;
            gload16(Bh + gb, (char*)sBh + o);
            gload16(Bl + gb, (char*)sBl + o);
            const float* src = A + (size_t)(row0 + r) * K + k0 + s * 8;
            float4 f0 = *(const float4*)src;
            float4 f1 = *(const float4*)(src + 4);
            float xs[8] = {f0.x, f0.y, f0.z, f0.w, f1.x, f1.y, f1.z, f1.w};
            short hs[8], ls[8];
            #pragma unroll
            for (int j = 0; j < 8; ++j) {
                unsigned short h = f2bf_rn(xs[j]);
                hs[j] = (short)h;
                ls[j] = (short)f2bf_rn(xs[j] - bf2f(h));
            }
            *(bf16x8*)((char*)sAh + o) = *(bf16x8*)hs;
            *(bf16x8*)((char*)sAl + o) = *(bf16x8*)ls;
        }
        __syncthreads();
        frag_step_bf16(sAh, sAl, sBh, sBl, lane, wm, wn, acc);
    }
    #pragma unroll
    for (int i = 0; i < 4; ++i)
        #pragma unroll
        for (int j = 0; j < 4; ++j) {
            int colg = col0 + wn + j * 16 + (lane & 15);
            int rowb = row0 + wm + i * 16 + ((lane >> 4) << 2);
            if (OUT == 1) {
                #pragma unroll
                for (int r = 0; r < 4; ++r)
                    C[(size_t)(rowb + r) * N + colg] = (_Float16)acc[i][j][r];
            } else {
                // transposed, per-batch: vpt[b][colg][n], n = row within batch.
                int b = rowb >> 11;
                int n0 = rowb & (NP - 1);
                _Float16 h4[4];
                #pragma unroll
                for (int r = 0; r < 4; ++r) h4[r] = (_Float16)acc[i][j][r];
                *(f16x4*)(C + (size_t)b * DD * NP + (size_t)colg * NP + n0) =
                    *(f16x4*)h4;
            }
        }
}

// ---------------------------------------------------------------------------
// Row squared-norm from fp16: out[r] = sum_d x^2. One wave per row.
// ---------------------------------------------------------------------------
__global__ __launch_bounds__(256) void rownorm_f16(
    const _Float16* __restrict__ X, float* __restrict__ o, int rows)
{
    int w = blockIdx.x * 4 + (threadIdx.x >> 6);
    int lane = threadIdx.x & 63;
    if (w >= rows) return;
    f16x8 v = *(const f16x8*)(X + (size_t)w * DD + lane * 8);
    float s = 0.f;
    #pragma unroll
    for (int j = 0; j < 8; ++j) {
        float x = (float)v[j];
        s = fmaf(x, x, s);
    }
    #pragma unroll
    for (int off = 32; off; off >>= 1) s += __shfl_down(s, off, 64);
    if (lane == 0) o[w] = s;
}

// ---------------------------------------------------------------------------
// Cost GEMM (NT, fp16, 2-phase prefetch): S = qp @ kp^T per batch, epilogue
//   dist = sqrt(max(q2+k2-2S,0));  E16 = f16(exp(CC - dist))  [clamped]
// 1-D grid, XCD-chunked swizzle: one batch per XCD.
// ---------------------------------------------------------------------------
__global__ __launch_bounds__(256) void gemm_cost_f16(
    const _Float16* __restrict__ A, const _Float16* __restrict__ B,
    const float* __restrict__ q2, const float* __restrict__ k2,
    _Float16* __restrict__ E)
{
    const int bid = blockIdx.x;
    const int sid = ((bid & 7) << 8) | (bid >> 3);
    const int b  = sid >> 8;
    const int by = (sid >> 4) & 15;
    const int bx = sid & 15;

    const _Float16* Bb = B + (size_t)b * NP * DD;
    const float* k2b = k2 + (size_t)b * NP;
    _Float16* Cb = E + (size_t)b * TT * NP;

    __shared__ __attribute__((aligned(16))) _Float16 sA[2][4096], sB[2][4096];
    const int tid = threadIdx.x;
    const int lane = tid & 63;
    const int row0 = by * 128;   // t
    const int col0 = bx * 128;   // n
    const int wm = ((tid >> 7) & 1) * 64;
    const int wn = ((tid >> 6) & 1) * 64;
    f32x4 acc[4][4];
    zero_acc(acc);

    auto STAGE = [&](int buf, int k0) {
        #pragma unroll
        for (int q = 0; q < 2; ++q) {
            int o = (tid + (q << 8)) << 4;
            int s = o >> 11;
            int r = (o & 2047) >> 4;
            gload16(A + (size_t)(row0 + r) * DD + k0 + s * 8, (char*)&sA[buf][0] + o);
            gload16(Bb + (size_t)(col0 + r) * DD + k0 + s * 8, (char*)&sB[buf][0] + o);
        }
    };

    STAGE(0, 0);
    __syncthreads();
    int cur = 0;
    for (int k0 = 0; k0 < DD; k0 += 32) {
        if (k0 + 32 < DD) STAGE(cur ^ 1, k0 + 32);
        frag_step_f16(&sA[cur][0], &sB[cur][0], lane, wm, wn, acc);
        __syncthreads();
        cur ^= 1;
    }
    #pragma unroll
    for (int i = 0; i < 4; ++i)
        #pragma unroll
        for (int j = 0; j < 4; ++j) {
            int colg = col0 + wn + j * 16 + (lane & 15);
            float k2v = k2b[colg];
            int rowb = row0 + wm + i * 16 + ((lane >> 4) << 2);
            #pragma unroll
            for (int r = 0; r < 4; ++r) {
                float sq = q2[rowb + r] + k2v - 2.f * acc[i][j][r];
                float dist = sqrtf(fmaxf(sq, 0.f));
                float e = fminf(__expf(CC - dist), 60000.f);
                Cb[(size_t)(rowb + r) * NP + colg] = (_Float16)e;
            }
        }
}

// ---------------------------------------------------------------------------
// Y init: Y = 1 (v = 0)
// ---------------------------------------------------------------------------
__global__ __launch_bounds__(256) void init_ones(float* __restrict__ Y)
{
    Y[blockIdx.x * 256 + threadIdx.x] = 1.0f;
}

// ---------------------------------------------------------------------------
// u partials: ps[b,tch,n] = sum over 256 rows of E[t,n] * Y[t].
// Pure fmaf — no exp/max. Grid (NP/128, TCH, BB) = 1024 blocks.
// ---------------------------------------------------------------------------
__global__ __launch_bounds__(256) void u_part(
    const _Float16* __restrict__ E, const float* __restrict__ Y,
    float* __restrict__ ps)
{
    const int b = blockIdx.z;
    const int tch = blockIdx.y;
    const int lane = threadIdx.x & 63;
    const int p = threadIdx.x >> 6;
    const int n0 = blockIdx.x * 128;
    const unsigned* Eb = (const unsigned*)(E + (size_t)b * TT * NP + n0);
    const float* Yb = Y + (size_t)b * TT;

    float s0 = 0.f, s1 = 0.f;
    const int t0 = tch * (TT / TCH) + p * (TT / TCH / 4);
    for (int tt = 0; tt < TT / TCH / 4; ++tt) {       // 64 rows
        int t = t0 + tt;
        unsigned w = Eb[(size_t)t * (NP / 2) + lane];
        float yv = Yb[t];
        s0 = fmaf(f16u2f((unsigned short)(w & 0xFFFFu)), yv, s0);
        s1 = fmaf(f16u2f((unsigned short)(w >> 16)),     yv, s1);
    }
    __shared__ float sss[4][128];
    sss[p][2 * lane] = s0; sss[p][2 * lane + 1] = s1;
    __syncthreads();
    if (p == 0) {
        s0 += sss[1][2 * lane]     + sss[2][2 * lane]     + sss[3][2 * lane];
        s1 += sss[1][2 * lane + 1] + sss[2][2 * lane + 1] + sss[3][2 * lane + 1];
        size_t o = ((size_t)b * TCH + tch) * NP + n0 + 2 * lane;
        ps[o] = s0; ps[o + 1] = s1;
    }
}

// ---------------------------------------------------------------------------
// u combine: U[b,n] = exp(LOG_A + CC - log(sum_chunks)). 64 blocks.
// ---------------------------------------------------------------------------
__global__ __launch_bounds__(256) void u_combine(
    const float* __restrict__ ps, float* __restrict__ U)
{
    int gid = blockIdx.x * 256 + threadIdx.x;     // over BB*NP
    int b = gid >> 11;
    int n = gid & (NP - 1);
    float S = 0.f;
    #pragma unroll
    for (int c = 0; c < TCH; ++c)
        S += ps[((size_t)b * TCH + c) * NP + n];
    U[gid] = __expf(LOG_A + CC - __logf(S));
}

// ---------------------------------------------------------------------------
// v update: S_t = sum_n E[t,n]*U[n];  Y[t] = e^CC / S_t.
// WP=true (final iteration): also write P[t,n] = E*U/S as f16.
// Adds-only reduce: wave shuffle + 4-way LDS.
// ---------------------------------------------------------------------------
template<bool WP>
__global__ __launch_bounds__(256) void v_update_q(
    const _Float16* __restrict__ E, const float* __restrict__ U,
    float* __restrict__ Y, _Float16* __restrict__ P)
{
    const int b = blockIdx.y;
    const int t = blockIdx.x;
    const uint4* Eb = (const uint4*)(E + ((size_t)b * TT + t) * NP);
    const float* Ub = U + (size_t)b * NP;
    const int tid = threadIdx.x;

    uint4 w = Eb[tid];
    const int n0 = tid * 8;
    float4 u0 = *(const float4*)(Ub + n0);
    float4 u1 = *(const float4*)(Ub + n0 + 4);
    float ev[8];
    ev[0] = f16u2f((unsigned short)(w.x & 0xFFFFu));
    ev[1] = f16u2f((unsigned short)(w.x >> 16));
    ev[2] = f16u2f((unsigned short)(w.y & 0xFFFFu));
    ev[3] = f16u2f((unsigned short)(w.y >> 16));
    ev[4] = f16u2f((unsigned short)(w.z & 0xFFFFu));
    ev[5] = f16u2f((unsigned short)(w.z >> 16));
    ev[6] = f16u2f((unsigned short)(w.w & 0xFFFFu));
    ev[7] = f16u2f((unsigned short)(w.w >> 16));
    float uv[8] = {u0.x, u0.y, u0.z, u0.w, u1.x, u1.y, u1.z, u1.w};

    float s = 0.f;
    #pragma unroll
    for (int j = 0; j < 8; ++j) s = fmaf(ev[j], uv[j], s);

    #pragma unroll
    for (int off = 32; off; off >>= 1) s += __shfl_down(s, off, 64);

    __shared__ float sw[4];
    __shared__ float Sall;
    if ((tid & 63) == 0) sw[tid >> 6] = s;
    __syncthreads();
    if (tid == 0) {
        float S = sw[0] + sw[1] + sw[2] + sw[3];
        Y[(size_t)b * TT + t] = E30 / S;
        Sall = S;
    }
    if (WP) {
        __syncthreads();
        float invS = 1.0f / Sall;
        _Float16 hp[8];
        #pragma unroll
        for (int j = 0; j < 8; ++j)
            hp[j] = (_Float16)(ev[j] * uv[j] * invS);
        *(f16x8*)(P + ((size_t)b * TT + t) * NP + n0) = *(f16x8*)hp;
    }
}

// ---------------------------------------------------------------------------
// pi GEMM (NT, pure fp16, 2-phase prefetch):
//   out[b,t,d] = sum_n P[b,t,n] * vpT[b,d,n]
// 1-D grid, XCD-chunked swizzle (one batch per XCD).
// ---------------------------------------------------------------------------
__global__ __launch_bounds__(256) void gemm_pi_f16(
    const _Float16* __restrict__ P, const _Float16* __restrict__ B,
    float* __restrict__ out)
{
    const int bid = blockIdx.x;
    const int sid = ((bid & 7) << 6) | (bid >> 3);   // 512 blocks, 64/XCD
    const int b  = sid >> 6;
    const int by = (sid >> 2) & 15;
    const int bx = sid & 3;

    const _Float16* Pb = P + (size_t)b * TT * NP;
    const _Float16* Bb = B + (size_t)b * DD * NP;
    float* Cb = out + (size_t)b * TT * DD;

    __shared__ __attribute__((aligned(16))) _Float16 sA[2][4096], sB[2][4096];
    const int tid = threadIdx.x;
    const int lane = tid & 63;
    const int row0 = by * 128;   // t
    const int col0 = bx * 128;   // d
    const int wm = ((tid >> 7) & 1) * 64;
    const int wn = ((tid >> 6) & 1) * 64;
    f32x4 acc[4][4];
    zero_acc(acc);

    auto STAGE = [&](int buf, int k0) {
        #pragma unroll
        for (int q = 0; q < 2; ++q) {
            int o = (tid + (q << 8)) << 4;
            int s = o >> 11;
            int r = (o & 2047) >> 4;
            gload16(Pb + (size_t)(row0 + r) * NP + k0 + s * 8, (char*)&sA[buf][0] + o);
            gload16(Bb + (size_t)(col0 + r) * NP + k0 + s * 8, (char*)&sB[buf][0] + o);
        }
    };

    STAGE(0, 0);
    __syncthreads();
    int cur = 0;
    for (int k0 = 0; k0 < NP; k0 += 32) {
        if (k0 + 32 < NP) STAGE(cur ^ 1, k0 + 32);
        frag_step_f16(&sA[cur][0], &sB[cur][0], lane, wm, wn, acc);
        __syncthreads();
        cur ^= 1;
    }
    store_plain(Cb, DD, row0, col0, lane, wm, wn, acc);
}

// ---------------------------------------------------------------------------
extern "C" void kernel_launch(void* const* d_in, const int* in_sizes, int n_in,
                              void* d_out, int out_size, void* d_ws, size_t ws_size,
                              hipStream_t stream)
{
    const float* q  = (const float*)d_in[0];
    const float* k  = (const float*)d_in[1];
    const float* v  = (const float*)d_in[2];
    const float* Qw = (const float*)d_in[3];
    const float* Kw = (const float*)d_in[4];
    const float* Vw = (const float*)d_in[5];
    float* out = (float*)d_out;

    // ---- workspace: ~131 MiB ----
    char* base = (char*)d_ws;
    _Float16* E16 = (_Float16*)base;                                // 64 MiB @ 0
    char* p2 = base + (size_t)BB * TT * NP * 2;
    _Float16* P   = (_Float16*)p2; p2 += (size_t)BB * TT * NP * 2;  // 32 MiB
    _Float16* qpf = (_Float16*)p2; p2 += (size_t)TT * DD * 2;       //  2 MiB
    _Float16* kpf = (_Float16*)p2; p2 += (size_t)BB * NP * DD * 2;  // 16 MiB
    _Float16* vpt = (_Float16*)p2; p2 += (size_t)BB * DD * NP * 2;  // 16 MiB (vpT)
    float* q2 = (float*)p2; p2 += (size_t)TT * 4;
    float* k2 = (float*)p2; p2 += (size_t)BB * NP * 4;
    float* U  = (float*)p2; p2 += (size_t)BB * NP * 4;
    float* Y  = (float*)p2; p2 += (size_t)BB * TT * 4;
    float* ps = (float*)p2; p2 += (size_t)BB * TCH * NP * 4;        // 512 KiB

    // weight temporaries aliased INSIDE the E16 region (dead before E16 write):
    short* wqh = (short*)base;                                      // 6 x 0.5 MiB
    short* wql = wqh + 262144;
    short* wkh = wql + 262144;
    short* wkl = wkh + 262144;
    short* wvh = wkl + 262144;
    short* wvl = wvh + 262144;

    dim3 blk(256);

    // Weights: transpose + hi/lo convert ([K][N] -> [N][K])
    transpose_hilo<<<dim3(8, 8, 1), blk, 0, stream>>>(Qw, wqh, wql, 512, 512);
    transpose_hilo<<<dim3(8, 8, 1), blk, 0, stream>>>(Kw, wkh, wkl, 512, 512);
    transpose_hilo<<<dim3(8, 8, 1), blk, 0, stream>>>(Vw, wvh, wvl, 512, 512);

    // Projections (split-bf16 core, fp32-grade): q,k -> f16 row-major;
    // v -> f16 transposed per batch (vpT direct, no fp32 intermediate)
    gemm_nt_f32A<1><<<dim3(4, 16, 1), blk, 0, stream>>>(
        q, wqh, wql, qpf, TT, DD, DD);
    gemm_nt_f32A<1><<<dim3(4, 128, 1), blk, 0, stream>>>(
        k, wkh, wkl, kpf, BB * NP, DD, DD);
    gemm_nt_f32A<2><<<dim3(4, 128, 1), blk, 0, stream>>>(
        v, wvh, wvl, vpt, BB * NP, DD, DD);

    // Squared norms from fp16 (self-consistent with cost GEMM operands)
    rownorm_f16<<<dim3(TT / 4), blk, 0, stream>>>(qpf, q2, TT);
    rownorm_f16<<<dim3((BB * NP) / 4), blk, 0, stream>>>(kpf, k2, BB * NP);

    // Cost matrix -> E16 = exp(CC - dist) (overwrites aliased weight temps)
    gemm_cost_f16<<<dim3(2048), blk, 0, stream>>>(qpf, kpf, q2, k2, E16);

    // Sinkhorn iterations, exp-free inner loops (Y = e^v, U = e^u):
    init_ones<<<dim3(BB * TT / 256), blk, 0, stream>>>(Y);
    for (int it = 0; it < 5; ++it) {
        u_part<<<dim3(NP / 128, TCH, BB), blk, 0, stream>>>(E16, Y, ps);
        u_combine<<<dim3(BB * NP / 256), blk, 0, stream>>>(ps, U);
        if (it < 4)
            v_update_q<false><<<dim3(TT, BB), blk, 0, stream>>>(E16, U, Y, nullptr);
        else
            v_update_q<true><<<dim3(TT, BB), blk, 0, stream>>>(E16, U, Y, P);
    }

    // out = P @ vp (pure fp16 MFMA, 2-phase prefetch)
    gemm_pi_f16<<<dim3(512), blk, 0, stream>>>(P, vpt, out);
}

// Round 12
// 425.720 us; speedup vs baseline: 3.9514x; 1.0758x over previous
//
#include <hip/hip_runtime.h>
#include <math.h>

#define TT 2048   // tokens
#define NP 2048   // num params (N)
#define BB 8      // batch
#define DD 512    // d_model = kdim = vdim
#define TCH 8     // u-update T chunks

#define LOG_A (-7.6246189861593985f)  // -log(2048)
#define CC 30.0f                       // E = exp(CC - dist) shift
#define E30 1.0686475e13f              // exp(30)

typedef __attribute__((ext_vector_type(8))) _Float16 f16x8;
typedef __attribute__((ext_vector_type(4))) _Float16 f16x4;
typedef __attribute__((ext_vector_type(4))) float f32x4;

#define MFMA_F16(a, b, c)  __builtin_amdgcn_mfma_f32_16x16x32_f16((a), (b), (c), 0, 0, 0)

// ---------------------------------------------------------------------------
// helpers
// ---------------------------------------------------------------------------
__device__ __forceinline__ float f16u2f(unsigned short u) {
    union { unsigned short s; _Float16 h; } v; v.s = u;
    return (float)v.h;
}

// async global->LDS, 16B per lane (wave-uniform LDS base + lane*16, per-lane src)
__device__ __forceinline__ void gload16(const void* g, void* l) {
    __builtin_amdgcn_global_load_lds(
        (const __attribute__((address_space(1))) void*)g,
        (__attribute__((address_space(3))) void*)l, 16, 0, 0);
}

// ---------------------------------------------------------------------------
// LDS tile layout, "k-group-major": tile[s][r][8 elems], s = k-subgroup
// (0..3 => BK=32), r = row (0..127). Byte off = s*2048 + r*16.
// A-frag (16x16x32): lane holds A[m=lane%16][k=(lane/16)*8+j]
// B-frag:            lane holds B[k=(lane/16)*8+j][n=lane%16]  (B stored [N][K])
// C/D:               col=lane&15, row=(lane>>4)*4+reg   [m89-verified]
// ---------------------------------------------------------------------------
__device__ __forceinline__ void frag_step_f16(
    const _Float16* sA, const _Float16* sB,
    int lane, int wm, int wn, f32x4 acc[4][4])
{
    const int sb = (lane >> 4) << 11;
    const int rl = (lane & 15) << 4;
    f16x8 a[4], b[4];
    #pragma unroll
    for (int i = 0; i < 4; ++i) {
        a[i] = *(const f16x8*)((const char*)sA + sb + ((wm + i * 16) << 4) + rl);
        b[i] = *(const f16x8*)((const char*)sB + sb + ((wn + i * 16) << 4) + rl);
    }
    #pragma unroll
    for (int i = 0; i < 4; ++i)
        #pragma unroll
        for (int j = 0; j < 4; ++j)
            acc[i][j] = MFMA_F16(a[i], b[j], acc[i][j]);
}

__device__ __forceinline__ void zero_acc(f32x4 acc[4][4]) {
    #pragma unroll
    for (int i = 0; i < 4; ++i)
        #pragma unroll
        for (int j = 0; j < 4; ++j)
            acc[i][j] = (f32x4){0.f, 0.f, 0.f, 0.f};
}

__device__ __forceinline__ void store_plain(
    float* C, int N, int row0, int col0, int lane, int wm, int wn, f32x4 acc[4][4])
{
    #pragma unroll
    for (int i = 0; i < 4; ++i)
        #pragma unroll
        for (int j = 0; j < 4; ++j) {
            int colg = col0 + wn + j * 16 + (lane & 15);
            int rowb = row0 + wm + i * 16 + ((lane >> 4) << 2);
            #pragma unroll
            for (int r = 0; r < 4; ++r)
                C[(size_t)(rowb + r) * N + colg] = acc[i][j][r];
        }
}

// ---------------------------------------------------------------------------
// Transpose to fp16: X[z][R][C] fp32 -> out[z][C][R] f16. (weights, z=1)
// ---------------------------------------------------------------------------
__global__ __launch_bounds__(256) void transpose_f16(
    const float* __restrict__ X, _Float16* __restrict__ oT, int R, int C)
{
    const size_t zoff = (size_t)blockIdx.z * R * C;
    const float* Xb = X + zoff;
    _Float16* ob = oT + zoff;
    __shared__ float t[64][65];
    const int bx = blockIdx.x * 64;  // C base
    const int by = blockIdx.y * 64;  // R base
    const int tx = threadIdx.x & 63, ty = threadIdx.x >> 6;
    #pragma unroll
    for (int r = ty; r < 64; r += 4)
        t[r][tx] = Xb[(size_t)(by + r) * C + bx + tx];
    __syncthreads();
    #pragma unroll
    for (int r = ty; r < 64; r += 4)
        ob[(size_t)(bx + r) * R + by + tx] = (_Float16)t[tx][r];
}

// ---------------------------------------------------------------------------
// Projection GEMM (NT, fp16 single-product): C = A[M,K] @ Bt[N,K]^T.
// A fp32 reg-staged -> f16 -> ds_write; B f16 pre-transposed via gload_lds.
// OUT=1: f16 out, row-major [M][N] (qp, kp).
// OUT=2: f16 out, per-batch transposed [b][N][rows-within-batch] (vpT direct).
// ---------------------------------------------------------------------------
template<int OUT>
__global__ __launch_bounds__(256) void gemm_proj_f16(
    const float* __restrict__ A, const _Float16* __restrict__ Bt,
    _Float16* __restrict__ C, int M, int N, int K)
{
    __shared__ __attribute__((aligned(16))) _Float16 sA[4096], sB[4096];
    const int tid = threadIdx.x;
    const int lane = tid & 63;
    const int row0 = blockIdx.y * 128;
    const int col0 = blockIdx.x * 128;
    const int wm = ((tid >> 7) & 1) * 64;
    const int wn = ((tid >> 6) & 1) * 64;
    f32x4 acc[4][4];
    zero_acc(acc);

    for (int k0 = 0; k0 < K; k0 += 32) {
        __syncthreads();
        #pragma unroll
        for (int q = 0; q < 2; ++q) {
            int o = (tid + (q << 8)) << 4;     // byte offset in f16 tile
            int s = o >> 11;
            int r = (o & 2047) >> 4;
            gload16(Bt + (size_t)(col0 + r) * K + k0 + s * 8, (char*)sB + o);
            const float* src = A + (size_t)(row0 + r) * K + k0 + s * 8;
            float4 f0 = *(const float4*)src;
            float4 f1 = *(const float4*)(src + 4);
            _Float16 hs[8] = {(_Float16)f0.x, (_Float16)f0.y,
                              (_Float16)f0.z, (_Float16)f0.w,
                              (_Float16)f1.x, (_Float16)f1.y,
                              (_Float16)f1.z, (_Float16)f1.w};
            *(f16x8*)((char*)sA + o) = *(f16x8*)hs;
        }
        __syncthreads();
        frag_step_f16(sA, sB, lane, wm, wn, acc);
    }
    #pragma unroll
    for (int i = 0; i < 4; ++i)
        #pragma unroll
        for (int j = 0; j < 4; ++j) {
            int colg = col0 + wn + j * 16 + (lane & 15);
            int rowb = row0 + wm + i * 16 + ((lane >> 4) << 2);
            if (OUT == 1) {
                #pragma unroll
                for (int r = 0; r < 4; ++r)
                    C[(size_t)(rowb + r) * N + colg] = (_Float16)acc[i][j][r];
            } else {
                // transposed, per-batch: vpt[b][colg][n], n = row within batch.
                int b = rowb >> 11;
                int n0 = rowb & (NP - 1);
                _Float16 h4[4];
                #pragma unroll
                for (int r = 0; r < 4; ++r) h4[r] = (_Float16)acc[i][j][r];
                *(f16x4*)(C + (size_t)b * DD * NP + (size_t)colg * NP + n0) =
                    *(f16x4*)h4;
            }
        }
}

// ---------------------------------------------------------------------------
// Row squared-norm from fp16: out[r] = sum_d x^2. One wave per row.
// ---------------------------------------------------------------------------
__global__ __launch_bounds__(256) void rownorm_f16(
    const _Float16* __restrict__ X, float* __restrict__ o, int rows)
{
    int w = blockIdx.x * 4 + (threadIdx.x >> 6);
    int lane = threadIdx.x & 63;
    if (w >= rows) return;
    f16x8 v = *(const f16x8*)(X + (size_t)w * DD + lane * 8);
    float s = 0.f;
    #pragma unroll
    for (int j = 0; j < 8; ++j) {
        float x = (float)v[j];
        s = fmaf(x, x, s);
    }
    #pragma unroll
    for (int off = 32; off; off >>= 1) s += __shfl_down(s, off, 64);
    if (lane == 0) o[w] = s;
}

// ---------------------------------------------------------------------------
// Cost GEMM (NT, fp16, 2-phase prefetch) — R10-verbatim (passing, 104 us):
//   dist = sqrt(max(q2+k2-2S,0));  E16 = f16(exp(CC - dist))  [clamped]
// 1-D grid, XCD-chunked swizzle: one batch per XCD.
// ---------------------------------------------------------------------------
__global__ __launch_bounds__(256) void gemm_cost_f16(
    const _Float16* __restrict__ A, const _Float16* __restrict__ B,
    const float* __restrict__ q2, const float* __restrict__ k2,
    _Float16* __restrict__ E)
{
    const int bid = blockIdx.x;
    const int sid = ((bid & 7) << 8) | (bid >> 3);
    const int b  = sid >> 8;
    const int by = (sid >> 4) & 15;
    const int bx = sid & 15;

    const _Float16* Bb = B + (size_t)b * NP * DD;
    const float* k2b = k2 + (size_t)b * NP;
    _Float16* Cb = E + (size_t)b * TT * NP;

    __shared__ __attribute__((aligned(16))) _Float16 sA[2][4096], sB[2][4096];
    const int tid = threadIdx.x;
    const int lane = tid & 63;
    const int row0 = by * 128;   // t
    const int col0 = bx * 128;   // n
    const int wm = ((tid >> 7) & 1) * 64;
    const int wn = ((tid >> 6) & 1) * 64;
    f32x4 acc[4][4];
    zero_acc(acc);

    auto STAGE = [&](int buf, int k0) {
        #pragma unroll
        for (int q = 0; q < 2; ++q) {
            int o = (tid + (q << 8)) << 4;
            int s = o >> 11;
            int r = (o & 2047) >> 4;
            gload16(A + (size_t)(row0 + r) * DD + k0 + s * 8, (char*)&sA[buf][0] + o);
            gload16(Bb + (size_t)(col0 + r) * DD + k0 + s * 8, (char*)&sB[buf][0] + o);
        }
    };

    STAGE(0, 0);
    __syncthreads();
    int cur = 0;
    for (int k0 = 0; k0 < DD; k0 += 32) {
        if (k0 + 32 < DD) STAGE(cur ^ 1, k0 + 32);
        frag_step_f16(&sA[cur][0], &sB[cur][0], lane, wm, wn, acc);
        __syncthreads();
        cur ^= 1;
    }
    #pragma unroll
    for (int i = 0; i < 4; ++i)
        #pragma unroll
        for (int j = 0; j < 4; ++j) {
            int colg = col0 + wn + j * 16 + (lane & 15);
            float k2v = k2b[colg];
            int rowb = row0 + wm + i * 16 + ((lane >> 4) << 2);
            #pragma unroll
            for (int r = 0; r < 4; ++r) {
                float sq = q2[rowb + r] + k2v - 2.f * acc[i][j][r];
                float dist = sqrtf(fmaxf(sq, 0.f));
                float e = fminf(__expf(CC - dist), 60000.f);
                Cb[(size_t)(rowb + r) * NP + colg] = (_Float16)e;
            }
        }
}

// ---------------------------------------------------------------------------
// Y init: Y = 1 (v = 0)
// ---------------------------------------------------------------------------
__global__ __launch_bounds__(256) void init_ones(float* __restrict__ Y)
{
    Y[blockIdx.x * 256 + threadIdx.x] = 1.0f;
}

// ---------------------------------------------------------------------------
// u partials: ps[b,tch,n] = sum over 256 rows of E[t,n] * Y[t].
// Pure fmaf — no exp/max. Grid (NP/128, TCH, BB) = 1024 blocks.
// ---------------------------------------------------------------------------
__global__ __launch_bounds__(256) void u_part(
    const _Float16* __restrict__ E, const float* __restrict__ Y,
    float* __restrict__ ps)
{
    const int b = blockIdx.z;
    const int tch = blockIdx.y;
    const int lane = threadIdx.x & 63;
    const int p = threadIdx.x >> 6;
    const int n0 = blockIdx.x * 128;
    const unsigned* Eb = (const unsigned*)(E + (size_t)b * TT * NP + n0);
    const float* Yb = Y + (size_t)b * TT;

    float s0 = 0.f, s1 = 0.f;
    const int t0 = tch * (TT / TCH) + p * (TT / TCH / 4);
    for (int tt = 0; tt < TT / TCH / 4; ++tt) {       // 64 rows
        int t = t0 + tt;
        unsigned w = Eb[(size_t)t * (NP / 2) + lane];
        float yv = Yb[t];
        s0 = fmaf(f16u2f((unsigned short)(w & 0xFFFFu)), yv, s0);
        s1 = fmaf(f16u2f((unsigned short)(w >> 16)),     yv, s1);
    }
    __shared__ float sss[4][128];
    sss[p][2 * lane] = s0; sss[p][2 * lane + 1] = s1;
    __syncthreads();
    if (p == 0) {
        s0 += sss[1][2 * lane]     + sss[2][2 * lane]     + sss[3][2 * lane];
        s1 += sss[1][2 * lane + 1] + sss[2][2 * lane + 1] + sss[3][2 * lane + 1];
        size_t o = ((size_t)b * TCH + tch) * NP + n0 + 2 * lane;
        ps[o] = s0; ps[o + 1] = s1;
    }
}

// ---------------------------------------------------------------------------
// u combine: U[b,n] = exp(LOG_A + CC - log(sum_chunks)). 64 blocks.
// ---------------------------------------------------------------------------
__global__ __launch_bounds__(256) void u_combine(
    const float* __restrict__ ps, float* __restrict__ U)
{
    int gid = blockIdx.x * 256 + threadIdx.x;     // over BB*NP
    int b = gid >> 11;
    int n = gid & (NP - 1);
    float S = 0.f;
    #pragma unroll
    for (int c = 0; c < TCH; ++c)
        S += ps[((size_t)b * TCH + c) * NP + n];
    U[gid] = __expf(LOG_A + CC - __logf(S));
}

// ---------------------------------------------------------------------------
// v update: S_t = sum_n E[t,n]*U[n];  Y[t] = e^CC / S_t.
// WP=true (final iteration): also write P[t,n] = E*U/S as f16.
// ---------------------------------------------------------------------------
template<bool WP>
__global__ __launch_bounds__(256) void v_update_q(
    const _Float16* __restrict__ E, const float* __restrict__ U,
    float* __restrict__ Y, _Float16* __restrict__ P)
{
    const int b = blockIdx.y;
    const int t = blockIdx.x;
    const uint4* Eb = (const uint4*)(E + ((size_t)b * TT + t) * NP);
    const float* Ub = U + (size_t)b * NP;
    const int tid = threadIdx.x;

    uint4 w = Eb[tid];
    const int n0 = tid * 8;
    float4 u0 = *(const float4*)(Ub + n0);
    float4 u1 = *(const float4*)(Ub + n0 + 4);
    float ev[8];
    ev[0] = f16u2f((unsigned short)(w.x & 0xFFFFu));
    ev[1] = f16u2f((unsigned short)(w.x >> 16));
    ev[2] = f16u2f((unsigned short)(w.y & 0xFFFFu));
    ev[3] = f16u2f((unsigned short)(w.y >> 16));
    ev[4] = f16u2f((unsigned short)(w.z & 0xFFFFu));
    ev[5] = f16u2f((unsigned short)(w.z >> 16));
    ev[6] = f16u2f((unsigned short)(w.w & 0xFFFFu));
    ev[7] = f16u2f((unsigned short)(w.w >> 16));
    float uv[8] = {u0.x, u0.y, u0.z, u0.w, u1.x, u1.y, u1.z, u1.w};

    float s = 0.f;
    #pragma unroll
    for (int j = 0; j < 8; ++j) s = fmaf(ev[j], uv[j], s);

    #pragma unroll
    for (int off = 32; off; off >>= 1) s += __shfl_down(s, off, 64);

    __shared__ float sw[4];
    __shared__ float Sall;
    if ((tid & 63) == 0) sw[tid >> 6] = s;
    __syncthreads();
    if (tid == 0) {
        float S = sw[0] + sw[1] + sw[2] + sw[3];
        Y[(size_t)b * TT + t] = E30 / S;
        Sall = S;
    }
    if (WP) {
        __syncthreads();
        float invS = 1.0f / Sall;
        _Float16 hp[8];
        #pragma unroll
        for (int j = 0; j < 8; ++j)
            hp[j] = (_Float16)(ev[j] * uv[j] * invS);
        *(f16x8*)(P + ((size_t)b * TT + t) * NP + n0) = *(f16x8*)hp;
    }
}

// ---------------------------------------------------------------------------
// pi GEMM (NT, pure fp16, 2-phase prefetch):
//   out[b,t,d] = sum_n P[b,t,n] * vpT[b,d,n]
// 1-D grid, XCD-chunked swizzle (one batch per XCD).
// ---------------------------------------------------------------------------
__global__ __launch_bounds__(256) void gemm_pi_f16(
    const _Float16* __restrict__ P, const _Float16* __restrict__ B,
    float* __restrict__ out)
{
    const int bid = blockIdx.x;
    const int sid = ((bid & 7) << 6) | (bid >> 3);   // 512 blocks, 64/XCD
    const int b  = sid >> 6;
    const int by = (sid >> 2) & 15;
    const int bx = sid & 3;

    const _Float16* Pb = P + (size_t)b * TT * NP;
    const _Float16* Bb = B + (size_t)b * DD * NP;
    float* Cb = out + (size_t)b * TT * DD;

    __shared__ __attribute__((aligned(16))) _Float16 sA[2][4096], sB[2][4096];
    const int tid = threadIdx.x;
    const int lane = tid & 63;
    const int row0 = by * 128;   // t
    const int col0 = bx * 128;   // d
    const int wm = ((tid >> 7) & 1) * 64;
    const int wn = ((tid >> 6) & 1) * 64;
    f32x4 acc[4][4];
    zero_acc(acc);

    auto STAGE = [&](int buf, int k0) {
        #pragma unroll
        for (int q = 0; q < 2; ++q) {
            int o = (tid + (q << 8)) << 4;
            int s = o >> 11;
            int r = (o & 2047) >> 4;
            gload16(Pb + (size_t)(row0 + r) * NP + k0 + s * 8, (char*)&sA[buf][0] + o);
            gload16(Bb + (size_t)(col0 + r) * NP + k0 + s * 8, (char*)&sB[buf][0] + o);
        }
    };

    STAGE(0, 0);
    __syncthreads();
    int cur = 0;
    for (int k0 = 0; k0 < NP; k0 += 32) {
        if (k0 + 32 < NP) STAGE(cur ^ 1, k0 + 32);
        frag_step_f16(&sA[cur][0], &sB[cur][0], lane, wm, wn, acc);
        __syncthreads();
        cur ^= 1;
    }
    store_plain(Cb, DD, row0, col0, lane, wm, wn, acc);
}

// ---------------------------------------------------------------------------
extern "C" void kernel_launch(void* const* d_in, const int* in_sizes, int n_in,
                              void* d_out, int out_size, void* d_ws, size_t ws_size,
                              hipStream_t stream)
{
    const float* q  = (const float*)d_in[0];
    const float* k  = (const float*)d_in[1];
    const float* v  = (const float*)d_in[2];
    const float* Qw = (const float*)d_in[3];
    const float* Kw = (const float*)d_in[4];
    const float* Vw = (const float*)d_in[5];
    float* out = (float*)d_out;

    // ---- workspace: ~131 MiB ----
    char* base = (char*)d_ws;
    _Float16* E16 = (_Float16*)base;                                // 64 MiB @ 0
    char* p2 = base + (size_t)BB * TT * NP * 2;
    _Float16* P   = (_Float16*)p2; p2 += (size_t)BB * TT * NP * 2;  // 32 MiB
    _Float16* qpf = (_Float16*)p2; p2 += (size_t)TT * DD * 2;       //  2 MiB
    _Float16* kpf = (_Float16*)p2; p2 += (size_t)BB * NP * DD * 2;  // 16 MiB
    _Float16* vpt = (_Float16*)p2; p2 += (size_t)BB * DD * NP * 2;  // 16 MiB (vpT)
    float* q2 = (float*)p2; p2 += (size_t)TT * 4;
    float* k2 = (float*)p2; p2 += (size_t)BB * NP * 4;
    float* U  = (float*)p2; p2 += (size_t)BB * NP * 4;
    float* Y  = (float*)p2; p2 += (size_t)BB * TT * 4;
    float* ps = (float*)p2; p2 += (size_t)BB * TCH * NP * 4;        // 512 KiB

    // weight f16 temporaries aliased INSIDE E16 (dead before E16 is written):
    _Float16* wq = (_Float16*)base;                 // 3 x 512 KiB
    _Float16* wk = wq + 262144;
    _Float16* wv = wk + 262144;

    dim3 blk(256);

    // Weights: transpose to f16 ([K][N] -> [N][K])
    transpose_f16<<<dim3(8, 8, 1), blk, 0, stream>>>(Qw, wq, 512, 512);
    transpose_f16<<<dim3(8, 8, 1), blk, 0, stream>>>(Kw, wk, 512, 512);
    transpose_f16<<<dim3(8, 8, 1), blk, 0, stream>>>(Vw, wv, 512, 512);

    // Projections (fp16 single-product): q,k -> f16 row-major;
    // v -> f16 transposed per batch (vpT direct)
    gemm_proj_f16<1><<<dim3(4, 16, 1), blk, 0, stream>>>(q, wq, qpf, TT, DD, DD);
    gemm_proj_f16<1><<<dim3(4, 128, 1), blk, 0, stream>>>(k, wk, kpf, BB * NP, DD, DD);
    gemm_proj_f16<2><<<dim3(4, 128, 1), blk, 0, stream>>>(v, wv, vpt, BB * NP, DD, DD);

    // Squared norms from stored fp16 (self-consistent with cost GEMM operands)
    rownorm_f16<<<dim3(TT / 4), blk, 0, stream>>>(qpf, q2, TT);
    rownorm_f16<<<dim3((BB * NP) / 4), blk, 0, stream>>>(kpf, k2, BB * NP);

    // Cost matrix -> E16 = exp(CC - dist) (overwrites aliased weight temps)
    gemm_cost_f16<<<dim3(2048), blk, 0, stream>>>(qpf, kpf, q2, k2, E16);

    // Sinkhorn iterations, exp-free inner loops (Y = e^v, U = e^u):
    init_ones<<<dim3(BB * TT / 256), blk, 0, stream>>>(Y);
    for (int it = 0; it < 5; ++it) {
        u_part<<<dim3(NP / 128, TCH, BB), blk, 0, stream>>>(E16, Y, ps);
        u_combine<<<dim3(BB * NP / 256), blk, 0, stream>>>(ps, U);
        if (it < 4)
            v_update_q<false><<<dim3(TT, BB), blk, 0, stream>>>(E16, U, Y, nullptr);
        else
            v_update_q<true><<<dim3(TT, BB), blk, 0, stream>>>(E16, U, Y, P);
    }

    // out = P @ vp (pure fp16 MFMA, 2-phase prefetch)
    gemm_pi_f16<<<dim3(512), blk, 0, stream>>>(P, vpt, out);
}

// Round 13
// 424.144 us; speedup vs baseline: 3.9661x; 1.0037x over previous
//
#include <hip/hip_runtime.h>
#include <math.h>

#define TT 2048   // tokens
#define NP 2048   // num params (N)
#define BB 8      // batch
#define DD 512    // d_model = kdim = vdim

#define LOG_A (-7.6246189861593985f)  // -log(2048)
#define CC 30.0f                       // E = exp(CC - dist) shift
#define E30 1.0686475e13f              // exp(30)
#define K0U 5.2180055e9f               // exp(30)/2048

typedef __attribute__((ext_vector_type(8))) _Float16 f16x8;
typedef __attribute__((ext_vector_type(4))) _Float16 f16x4;
typedef __attribute__((ext_vector_type(4))) float f32x4;

#define MFMA_F16(a, b, c)  __builtin_amdgcn_mfma_f32_16x16x32_f16((a), (b), (c), 0, 0, 0)

// ---------------------------------------------------------------------------
// helpers
// ---------------------------------------------------------------------------
__device__ __forceinline__ float f16u2f(unsigned short u) {
    union { unsigned short s; _Float16 h; } v; v.s = u;
    return (float)v.h;
}

// async global->LDS, 16B per lane (wave-uniform LDS base + lane*16, per-lane src)
__device__ __forceinline__ void gload16(const void* g, void* l) {
    __builtin_amdgcn_global_load_lds(
        (const __attribute__((address_space(1))) void*)g,
        (__attribute__((address_space(3))) void*)l, 16, 0, 0);
}

// ---------------------------------------------------------------------------
// LDS tile layout, "k-group-major": tile[s][r][8 elems], s = k-subgroup
// (0..3 => BK=32), r = row (0..127). Byte off = s*2048 + r*16.
// A-frag (16x16x32): lane holds A[m=lane%16][k=(lane/16)*8+j]
// B-frag:            lane holds B[k=(lane/16)*8+j][n=lane%16]  (B stored [N][K])
// C/D:               col=lane&15, row=(lane>>4)*4+reg   [m89-verified]
// ---------------------------------------------------------------------------
__device__ __forceinline__ void frag_step_f16(
    const _Float16* sA, const _Float16* sB,
    int lane, int wm, int wn, f32x4 acc[4][4])
{
    const int sb = (lane >> 4) << 11;
    const int rl = (lane & 15) << 4;
    f16x8 a[4], b[4];
    #pragma unroll
    for (int i = 0; i < 4; ++i) {
        a[i] = *(const f16x8*)((const char*)sA + sb + ((wm + i * 16) << 4) + rl);
        b[i] = *(const f16x8*)((const char*)sB + sb + ((wn + i * 16) << 4) + rl);
    }
    #pragma unroll
    for (int i = 0; i < 4; ++i)
        #pragma unroll
        for (int j = 0; j < 4; ++j)
            acc[i][j] = MFMA_F16(a[i], b[j], acc[i][j]);
}

__device__ __forceinline__ void zero_acc(f32x4 acc[4][4]) {
    #pragma unroll
    for (int i = 0; i < 4; ++i)
        #pragma unroll
        for (int j = 0; j < 4; ++j)
            acc[i][j] = (f32x4){0.f, 0.f, 0.f, 0.f};
}

__device__ __forceinline__ void store_plain(
    float* C, int N, int row0, int col0, int lane, int wm, int wn, f32x4 acc[4][4])
{
    #pragma unroll
    for (int i = 0; i < 4; ++i)
        #pragma unroll
        for (int j = 0; j < 4; ++j) {
            int colg = col0 + wn + j * 16 + (lane & 15);
            int rowb = row0 + wm + i * 16 + ((lane >> 4) << 2);
            #pragma unroll
            for (int r = 0; r < 4; ++r)
                C[(size_t)(rowb + r) * N + colg] = acc[i][j][r];
        }
}

// ---------------------------------------------------------------------------
// Transpose to fp16: X[z][R][C] fp32 -> out[z][C][R] f16. (weights, z=1)
// ---------------------------------------------------------------------------
__global__ __launch_bounds__(256) void transpose_f16(
    const float* __restrict__ X, _Float16* __restrict__ oT, int R, int C)
{
    const size_t zoff = (size_t)blockIdx.z * R * C;
    const float* Xb = X + zoff;
    _Float16* ob = oT + zoff;
    __shared__ float t[64][65];
    const int bx = blockIdx.x * 64;  // C base
    const int by = blockIdx.y * 64;  // R base
    const int tx = threadIdx.x & 63, ty = threadIdx.x >> 6;
    #pragma unroll
    for (int r = ty; r < 64; r += 4)
        t[r][tx] = Xb[(size_t)(by + r) * C + bx + tx];
    __syncthreads();
    #pragma unroll
    for (int r = ty; r < 64; r += 4)
        ob[(size_t)(bx + r) * R + by + tx] = (_Float16)t[tx][r];
}

// ---------------------------------------------------------------------------
// Projection GEMM (NT, fp16 single-product): C = A[M,K] @ Bt[N,K]^T.
// OUT=1: f16 out, row-major [M][N] (qp, kp).
// OUT=2: f16 out, per-batch transposed (vpT direct).
// ---------------------------------------------------------------------------
template<int OUT>
__global__ __launch_bounds__(256) void gemm_proj_f16(
    const float* __restrict__ A, const _Float16* __restrict__ Bt,
    _Float16* __restrict__ C, int M, int N, int K)
{
    __shared__ __attribute__((aligned(16))) _Float16 sA[4096], sB[4096];
    const int tid = threadIdx.x;
    const int lane = tid & 63;
    const int row0 = blockIdx.y * 128;
    const int col0 = blockIdx.x * 128;
    const int wm = ((tid >> 7) & 1) * 64;
    const int wn = ((tid >> 6) & 1) * 64;
    f32x4 acc[4][4];
    zero_acc(acc);

    for (int k0 = 0; k0 < K; k0 += 32) {
        __syncthreads();
        #pragma unroll
        for (int q = 0; q < 2; ++q) {
            int o = (tid + (q << 8)) << 4;     // byte offset in f16 tile
            int s = o >> 11;
            int r = (o & 2047) >> 4;
            gload16(Bt + (size_t)(col0 + r) * K + k0 + s * 8, (char*)sB + o);
            const float* src = A + (size_t)(row0 + r) * K + k0 + s * 8;
            float4 f0 = *(const float4*)src;
            float4 f1 = *(const float4*)(src + 4);
            _Float16 hs[8] = {(_Float16)f0.x, (_Float16)f0.y,
                              (_Float16)f0.z, (_Float16)f0.w,
                              (_Float16)f1.x, (_Float16)f1.y,
                              (_Float16)f1.z, (_Float16)f1.w};
            *(f16x8*)((char*)sA + o) = *(f16x8*)hs;
        }
        __syncthreads();
        frag_step_f16(sA, sB, lane, wm, wn, acc);
    }
    #pragma unroll
    for (int i = 0; i < 4; ++i)
        #pragma unroll
        for (int j = 0; j < 4; ++j) {
            int colg = col0 + wn + j * 16 + (lane & 15);
            int rowb = row0 + wm + i * 16 + ((lane >> 4) << 2);
            if (OUT == 1) {
                #pragma unroll
                for (int r = 0; r < 4; ++r)
                    C[(size_t)(rowb + r) * N + colg] = (_Float16)acc[i][j][r];
            } else {
                int b = rowb >> 11;
                int n0 = rowb & (NP - 1);
                _Float16 h4[4];
                #pragma unroll
                for (int r = 0; r < 4; ++r) h4[r] = (_Float16)acc[i][j][r];
                *(f16x4*)(C + (size_t)b * DD * NP + (size_t)colg * NP + n0) =
                    *(f16x4*)h4;
            }
        }
}

// ---------------------------------------------------------------------------
// Row squared-norm from fp16: out[r] = sum_d x^2. One wave per row.
// ---------------------------------------------------------------------------
__global__ __launch_bounds__(256) void rownorm_f16(
    const _Float16* __restrict__ X, float* __restrict__ o, int rows)
{
    int w = blockIdx.x * 4 + (threadIdx.x >> 6);
    int lane = threadIdx.x & 63;
    if (w >= rows) return;
    f16x8 v = *(const f16x8*)(X + (size_t)w * DD + lane * 8);
    float s = 0.f;
    #pragma unroll
    for (int j = 0; j < 8; ++j) {
        float x = (float)v[j];
        s = fmaf(x, x, s);
    }
    #pragma unroll
    for (int off = 32; off; off >>= 1) s += __shfl_down(s, off, 64);
    if (lane == 0) o[w] = s;
}

// ---------------------------------------------------------------------------
// Cost GEMM (NT, fp16, 2-phase prefetch): S = qp @ kp^T per batch, epilogue
//   dist = sqrt(max(q2+k2-2S,0));  E16 = f16(exp(CC - dist))  [clamped]
// Epilogue repack: E tile staged into the (dead) sA/sB static LDS arrays
// (wm-uniform split, no pointer arrays), then 8x coalesced f16x8 stores.
// 1-D grid, XCD-chunked swizzle: one batch per XCD.
// ---------------------------------------------------------------------------
__global__ __launch_bounds__(256) void gemm_cost_f16(
    const _Float16* __restrict__ A, const _Float16* __restrict__ B,
    const float* __restrict__ q2, const float* __restrict__ k2,
    _Float16* __restrict__ E)
{
    const int bid = blockIdx.x;
    const int sid = ((bid & 7) << 8) | (bid >> 3);
    const int b  = sid >> 8;
    const int by = (sid >> 4) & 15;
    const int bx = sid & 15;

    const _Float16* Bb = B + (size_t)b * NP * DD;
    const float* k2b = k2 + (size_t)b * NP;
    _Float16* Cb = E + (size_t)b * TT * NP;

    __shared__ __attribute__((aligned(16))) _Float16 sA[2][4096], sB[2][4096];
    const int tid = threadIdx.x;
    const int lane = tid & 63;
    const int row0 = by * 128;   // t
    const int col0 = bx * 128;   // n
    const int wm = ((tid >> 7) & 1) * 64;
    const int wn = ((tid >> 6) & 1) * 64;
    f32x4 acc[4][4];
    zero_acc(acc);

    auto STAGE = [&](int buf, int k0) {
        #pragma unroll
        for (int q = 0; q < 2; ++q) {
            int o = (tid + (q << 8)) << 4;
            int s = o >> 11;
            int r = (o & 2047) >> 4;
            gload16(A + (size_t)(row0 + r) * DD + k0 + s * 8, (char*)&sA[buf][0] + o);
            gload16(Bb + (size_t)(col0 + r) * DD + k0 + s * 8, (char*)&sB[buf][0] + o);
        }
    };

    STAGE(0, 0);
    __syncthreads();
    int cur = 0;
    for (int k0 = 0; k0 < DD; k0 += 32) {
        if (k0 + 32 < DD) STAGE(cur ^ 1, k0 + 32);
        frag_step_f16(&sA[cur][0], &sB[cur][0], lane, wm, wn, acc);
        __syncthreads();
        cur ^= 1;
    }

    // ---- epilogue: compute E into LDS halves, then coalesced stores ----
    // rows 0..63 (wm==0 waves) -> sA flat [64][128]; rows 64..127 -> sB flat.
    _Float16* half0 = &sA[0][0];
    _Float16* half1 = &sB[0][0];
    #pragma unroll
    for (int i = 0; i < 4; ++i)
        #pragma unroll
        for (int j = 0; j < 4; ++j) {
            int lc = wn + j * 16 + (lane & 15);
            float k2v = k2b[col0 + lc];
            int lrb = wm + i * 16 + ((lane >> 4) << 2);
            #pragma unroll
            for (int r = 0; r < 4; ++r) {
                float sq = q2[row0 + lrb + r] + k2v - 2.f * acc[i][j][r];
                float dist = sqrtf(fmaxf(sq, 0.f));
                float e = fminf(__expf(CC - dist), 60000.f);
                if (wm == 0) half0[(lrb + r) * 128 + lc] = (_Float16)e;
                else         half1[(lrb + r - 64) * 128 + lc] = (_Float16)e;
            }
        }
    __syncthreads();
    {
        const int lr16 = tid >> 4;          // 0..15
        const int c8 = (tid & 15) * 8;      // 0..120
        #pragma unroll
        for (int m = 0; m < 4; ++m) {
            int lr = m * 16 + lr16;
            f16x8 vrow = *(const f16x8*)(half0 + lr * 128 + c8);
            *(f16x8*)(Cb + (size_t)(row0 + lr) * NP + col0 + c8) = vrow;
        }
        #pragma unroll
        for (int m = 0; m < 4; ++m) {
            int lr = 64 + m * 16 + lr16;
            f16x8 vrow = *(const f16x8*)(half1 + (lr - 64) * 128 + c8);
            *(f16x8*)(Cb + (size_t)(row0 + lr) * NP + col0 + c8) = vrow;
        }
    }
}

// ---------------------------------------------------------------------------
// Fused Sinkhorn pass: block = 32 rows x all 2048 cols, batch b.
// FIRST: colsum of E (Y=1) -> ps.  Else: per-row S_t = sum E*U, Y=E30/S_t
// (in-kernel, never stored), then colsum of E*Y -> ps[b][chunk][n].
// Grid (TT/32, BB) = 512 blocks, 64 chunks.
// ---------------------------------------------------------------------------
template<bool FIRST>
__global__ __launch_bounds__(256) void sink_fused(
    const _Float16* __restrict__ E, const float* __restrict__ U,
    float* __restrict__ ps)
{
    const int b = blockIdx.y;
    const int t0 = blockIdx.x * 32;
    const int tid = threadIdx.x;
    const int n0 = tid * 8;
    const _Float16* Eb = E + ((size_t)b * TT + t0) * NP;

    float u8[8];
    if (!FIRST) {
        float4 a = *(const float4*)(U + (size_t)b * NP + n0);
        float4 c = *(const float4*)(U + (size_t)b * NP + n0 + 4);
        u8[0] = a.x; u8[1] = a.y; u8[2] = a.z; u8[3] = a.w;
        u8[4] = c.x; u8[5] = c.y; u8[6] = c.z; u8[7] = c.w;
    }

    float cs[8] = {0.f, 0.f, 0.f, 0.f, 0.f, 0.f, 0.f, 0.f};
    __shared__ float red[8][256];   // 8 KB
    __shared__ float yy[8];

    #pragma unroll
    for (int g = 0; g < 4; ++g) {
        uint4 ev[8];
        #pragma unroll
        for (int r = 0; r < 8; ++r)
            ev[r] = *(const uint4*)(Eb + (size_t)(g * 8 + r) * NP + n0);

        if (!FIRST) {
            // per-row dot with U
            #pragma unroll
            for (int r = 0; r < 8; ++r) {
                float d = 0.f;
                d = fmaf(f16u2f((unsigned short)(ev[r].x & 0xFFFFu)), u8[0], d);
                d = fmaf(f16u2f((unsigned short)(ev[r].x >> 16)),     u8[1], d);
                d = fmaf(f16u2f((unsigned short)(ev[r].y & 0xFFFFu)), u8[2], d);
                d = fmaf(f16u2f((unsigned short)(ev[r].y >> 16)),     u8[3], d);
                d = fmaf(f16u2f((unsigned short)(ev[r].z & 0xFFFFu)), u8[4], d);
                d = fmaf(f16u2f((unsigned short)(ev[r].z >> 16)),     u8[5], d);
                d = fmaf(f16u2f((unsigned short)(ev[r].w & 0xFFFFu)), u8[6], d);
                d = fmaf(f16u2f((unsigned short)(ev[r].w >> 16)),     u8[7], d);
                red[r][tid] = d;
            }
            __syncthreads();
            // wave w reduces rows 2w, 2w+1
            {
                int w = tid >> 6, lane = tid & 63;
                #pragma unroll
                for (int rr = 0; rr < 2; ++rr) {
                    int r = w * 2 + rr;
                    float s = red[r][lane] + red[r][lane + 64] +
                              red[r][lane + 128] + red[r][lane + 192];
                    #pragma unroll
                    for (int off = 32; off; off >>= 1)
                        s += __shfl_down(s, off, 64);
                    if (lane == 0) yy[r] = E30 / s;
                }
            }
            __syncthreads();
            #pragma unroll
            for (int r = 0; r < 8; ++r) {
                float yv = yy[r];
                cs[0] = fmaf(f16u2f((unsigned short)(ev[r].x & 0xFFFFu)), yv, cs[0]);
                cs[1] = fmaf(f16u2f((unsigned short)(ev[r].x >> 16)),     yv, cs[1]);
                cs[2] = fmaf(f16u2f((unsigned short)(ev[r].y & 0xFFFFu)), yv, cs[2]);
                cs[3] = fmaf(f16u2f((unsigned short)(ev[r].y >> 16)),     yv, cs[3]);
                cs[4] = fmaf(f16u2f((unsigned short)(ev[r].z & 0xFFFFu)), yv, cs[4]);
                cs[5] = fmaf(f16u2f((unsigned short)(ev[r].z >> 16)),     yv, cs[5]);
                cs[6] = fmaf(f16u2f((unsigned short)(ev[r].w & 0xFFFFu)), yv, cs[6]);
                cs[7] = fmaf(f16u2f((unsigned short)(ev[r].w >> 16)),     yv, cs[7]);
            }
            __syncthreads();   // protect red/yy before next group
        } else {
            #pragma unroll
            for (int r = 0; r < 8; ++r) {
                cs[0] += f16u2f((unsigned short)(ev[r].x & 0xFFFFu));
                cs[1] += f16u2f((unsigned short)(ev[r].x >> 16));
                cs[2] += f16u2f((unsigned short)(ev[r].y & 0xFFFFu));
                cs[3] += f16u2f((unsigned short)(ev[r].y >> 16));
                cs[4] += f16u2f((unsigned short)(ev[r].z & 0xFFFFu));
                cs[5] += f16u2f((unsigned short)(ev[r].z >> 16));
                cs[6] += f16u2f((unsigned short)(ev[r].w & 0xFFFFu));
                cs[7] += f16u2f((unsigned short)(ev[r].w >> 16));
            }
        }
    }

    size_t o = ((size_t)b * 64 + blockIdx.x) * NP + n0;
    *(float4*)(ps + o)     = make_float4(cs[0], cs[1], cs[2], cs[3]);
    *(float4*)(ps + o + 4) = make_float4(cs[4], cs[5], cs[6], cs[7]);
}

// ---------------------------------------------------------------------------
// u combine: U[b,n] = K0U / sum_chunks ps  (pure reciprocal — no exp/log).
// Grid 64 blocks x 256 threads = BB*NP.
// ---------------------------------------------------------------------------
__global__ __launch_bounds__(256) void u_combine(
    const float* __restrict__ ps, float* __restrict__ U)
{
    int gid = blockIdx.x * 256 + threadIdx.x;     // over BB*NP
    int b = gid >> 11;
    int n = gid & (NP - 1);
    float S = 0.f;
    #pragma unroll 8
    for (int c = 0; c < 64; ++c)
        S += ps[((size_t)b * 64 + c) * NP + n];
    U[gid] = K0U / S;
}

// ---------------------------------------------------------------------------
// Final v pass: S_t = sum_n E*U;  P[t,n] = E*U/S as f16. One block per row.
// ---------------------------------------------------------------------------
__global__ __launch_bounds__(256) void v_final(
    const _Float16* __restrict__ E, const float* __restrict__ U,
    _Float16* __restrict__ P)
{
    const int b = blockIdx.y;
    const int t = blockIdx.x;
    const uint4* Eb = (const uint4*)(E + ((size_t)b * TT + t) * NP);
    const float* Ub = U + (size_t)b * NP;
    const int tid = threadIdx.x;

    uint4 w = Eb[tid];
    const int n0 = tid * 8;
    float4 u0 = *(const float4*)(Ub + n0);
    float4 u1 = *(const float4*)(Ub + n0 + 4);
    float ev[8];
    ev[0] = f16u2f((unsigned short)(w.x & 0xFFFFu));
    ev[1] = f16u2f((unsigned short)(w.x >> 16));
    ev[2] = f16u2f((unsigned short)(w.y & 0xFFFFu));
    ev[3] = f16u2f((unsigned short)(w.y >> 16));
    ev[4] = f16u2f((unsigned short)(w.z & 0xFFFFu));
    ev[5] = f16u2f((unsigned short)(w.z >> 16));
    ev[6] = f16u2f((unsigned short)(w.w & 0xFFFFu));
    ev[7] = f16u2f((unsigned short)(w.w >> 16));
    float uv[8] = {u0.x, u0.y, u0.z, u0.w, u1.x, u1.y, u1.z, u1.w};

    float s = 0.f;
    #pragma unroll
    for (int j = 0; j < 8; ++j) s = fmaf(ev[j], uv[j], s);
    #pragma unroll
    for (int off = 32; off; off >>= 1) s += __shfl_down(s, off, 64);

    __shared__ float sw[4];
    __shared__ float Sall;
    if ((tid & 63) == 0) sw[tid >> 6] = s;
    __syncthreads();
    if (tid == 0) Sall = sw[0] + sw[1] + sw[2] + sw[3];
    __syncthreads();
    float invS = 1.0f / Sall;
    _Float16 hp[8];
    #pragma unroll
    for (int j = 0; j < 8; ++j)
        hp[j] = (_Float16)(ev[j] * uv[j] * invS);
    *(f16x8*)(P + ((size_t)b * TT + t) * NP + n0) = *(f16x8*)hp;
}

// ---------------------------------------------------------------------------
// pi GEMM (NT, pure fp16, 2-phase prefetch):
//   out[b,t,d] = sum_n P[b,t,n] * vpT[b,d,n]
// 1-D grid, XCD-chunked swizzle (one batch per XCD).
// ---------------------------------------------------------------------------
__global__ __launch_bounds__(256) void gemm_pi_f16(
    const _Float16* __restrict__ P, const _Float16* __restrict__ B,
    float* __restrict__ out)
{
    const int bid = blockIdx.x;
    const int sid = ((bid & 7) << 6) | (bid >> 3);   // 512 blocks, 64/XCD
    const int b  = sid >> 6;
    const int by = (sid >> 2) & 15;
    const int bx = sid & 3;

    const _Float16* Pb = P + (size_t)b * TT * NP;
    const _Float16* Bb = B + (size_t)b * DD * NP;
    float* Cb = out + (size_t)b * TT * DD;

    __shared__ __attribute__((aligned(16))) _Float16 sA[2][4096], sB[2][4096];
    const int tid = threadIdx.x;
    const int lane = tid & 63;
    const int row0 = by * 128;   // t
    const int col0 = bx * 128;   // d
    const int wm = ((tid >> 7) & 1) * 64;
    const int wn = ((tid >> 6) & 1) * 64;
    f32x4 acc[4][4];
    zero_acc(acc);

    auto STAGE = [&](int buf, int k0) {
        #pragma unroll
        for (int q = 0; q < 2; ++q) {
            int o = (tid + (q << 8)) << 4;
            int s = o >> 11;
            int r = (o & 2047) >> 4;
            gload16(Pb + (size_t)(row0 + r) * NP + k0 + s * 8, (char*)&sA[buf][0] + o);
            gload16(Bb + (size_t)(col0 + r) * NP + k0 + s * 8, (char*)&sB[buf][0] + o);
        }
    };

    STAGE(0, 0);
    __syncthreads();
    int cur = 0;
    for (int k0 = 0; k0 < NP; k0 += 32) {
        if (k0 + 32 < NP) STAGE(cur ^ 1, k0 + 32);
        frag_step_f16(&sA[cur][0], &sB[cur][0], lane, wm, wn, acc);
        __syncthreads();
        cur ^= 1;
    }
    store_plain(Cb, DD, row0, col0, lane, wm, wn, acc);
}

// ---------------------------------------------------------------------------
extern "C" void kernel_launch(void* const* d_in, const int* in_sizes, int n_in,
                              void* d_out, int out_size, void* d_ws, size_t ws_size,
                              hipStream_t stream)
{
    const float* q  = (const float*)d_in[0];
    const float* k  = (const float*)d_in[1];
    const float* v  = (const float*)d_in[2];
    const float* Qw = (const float*)d_in[3];
    const float* Kw = (const float*)d_in[4];
    const float* Vw = (const float*)d_in[5];
    float* out = (float*)d_out;

    // ---- workspace: ~135 MiB ----
    char* base = (char*)d_ws;
    _Float16* E16 = (_Float16*)base;                                // 64 MiB @ 0
    char* p2 = base + (size_t)BB * TT * NP * 2;
    _Float16* P   = (_Float16*)p2; p2 += (size_t)BB * TT * NP * 2;  // 32 MiB
    _Float16* qpf = (_Float16*)p2; p2 += (size_t)TT * DD * 2;       //  2 MiB
    _Float16* kpf = (_Float16*)p2; p2 += (size_t)BB * NP * DD * 2;  // 16 MiB
    _Float16* vpt = (_Float16*)p2; p2 += (size_t)BB * DD * NP * 2;  // 16 MiB (vpT)
    float* q2 = (float*)p2; p2 += (size_t)TT * 4;
    float* k2 = (float*)p2; p2 += (size_t)BB * NP * 4;
    float* U  = (float*)p2; p2 += (size_t)BB * NP * 4;
    float* ps = (float*)p2; p2 += (size_t)BB * 64 * NP * 4;         // 4 MiB

    // weight f16 temporaries aliased INSIDE E16 (dead before E16 is written):
    _Float16* wq = (_Float16*)base;                 // 3 x 512 KiB
    _Float16* wk = wq + 262144;
    _Float16* wv = wk + 262144;

    dim3 blk(256);

    // Weights: transpose to f16 ([K][N] -> [N][K])
    transpose_f16<<<dim3(8, 8, 1), blk, 0, stream>>>(Qw, wq, 512, 512);
    transpose_f16<<<dim3(8, 8, 1), blk, 0, stream>>>(Kw, wk, 512, 512);
    transpose_f16<<<dim3(8, 8, 1), blk, 0, stream>>>(Vw, wv, 512, 512);

    // Projections (fp16 single-product): q,k -> f16 row-major;
    // v -> f16 transposed per batch (vpT direct)
    gemm_proj_f16<1><<<dim3(4, 16, 1), blk, 0, stream>>>(q, wq, qpf, TT, DD, DD);
    gemm_proj_f16<1><<<dim3(4, 128, 1), blk, 0, stream>>>(k, wk, kpf, BB * NP, DD, DD);
    gemm_proj_f16<2><<<dim3(4, 128, 1), blk, 0, stream>>>(v, wv, vpt, BB * NP, DD, DD);

    // Squared norms from stored fp16 (self-consistent with cost GEMM operands)
    rownorm_f16<<<dim3(TT / 4), blk, 0, stream>>>(qpf, q2, TT);
    rownorm_f16<<<dim3((BB * NP) / 4), blk, 0, stream>>>(kpf, k2, BB * NP);

    // Cost matrix -> E16 = exp(CC - dist) (overwrites aliased weight temps)
    gemm_cost_f16<<<dim3(2048), blk, 0, stream>>>(qpf, kpf, q2, k2, E16);

    // Sinkhorn: 6 E-passes total.
    // FIRST colsum (Y0=1) -> U1; then 4x fused (v_it + next-u partials);
    // after each, combine -> U_{it+1}; finally v5 + P write.
    sink_fused<true><<<dim3(TT / 32, BB), blk, 0, stream>>>(E16, U, ps);
    u_combine<<<dim3(BB * NP / 256), blk, 0, stream>>>(ps, U);
    for (int it = 0; it < 4; ++it) {
        sink_fused<false><<<dim3(TT / 32, BB), blk, 0, stream>>>(E16, U, ps);
        u_combine<<<dim3(BB * NP / 256), blk, 0, stream>>>(ps, U);
    }
    v_final<<<dim3(TT, BB), blk, 0, stream>>>(E16, U, P);

    // out = P @ vp (pure fp16 MFMA, 2-phase prefetch)
    gemm_pi_f16<<<dim3(512), blk, 0, stream>>>(P, vpt, out);
}

// Round 14
// 392.524 us; speedup vs baseline: 4.2856x; 1.0806x over previous
//
#include <hip/hip_runtime.h>
#include <math.h>

#define TT 2048   // tokens
#define NP 2048   // num params (N)
#define BB 8      // batch
#define DD 512    // d_model = kdim = vdim

#define LOG_A (-7.6246189861593985f)  // -log(2048)
#define CC 30.0f                       // E = exp(CC - dist) shift
#define E30 1.0686475e13f              // exp(30)
#define K0U 5.2180055e9f               // exp(30)/2048

typedef __attribute__((ext_vector_type(8))) _Float16 f16x8;
typedef __attribute__((ext_vector_type(4))) _Float16 f16x4;
typedef __attribute__((ext_vector_type(4))) float f32x4;

#define MFMA_F16(a, b, c)  __builtin_amdgcn_mfma_f32_16x16x32_f16((a), (b), (c), 0, 0, 0)

// ---------------------------------------------------------------------------
// helpers
// ---------------------------------------------------------------------------
__device__ __forceinline__ float f16u2f(unsigned short u) {
    union { unsigned short s; _Float16 h; } v; v.s = u;
    return (float)v.h;
}

// async global->LDS, 16B per lane (wave-uniform LDS base + lane*16, per-lane src)
__device__ __forceinline__ void gload16(const void* g, void* l) {
    __builtin_amdgcn_global_load_lds(
        (const __attribute__((address_space(1))) void*)g,
        (__attribute__((address_space(3))) void*)l, 16, 0, 0);
}

// ---------------------------------------------------------------------------
// LDS tile layout, "k-group-major": tile[s][r][8 elems], s = k-subgroup
// (0..3 => BK=32), r = row (0..127). Byte off = s*2048 + r*16.
// A-frag (16x16x32): lane holds A[m=lane%16][k=(lane/16)*8+j]
// B-frag:            lane holds B[k=(lane/16)*8+j][n=lane%16]  (B stored [N][K])
// C/D:               col=lane&15, row=(lane>>4)*4+reg   [m89-verified]
// ---------------------------------------------------------------------------
__device__ __forceinline__ void frag_step_f16(
    const _Float16* sA, const _Float16* sB,
    int lane, int wm, int wn, f32x4 acc[4][4])
{
    const int sb = (lane >> 4) << 11;
    const int rl = (lane & 15) << 4;
    f16x8 a[4], b[4];
    #pragma unroll
    for (int i = 0; i < 4; ++i) {
        a[i] = *(const f16x8*)((const char*)sA + sb + ((wm + i * 16) << 4) + rl);
        b[i] = *(const f16x8*)((const char*)sB + sb + ((wn + i * 16) << 4) + rl);
    }
    #pragma unroll
    for (int i = 0; i < 4; ++i)
        #pragma unroll
        for (int j = 0; j < 4; ++j)
            acc[i][j] = MFMA_F16(a[i], b[j], acc[i][j]);
}

__device__ __forceinline__ void zero_acc(f32x4 acc[4][4]) {
    #pragma unroll
    for (int i = 0; i < 4; ++i)
        #pragma unroll
        for (int j = 0; j < 4; ++j)
            acc[i][j] = (f32x4){0.f, 0.f, 0.f, 0.f};
}

__device__ __forceinline__ void store_plain(
    float* C, int N, int row0, int col0, int lane, int wm, int wn, f32x4 acc[4][4])
{
    #pragma unroll
    for (int i = 0; i < 4; ++i)
        #pragma unroll
        for (int j = 0; j < 4; ++j) {
            int colg = col0 + wn + j * 16 + (lane & 15);
            int rowb = row0 + wm + i * 16 + ((lane >> 4) << 2);
            #pragma unroll
            for (int r = 0; r < 4; ++r)
                C[(size_t)(rowb + r) * N + colg] = acc[i][j][r];
        }
}

// ---------------------------------------------------------------------------
// Transpose 3 weights to fp16 in ONE launch: X[512][512] fp32 -> [512][512]^T
// f16; blockIdx.z selects which weight. Grid (8,8,3).
// ---------------------------------------------------------------------------
__global__ __launch_bounds__(256) void transpose3_f16(
    const float* __restrict__ X0, const float* __restrict__ X1,
    const float* __restrict__ X2, _Float16* __restrict__ o0,
    _Float16* __restrict__ o1, _Float16* __restrict__ o2)
{
    const int z = blockIdx.z;
    const float* Xb = (z == 0) ? X0 : (z == 1) ? X1 : X2;
    _Float16* ob = (z == 0) ? o0 : (z == 1) ? o1 : o2;
    __shared__ float t[64][65];
    const int bx = blockIdx.x * 64;  // col base
    const int by = blockIdx.y * 64;  // row base
    const int tx = threadIdx.x & 63, ty = threadIdx.x >> 6;
    #pragma unroll
    for (int r = ty; r < 64; r += 4)
        t[r][tx] = Xb[(size_t)(by + r) * 512 + bx + tx];
    __syncthreads();
    #pragma unroll
    for (int r = ty; r < 64; r += 4)
        ob[(size_t)(bx + r) * 512 + by + tx] = (_Float16)t[tx][r];
}

// ---------------------------------------------------------------------------
// Merged q+k projection GEMM (NT, fp16 single-product).
// Grid (4, 144): by<16 -> q rows (M=2048), else k rows (M=16384).
// Output C is the merged [18432][512] f16 region (qpf followed by kpf).
// ---------------------------------------------------------------------------
__global__ __launch_bounds__(256) void gemm_projqk_f16(
    const float* __restrict__ Aq, const float* __restrict__ Ak,
    const _Float16* __restrict__ Btq, const _Float16* __restrict__ Btk,
    _Float16* __restrict__ C)
{
    const int by = blockIdx.y;
    const bool isq = (by < 16);
    const float* A = isq ? Aq : Ak;
    const _Float16* Bt = isq ? Btq : Btk;
    const int arow0 = isq ? by * 128 : (by - 16) * 128;
    const int crow0 = by * 128;          // 16*128 == 2048 == qp rows
    const int col0 = blockIdx.x * 128;

    __shared__ __attribute__((aligned(16))) _Float16 sA[4096], sB[4096];
    const int tid = threadIdx.x;
    const int lane = tid & 63;
    const int wm = ((tid >> 7) & 1) * 64;
    const int wn = ((tid >> 6) & 1) * 64;
    f32x4 acc[4][4];
    zero_acc(acc);

    for (int k0 = 0; k0 < DD; k0 += 32) {
        __syncthreads();
        #pragma unroll
        for (int q = 0; q < 2; ++q) {
            int o = (tid + (q << 8)) << 4;
            int s = o >> 11;
            int r = (o & 2047) >> 4;
            gload16(Bt + (size_t)(col0 + r) * DD + k0 + s * 8, (char*)sB + o);
            const float* src = A + (size_t)(arow0 + r) * DD + k0 + s * 8;
            float4 f0 = *(const float4*)src;
            float4 f1 = *(const float4*)(src + 4);
            _Float16 hs[8] = {(_Float16)f0.x, (_Float16)f0.y,
                              (_Float16)f0.z, (_Float16)f0.w,
                              (_Float16)f1.x, (_Float16)f1.y,
                              (_Float16)f1.z, (_Float16)f1.w};
            *(f16x8*)((char*)sA + o) = *(f16x8*)hs;
        }
        __syncthreads();
        frag_step_f16(sA, sB, lane, wm, wn, acc);
    }
    #pragma unroll
    for (int i = 0; i < 4; ++i)
        #pragma unroll
        for (int j = 0; j < 4; ++j) {
            int colg = col0 + wn + j * 16 + (lane & 15);
            int rowb = crow0 + wm + i * 16 + ((lane >> 4) << 2);
            #pragma unroll
            for (int r = 0; r < 4; ++r)
                C[(size_t)(rowb + r) * DD + colg] = (_Float16)acc[i][j][r];
        }
}

// ---------------------------------------------------------------------------
// v projection GEMM (NT, fp16): writes vpT per-batch transposed directly.
// ---------------------------------------------------------------------------
__global__ __launch_bounds__(256) void gemm_projv_f16(
    const float* __restrict__ A, const _Float16* __restrict__ Bt,
    _Float16* __restrict__ C)
{
    __shared__ __attribute__((aligned(16))) _Float16 sA[4096], sB[4096];
    const int tid = threadIdx.x;
    const int lane = tid & 63;
    const int row0 = blockIdx.y * 128;
    const int col0 = blockIdx.x * 128;
    const int wm = ((tid >> 7) & 1) * 64;
    const int wn = ((tid >> 6) & 1) * 64;
    f32x4 acc[4][4];
    zero_acc(acc);

    for (int k0 = 0; k0 < DD; k0 += 32) {
        __syncthreads();
        #pragma unroll
        for (int q = 0; q < 2; ++q) {
            int o = (tid + (q << 8)) << 4;
            int s = o >> 11;
            int r = (o & 2047) >> 4;
            gload16(Bt + (size_t)(col0 + r) * DD + k0 + s * 8, (char*)sB + o);
            const float* src = A + (size_t)(row0 + r) * DD + k0 + s * 8;
            float4 f0 = *(const float4*)src;
            float4 f1 = *(const float4*)(src + 4);
            _Float16 hs[8] = {(_Float16)f0.x, (_Float16)f0.y,
                              (_Float16)f0.z, (_Float16)f0.w,
                              (_Float16)f1.x, (_Float16)f1.y,
                              (_Float16)f1.z, (_Float16)f1.w};
            *(f16x8*)((char*)sA + o) = *(f16x8*)hs;
        }
        __syncthreads();
        frag_step_f16(sA, sB, lane, wm, wn, acc);
    }
    #pragma unroll
    for (int i = 0; i < 4; ++i)
        #pragma unroll
        for (int j = 0; j < 4; ++j) {
            int colg = col0 + wn + j * 16 + (lane & 15);
            int rowb = row0 + wm + i * 16 + ((lane >> 4) << 2);
            int b = rowb >> 11;
            int n0 = rowb & (NP - 1);
            _Float16 h4[4];
            #pragma unroll
            for (int r = 0; r < 4; ++r) h4[r] = (_Float16)acc[i][j][r];
            *(f16x4*)(C + (size_t)b * DD * NP + (size_t)colg * NP + n0) =
                *(f16x4*)h4;
        }
}

// ---------------------------------------------------------------------------
// Row squared-norm from fp16 (merged qp+kp, 18432 rows). One wave per row.
// ---------------------------------------------------------------------------
__global__ __launch_bounds__(256) void rownorm_f16(
    const _Float16* __restrict__ X, float* __restrict__ o, int rows)
{
    int w = blockIdx.x * 4 + (threadIdx.x >> 6);
    int lane = threadIdx.x & 63;
    if (w >= rows) return;
    f16x8 v = *(const f16x8*)(X + (size_t)w * DD + lane * 8);
    float s = 0.f;
    #pragma unroll
    for (int j = 0; j < 8; ++j) {
        float x = (float)v[j];
        s = fmaf(x, x, s);
    }
    #pragma unroll
    for (int off = 32; off; off >>= 1) s += __shfl_down(s, off, 64);
    if (lane == 0) o[w] = s;
}

// ---------------------------------------------------------------------------
// Cost GEMM (NT, fp16) with 3-buffer counted-vmcnt pipeline [T3/T4, m218]:
// per K-step: s_waitcnt vmcnt(4) (own loads for buf-s done; buf-s+1 loads
// stay in flight) -> s_barrier (cross-wave visibility) -> sched_barrier(0)
// (rule #18 fence) -> issue STAGE(s+2) -> ds_read+MFMA.
// Epilogue: dist = sqrt(max(q2+k2-2S,0)); E16 = f16(exp(CC-dist)), scattered
// stores (R12-proven; R13's LDS repack added 1M bank conflicts for 0 gain).
// 1-D grid, XCD-chunked swizzle: one batch per XCD.
// ---------------------------------------------------------------------------
__global__ __launch_bounds__(256) void gemm_cost_f16(
    const _Float16* __restrict__ A, const _Float16* __restrict__ B,
    const float* __restrict__ q2, const float* __restrict__ k2,
    _Float16* __restrict__ E)
{
    const int bid = blockIdx.x;
    const int sid = ((bid & 7) << 8) | (bid >> 3);
    const int b  = sid >> 8;
    const int by = (sid >> 4) & 15;
    const int bx = sid & 15;

    const _Float16* Bb = B + (size_t)b * NP * DD;
    const float* k2b = k2 + (size_t)b * NP;
    _Float16* Cb = E + (size_t)b * TT * NP;

    __shared__ __attribute__((aligned(16))) _Float16 sA[3][4096], sB[3][4096];
    const int tid = threadIdx.x;
    const int lane = tid & 63;
    const int row0 = by * 128;   // t
    const int col0 = bx * 128;   // n
    const int wm = ((tid >> 7) & 1) * 64;
    const int wn = ((tid >> 6) & 1) * 64;
    f32x4 acc[4][4];
    zero_acc(acc);

    auto STAGE = [&](int buf, int k0) {
        #pragma unroll
        for (int q = 0; q < 2; ++q) {
            int o = (tid + (q << 8)) << 4;
            int s = o >> 11;
            int r = (o & 2047) >> 4;
            gload16(A + (size_t)(row0 + r) * DD + k0 + s * 8, (char*)&sA[buf][0] + o);
            gload16(Bb + (size_t)(col0 + r) * DD + k0 + s * 8, (char*)&sB[buf][0] + o);
        }
    };

    // prologue: 2 K-tiles in flight (8 outstanding loads per wave)
    STAGE(0, 0);
    STAGE(1, 32);

    // steady state: 16 K-steps, vmcnt(4) = wait own oldest STAGE only
    #pragma unroll
    for (int s = 0; s < 14; ++s) {
        asm volatile("s_waitcnt vmcnt(4)" ::: "memory");
        __builtin_amdgcn_s_barrier();
        __builtin_amdgcn_sched_barrier(0);
        STAGE((s + 2) % 3, (s + 2) * 32);
        frag_step_f16(&sA[s % 3][0], &sB[s % 3][0], lane, wm, wn, acc);
    }
    // s = 14: nothing left to stage; buf15 loads still in flight
    asm volatile("s_waitcnt vmcnt(4)" ::: "memory");
    __builtin_amdgcn_s_barrier();
    __builtin_amdgcn_sched_barrier(0);
    frag_step_f16(&sA[2][0], &sB[2][0], lane, wm, wn, acc);   // 14 % 3 == 2
    // s = 15: drain
    asm volatile("s_waitcnt vmcnt(0)" ::: "memory");
    __builtin_amdgcn_s_barrier();
    __builtin_amdgcn_sched_barrier(0);
    frag_step_f16(&sA[0][0], &sB[0][0], lane, wm, wn, acc);   // 15 % 3 == 0

    #pragma unroll
    for (int i = 0; i < 4; ++i)
        #pragma unroll
        for (int j = 0; j < 4; ++j) {
            int colg = col0 + wn + j * 16 + (lane & 15);
            float k2v = k2b[colg];
            int rowb = row0 + wm + i * 16 + ((lane >> 4) << 2);
            #pragma unroll
            for (int r = 0; r < 4; ++r) {
                float sq = q2[rowb + r] + k2v - 2.f * acc[i][j][r];
                float dist = sqrtf(fmaxf(sq, 0.f));
                float e = fminf(__expf(CC - dist), 60000.f);
                Cb[(size_t)(rowb + r) * NP + colg] = (_Float16)e;
            }
        }
}

// ---------------------------------------------------------------------------
// Fused Sinkhorn pass: block = 32 rows x all 2048 cols, batch b.
// FIRST: colsum of E (Y=1) -> ps.  Else: per-row S_t = sum E*U, Y=E30/S_t
// (in-kernel, never stored), then colsum of E*Y -> ps[b][chunk][n].
// Grid (TT/32, BB) = 512 blocks, 64 chunks.
// ---------------------------------------------------------------------------
template<bool FIRST>
__global__ __launch_bounds__(256) void sink_fused(
    const _Float16* __restrict__ E, const float* __restrict__ U,
    float* __restrict__ ps)
{
    const int b = blockIdx.y;
    const int t0 = blockIdx.x * 32;
    const int tid = threadIdx.x;
    const int n0 = tid * 8;
    const _Float16* Eb = E + ((size_t)b * TT + t0) * NP;

    float u8[8];
    if (!FIRST) {
        float4 a = *(const float4*)(U + (size_t)b * NP + n0);
        float4 c = *(const float4*)(U + (size_t)b * NP + n0 + 4);
        u8[0] = a.x; u8[1] = a.y; u8[2] = a.z; u8[3] = a.w;
        u8[4] = c.x; u8[5] = c.y; u8[6] = c.z; u8[7] = c.w;
    }

    float cs[8] = {0.f, 0.f, 0.f, 0.f, 0.f, 0.f, 0.f, 0.f};
    __shared__ float red[8][256];   // 8 KB
    __shared__ float yy[8];

    #pragma unroll
    for (int g = 0; g < 4; ++g) {
        uint4 ev[8];
        #pragma unroll
        for (int r = 0; r < 8; ++r)
            ev[r] = *(const uint4*)(Eb + (size_t)(g * 8 + r) * NP + n0);

        if (!FIRST) {
            #pragma unroll
            for (int r = 0; r < 8; ++r) {
                float d = 0.f;
                d = fmaf(f16u2f((unsigned short)(ev[r].x & 0xFFFFu)), u8[0], d);
                d = fmaf(f16u2f((unsigned short)(ev[r].x >> 16)),     u8[1], d);
                d = fmaf(f16u2f((unsigned short)(ev[r].y & 0xFFFFu)), u8[2], d);
                d = fmaf(f16u2f((unsigned short)(ev[r].y >> 16)),     u8[3], d);
                d = fmaf(f16u2f((unsigned short)(ev[r].z & 0xFFFFu)), u8[4], d);
                d = fmaf(f16u2f((unsigned short)(ev[r].z >> 16)),     u8[5], d);
                d = fmaf(f16u2f((unsigned short)(ev[r].w & 0xFFFFu)), u8[6], d);
                d = fmaf(f16u2f((unsigned short)(ev[r].w >> 16)),     u8[7], d);
                red[r][tid] = d;
            }
            __syncthreads();
            {
                int w = tid >> 6, lane = tid & 63;
                #pragma unroll
                for (int rr = 0; rr < 2; ++rr) {
                    int r = w * 2 + rr;
                    float s = red[r][lane] + red[r][lane + 64] +
                              red[r][lane + 128] + red[r][lane + 192];
                    #pragma unroll
                    for (int off = 32; off; off >>= 1)
                        s += __shfl_down(s, off, 64);
                    if (lane == 0) yy[r] = E30 / s;
                }
            }
            __syncthreads();
            #pragma unroll
            for (int r = 0; r < 8; ++r) {
                float yv = yy[r];
                cs[0] = fmaf(f16u2f((unsigned short)(ev[r].x & 0xFFFFu)), yv, cs[0]);
                cs[1] = fmaf(f16u2f((unsigned short)(ev[r].x >> 16)),     yv, cs[1]);
                cs[2] = fmaf(f16u2f((unsigned short)(ev[r].y & 0xFFFFu)), yv, cs[2]);
                cs[3] = fmaf(f16u2f((unsigned short)(ev[r].y >> 16)),     yv, cs[3]);
                cs[4] = fmaf(f16u2f((unsigned short)(ev[r].z & 0xFFFFu)), yv, cs[4]);
                cs[5] = fmaf(f16u2f((unsigned short)(ev[r].z >> 16)),     yv, cs[5]);
                cs[6] = fmaf(f16u2f((unsigned short)(ev[r].w & 0xFFFFu)), yv, cs[6]);
                cs[7] = fmaf(f16u2f((unsigned short)(ev[r].w >> 16)),     yv, cs[7]);
            }
            __syncthreads();
        } else {
            #pragma unroll
            for (int r = 0; r < 8; ++r) {
                cs[0] += f16u2f((unsigned short)(ev[r].x & 0xFFFFu));
                cs[1] += f16u2f((unsigned short)(ev[r].x >> 16));
                cs[2] += f16u2f((unsigned short)(ev[r].y & 0xFFFFu));
                cs[3] += f16u2f((unsigned short)(ev[r].y >> 16));
                cs[4] += f16u2f((unsigned short)(ev[r].z & 0xFFFFu));
                cs[5] += f16u2f((unsigned short)(ev[r].z >> 16));
                cs[6] += f16u2f((unsigned short)(ev[r].w & 0xFFFFu));
                cs[7] += f16u2f((unsigned short)(ev[r].w >> 16));
            }
        }
    }

    size_t o = ((size_t)b * 64 + blockIdx.x) * NP + n0;
    *(float4*)(ps + o)     = make_float4(cs[0], cs[1], cs[2], cs[3]);
    *(float4*)(ps + o + 4) = make_float4(cs[4], cs[5], cs[6], cs[7]);
}

// ---------------------------------------------------------------------------
// u combine: U[b,n] = K0U / sum_chunks ps  (pure reciprocal).
// ---------------------------------------------------------------------------
__global__ __launch_bounds__(256) void u_combine(
    const float* __restrict__ ps, float* __restrict__ U)
{
    int gid = blockIdx.x * 256 + threadIdx.x;     // over BB*NP
    int b = gid >> 11;
    int n = gid & (NP - 1);
    float S = 0.f;
    #pragma unroll 8
    for (int c = 0; c < 64; ++c)
        S += ps[((size_t)b * 64 + c) * NP + n];
    U[gid] = K0U / S;
}

// ---------------------------------------------------------------------------
// Final v pass: S_t = sum_n E*U;  P[t,n] = E*U/S as f16. One block per row.
// ---------------------------------------------------------------------------
__global__ __launch_bounds__(256) void v_final(
    const _Float16* __restrict__ E, const float* __restrict__ U,
    _Float16* __restrict__ P)
{
    const int b = blockIdx.y;
    const int t = blockIdx.x;
    const uint4* Eb = (const uint4*)(E + ((size_t)b * TT + t) * NP);
    const float* Ub = U + (size_t)b * NP;
    const int tid = threadIdx.x;

    uint4 w = Eb[tid];
    const int n0 = tid * 8;
    float4 u0 = *(const float4*)(Ub + n0);
    float4 u1 = *(const float4*)(Ub + n0 + 4);
    float ev[8];
    ev[0] = f16u2f((unsigned short)(w.x & 0xFFFFu));
    ev[1] = f16u2f((unsigned short)(w.x >> 16));
    ev[2] = f16u2f((unsigned short)(w.y & 0xFFFFu));
    ev[3] = f16u2f((unsigned short)(w.y >> 16));
    ev[4] = f16u2f((unsigned short)(w.z & 0xFFFFu));
    ev[5] = f16u2f((unsigned short)(w.z >> 16));
    ev[6] = f16u2f((unsigned short)(w.w & 0xFFFFu));
    ev[7] = f16u2f((unsigned short)(w.w >> 16));
    float uv[8] = {u0.x, u0.y, u0.z, u0.w, u1.x, u1.y, u1.z, u1.w};

    float s = 0.f;
    #pragma unroll
    for (int j = 0; j < 8; ++j) s = fmaf(ev[j], uv[j], s);
    #pragma unroll
    for (int off = 32; off; off >>= 1) s += __shfl_down(s, off, 64);

    __shared__ float sw[4];
    __shared__ float Sall;
    if ((tid & 63) == 0) sw[tid >> 6] = s;
    __syncthreads();
    if (tid == 0) Sall = sw[0] + sw[1] + sw[2] + sw[3];
    __syncthreads();
    float invS = 1.0f / Sall;
    _Float16 hp[8];
    #pragma unroll
    for (int j = 0; j < 8; ++j)
        hp[j] = (_Float16)(ev[j] * uv[j] * invS);
    *(f16x8*)(P + ((size_t)b * TT + t) * NP + n0) = *(f16x8*)hp;
}

// ---------------------------------------------------------------------------
// pi GEMM (NT, pure fp16, 2-phase prefetch):
//   out[b,t,d] = sum_n P[b,t,n] * vpT[b,d,n]
// 1-D grid, XCD-chunked swizzle (one batch per XCD).
// ---------------------------------------------------------------------------
__global__ __launch_bounds__(256) void gemm_pi_f16(
    const _Float16* __restrict__ P, const _Float16* __restrict__ B,
    float* __restrict__ out)
{
    const int bid = blockIdx.x;
    const int sid = ((bid & 7) << 6) | (bid >> 3);   // 512 blocks, 64/XCD
    const int b  = sid >> 6;
    const int by = (sid >> 2) & 15;
    const int bx = sid & 3;

    const _Float16* Pb = P + (size_t)b * TT * NP;
    const _Float16* Bb = B + (size_t)b * DD * NP;
    float* Cb = out + (size_t)b * TT * DD;

    __shared__ __attribute__((aligned(16))) _Float16 sA[2][4096], sB[2][4096];
    const int tid = threadIdx.x;
    const int lane = tid & 63;
    const int row0 = by * 128;   // t
    const int col0 = bx * 128;   // d
    const int wm = ((tid >> 7) & 1) * 64;
    const int wn = ((tid >> 6) & 1) * 64;
    f32x4 acc[4][4];
    zero_acc(acc);

    auto STAGE = [&](int buf, int k0) {
        #pragma unroll
        for (int q = 0; q < 2; ++q) {
            int o = (tid + (q << 8)) << 4;
            int s = o >> 11;
            int r = (o & 2047) >> 4;
            gload16(Pb + (size_t)(row0 + r) * NP + k0 + s * 8, (char*)&sA[buf][0] + o);
            gload16(Bb + (size_t)(col0 + r) * NP + k0 + s * 8, (char*)&sB[buf][0] + o);
        }
    };

    STAGE(0, 0);
    __syncthreads();
    int cur = 0;
    for (int k0 = 0; k0 < NP; k0 += 32) {
        if (k0 + 32 < NP) STAGE(cur ^ 1, k0 + 32);
        frag_step_f16(&sA[cur][0], &sB[cur][0], lane, wm, wn, acc);
        __syncthreads();
        cur ^= 1;
    }
    store_plain(Cb, DD, row0, col0, lane, wm, wn, acc);
}

// ---------------------------------------------------------------------------
extern "C" void kernel_launch(void* const* d_in, const int* in_sizes, int n_in,
                              void* d_out, int out_size, void* d_ws, size_t ws_size,
                              hipStream_t stream)
{
    const float* q  = (const float*)d_in[0];
    const float* k  = (const float*)d_in[1];
    const float* v  = (const float*)d_in[2];
    const float* Qw = (const float*)d_in[3];
    const float* Kw = (const float*)d_in[4];
    const float* Vw = (const float*)d_in[5];
    float* out = (float*)d_out;

    // ---- workspace: ~135 MiB ----
    char* base = (char*)d_ws;
    _Float16* E16 = (_Float16*)base;                                // 64 MiB @ 0
    char* p2 = base + (size_t)BB * TT * NP * 2;
    _Float16* P   = (_Float16*)p2; p2 += (size_t)BB * TT * NP * 2;  // 32 MiB
    _Float16* qpf = (_Float16*)p2; p2 += (size_t)TT * DD * 2;       //  2 MiB
    _Float16* kpf = (_Float16*)p2; p2 += (size_t)BB * NP * DD * 2;  // 16 MiB
    _Float16* vpt = (_Float16*)p2; p2 += (size_t)BB * DD * NP * 2;  // 16 MiB (vpT)
    float* q2 = (float*)p2; p2 += (size_t)TT * 4;
    float* k2 = (float*)p2; p2 += (size_t)BB * NP * 4;
    float* U  = (float*)p2; p2 += (size_t)BB * NP * 4;
    float* ps = (float*)p2; p2 += (size_t)BB * 64 * NP * 4;         // 4 MiB

    // weight f16 temporaries aliased INSIDE E16 (dead before E16 is written):
    _Float16* wq = (_Float16*)base;                 // 3 x 512 KiB
    _Float16* wk = wq + 262144;
    _Float16* wv = wk + 262144;

    dim3 blk(256);

    // Weights: transpose to f16, single launch
    transpose3_f16<<<dim3(8, 8, 3), blk, 0, stream>>>(Qw, Kw, Vw, wq, wk, wv);

    // Projections: q+k merged (writes contiguous qpf|kpf); v -> vpT direct
    gemm_projqk_f16<<<dim3(4, 144, 1), blk, 0, stream>>>(q, k, wq, wk, qpf);
    gemm_projv_f16<<<dim3(4, 128, 1), blk, 0, stream>>>(v, wv, vpt);

    // Squared norms, merged (qpf|kpf and q2|k2 are contiguous)
    rownorm_f16<<<dim3((TT + BB * NP) / 4), blk, 0, stream>>>(qpf, q2, TT + BB * NP);

    // Cost matrix -> E16 = exp(CC - dist) (counted-vmcnt pipeline)
    gemm_cost_f16<<<dim3(2048), blk, 0, stream>>>(qpf, kpf, q2, k2, E16);

    // Sinkhorn: 6 E-passes total (FIRST colsum, 4 fused v+u, final v+P)
    sink_fused<true><<<dim3(TT / 32, BB), blk, 0, stream>>>(E16, U, ps);
    u_combine<<<dim3(BB * NP / 256), blk, 0, stream>>>(ps, U);
    for (int it = 0; it < 4; ++it) {
        sink_fused<false><<<dim3(TT / 32, BB), blk, 0, stream>>>(E16, U, ps);
        u_combine<<<dim3(BB * NP / 256), blk, 0, stream>>>(ps, U);
    }
    v_final<<<dim3(TT, BB), blk, 0, stream>>>(E16, U, P);

    // out = P @ vp (pure fp16 MFMA, 2-phase prefetch)
    gemm_pi_f16<<<dim3(512), blk, 0, stream>>>(P, vpt, out);
}

// Round 15
// 384.106 us; speedup vs baseline: 4.3795x; 1.0219x over previous
//
#include <hip/hip_runtime.h>
#include <math.h>

#define TT 2048   // tokens
#define NP 2048   // num params (N)
#define BB 8      // batch
#define DD 512    // d_model = kdim = vdim

#define LOG_A (-7.6246189861593985f)  // -log(2048)
#define CC 30.0f                       // E = exp(CC - dist) shift
#define E30 1.0686475e13f              // exp(30)
#define K0U 5.2180055e9f               // exp(30)/2048

typedef __attribute__((ext_vector_type(8))) _Float16 f16x8;
typedef __attribute__((ext_vector_type(4))) _Float16 f16x4;
typedef __attribute__((ext_vector_type(4))) float f32x4;

#define MFMA_F16(a, b, c)  __builtin_amdgcn_mfma_f32_16x16x32_f16((a), (b), (c), 0, 0, 0)

// ---------------------------------------------------------------------------
// helpers
// ---------------------------------------------------------------------------
__device__ __forceinline__ float f16u2f(unsigned short u) {
    union { unsigned short s; _Float16 h; } v; v.s = u;
    return (float)v.h;
}

// async global->LDS, 16B per lane (wave-uniform LDS base + lane*16, per-lane src)
__device__ __forceinline__ void gload16(const void* g, void* l) {
    __builtin_amdgcn_global_load_lds(
        (const __attribute__((address_space(1))) void*)g,
        (__attribute__((address_space(3))) void*)l, 16, 0, 0);
}

// ---------------------------------------------------------------------------
// LDS tile layout, "k-group-major": tile[s][r][8 elems], s = k-subgroup
// (0..3 => BK=32), r = row (0..127). Byte off = s*2048 + r*16.
// A-frag (16x16x32): lane holds A[m=lane%16][k=(lane/16)*8+j]
// B-frag:            lane holds B[k=(lane/16)*8+j][n=lane%16]  (B stored [N][K])
// C/D:               col=lane&15, row=(lane>>4)*4+reg   [m89-verified]
// ---------------------------------------------------------------------------
__device__ __forceinline__ void frag_step_f16(
    const _Float16* sA, const _Float16* sB,
    int lane, int wm, int wn, f32x4 acc[4][4])
{
    const int sb = (lane >> 4) << 11;
    const int rl = (lane & 15) << 4;
    f16x8 a[4], b[4];
    #pragma unroll
    for (int i = 0; i < 4; ++i) {
        a[i] = *(const f16x8*)((const char*)sA + sb + ((wm + i * 16) << 4) + rl);
        b[i] = *(const f16x8*)((const char*)sB + sb + ((wn + i * 16) << 4) + rl);
    }
    #pragma unroll
    for (int i = 0; i < 4; ++i)
        #pragma unroll
        for (int j = 0; j < 4; ++j)
            acc[i][j] = MFMA_F16(a[i], b[j], acc[i][j]);
}

__device__ __forceinline__ void zero_acc(f32x4 acc[4][4]) {
    #pragma unroll
    for (int i = 0; i < 4; ++i)
        #pragma unroll
        for (int j = 0; j < 4; ++j)
            acc[i][j] = (f32x4){0.f, 0.f, 0.f, 0.f};
}

__device__ __forceinline__ void store_plain(
    float* C, int N, int row0, int col0, int lane, int wm, int wn, f32x4 acc[4][4])
{
    #pragma unroll
    for (int i = 0; i < 4; ++i)
        #pragma unroll
        for (int j = 0; j < 4; ++j) {
            int colg = col0 + wn + j * 16 + (lane & 15);
            int rowb = row0 + wm + i * 16 + ((lane >> 4) << 2);
            #pragma unroll
            for (int r = 0; r < 4; ++r)
                C[(size_t)(rowb + r) * N + colg] = acc[i][j][r];
        }
}

// ---------------------------------------------------------------------------
// Transpose 3 weights to fp16 in ONE launch. Grid (8,8,3).
// ---------------------------------------------------------------------------
__global__ __launch_bounds__(256) void transpose3_f16(
    const float* __restrict__ X0, const float* __restrict__ X1,
    const float* __restrict__ X2, _Float16* __restrict__ o0,
    _Float16* __restrict__ o1, _Float16* __restrict__ o2)
{
    const int z = blockIdx.z;
    const float* Xb = (z == 0) ? X0 : (z == 1) ? X1 : X2;
    _Float16* ob = (z == 0) ? o0 : (z == 1) ? o1 : o2;
    __shared__ float t[64][65];
    const int bx = blockIdx.x * 64;
    const int by = blockIdx.y * 64;
    const int tx = threadIdx.x & 63, ty = threadIdx.x >> 6;
    #pragma unroll
    for (int r = ty; r < 64; r += 4)
        t[r][tx] = Xb[(size_t)(by + r) * 512 + bx + tx];
    __syncthreads();
    #pragma unroll
    for (int r = ty; r < 64; r += 4)
        ob[(size_t)(bx + r) * 512 + by + tx] = (_Float16)t[tx][r];
}

// ---------------------------------------------------------------------------
// Merged q+k projection GEMM (NT, fp16). Grid (4, 144).
// ---------------------------------------------------------------------------
__global__ __launch_bounds__(256) void gemm_projqk_f16(
    const float* __restrict__ Aq, const float* __restrict__ Ak,
    const _Float16* __restrict__ Btq, const _Float16* __restrict__ Btk,
    _Float16* __restrict__ C)
{
    const int by = blockIdx.y;
    const bool isq = (by < 16);
    const float* A = isq ? Aq : Ak;
    const _Float16* Bt = isq ? Btq : Btk;
    const int arow0 = isq ? by * 128 : (by - 16) * 128;
    const int crow0 = by * 128;
    const int col0 = blockIdx.x * 128;

    __shared__ __attribute__((aligned(16))) _Float16 sA[4096], sB[4096];
    const int tid = threadIdx.x;
    const int lane = tid & 63;
    const int wm = ((tid >> 7) & 1) * 64;
    const int wn = ((tid >> 6) & 1) * 64;
    f32x4 acc[4][4];
    zero_acc(acc);

    for (int k0 = 0; k0 < DD; k0 += 32) {
        __syncthreads();
        #pragma unroll
        for (int q = 0; q < 2; ++q) {
            int o = (tid + (q << 8)) << 4;
            int s = o >> 11;
            int r = (o & 2047) >> 4;
            gload16(Bt + (size_t)(col0 + r) * DD + k0 + s * 8, (char*)sB + o);
            const float* src = A + (size_t)(arow0 + r) * DD + k0 + s * 8;
            float4 f0 = *(const float4*)src;
            float4 f1 = *(const float4*)(src + 4);
            _Float16 hs[8] = {(_Float16)f0.x, (_Float16)f0.y,
                              (_Float16)f0.z, (_Float16)f0.w,
                              (_Float16)f1.x, (_Float16)f1.y,
                              (_Float16)f1.z, (_Float16)f1.w};
            *(f16x8*)((char*)sA + o) = *(f16x8*)hs;
        }
        __syncthreads();
        frag_step_f16(sA, sB, lane, wm, wn, acc);
    }
    #pragma unroll
    for (int i = 0; i < 4; ++i)
        #pragma unroll
        for (int j = 0; j < 4; ++j) {
            int colg = col0 + wn + j * 16 + (lane & 15);
            int rowb = crow0 + wm + i * 16 + ((lane >> 4) << 2);
            #pragma unroll
            for (int r = 0; r < 4; ++r)
                C[(size_t)(rowb + r) * DD + colg] = (_Float16)acc[i][j][r];
        }
}

// ---------------------------------------------------------------------------
// v projection GEMM (NT, fp16): writes vpT per-batch transposed directly.
// ---------------------------------------------------------------------------
__global__ __launch_bounds__(256) void gemm_projv_f16(
    const float* __restrict__ A, const _Float16* __restrict__ Bt,
    _Float16* __restrict__ C)
{
    __shared__ __attribute__((aligned(16))) _Float16 sA[4096], sB[4096];
    const int tid = threadIdx.x;
    const int lane = tid & 63;
    const int row0 = blockIdx.y * 128;
    const int col0 = blockIdx.x * 128;
    const int wm = ((tid >> 7) & 1) * 64;
    const int wn = ((tid >> 6) & 1) * 64;
    f32x4 acc[4][4];
    zero_acc(acc);

    for (int k0 = 0; k0 < DD; k0 += 32) {
        __syncthreads();
        #pragma unroll
        for (int q = 0; q < 2; ++q) {
            int o = (tid + (q << 8)) << 4;
            int s = o >> 11;
            int r = (o & 2047) >> 4;
            gload16(Bt + (size_t)(col0 + r) * DD + k0 + s * 8, (char*)sB + o);
            const float* src = A + (size_t)(row0 + r) * DD + k0 + s * 8;
            float4 f0 = *(const float4*)src;
            float4 f1 = *(const float4*)(src + 4);
            _Float16 hs[8] = {(_Float16)f0.x, (_Float16)f0.y,
                              (_Float16)f0.z, (_Float16)f0.w,
                              (_Float16)f1.x, (_Float16)f1.y,
                              (_Float16)f1.z, (_Float16)f1.w};
            *(f16x8*)((char*)sA + o) = *(f16x8*)hs;
        }
        __syncthreads();
        frag_step_f16(sA, sB, lane, wm, wn, acc);
    }
    #pragma unroll
    for (int i = 0; i < 4; ++i)
        #pragma unroll
        for (int j = 0; j < 4; ++j) {
            int colg = col0 + wn + j * 16 + (lane & 15);
            int rowb = row0 + wm + i * 16 + ((lane >> 4) << 2);
            int b = rowb >> 11;
            int n0 = rowb & (NP - 1);
            _Float16 h4[4];
            #pragma unroll
            for (int r = 0; r < 4; ++r) h4[r] = (_Float16)acc[i][j][r];
            *(f16x4*)(C + (size_t)b * DD * NP + (size_t)colg * NP + n0) =
                *(f16x4*)h4;
        }
}

// ---------------------------------------------------------------------------
// Row squared-norm from fp16 (merged qp+kp). One wave per row.
// ---------------------------------------------------------------------------
__global__ __launch_bounds__(256) void rownorm_f16(
    const _Float16* __restrict__ X, float* __restrict__ o, int rows)
{
    int w = blockIdx.x * 4 + (threadIdx.x >> 6);
    int lane = threadIdx.x & 63;
    if (w >= rows) return;
    f16x8 v = *(const f16x8*)(X + (size_t)w * DD + lane * 8);
    float s = 0.f;
    #pragma unroll
    for (int j = 0; j < 8; ++j) {
        float x = (float)v[j];
        s = fmaf(x, x, s);
    }
    #pragma unroll
    for (int off = 32; off; off >>= 1) s += __shfl_down(s, off, 64);
    if (lane == 0) o[w] = s;
}

// ---------------------------------------------------------------------------
// Cost GEMM (NT, fp16, 3-buffer counted-vmcnt pipeline) + FUSED first-u
// colsum: epilogue also writes ps16[b][by][n] = sum over this block's 128
// rows of E (Y0 = 1). Each (b,by,n) is written by exactly one block.
// ---------------------------------------------------------------------------
__global__ __launch_bounds__(256) void gemm_cost_f16(
    const _Float16* __restrict__ A, const _Float16* __restrict__ B,
    const float* __restrict__ q2, const float* __restrict__ k2,
    _Float16* __restrict__ E, float* __restrict__ ps16)
{
    const int bid = blockIdx.x;
    const int sid = ((bid & 7) << 8) | (bid >> 3);
    const int b  = sid >> 8;
    const int by = (sid >> 4) & 15;
    const int bx = sid & 15;

    const _Float16* Bb = B + (size_t)b * NP * DD;
    const float* k2b = k2 + (size_t)b * NP;
    _Float16* Cb = E + (size_t)b * TT * NP;

    __shared__ __attribute__((aligned(16))) _Float16 sA[3][4096], sB[3][4096];
    __shared__ float colbuf[2][128];
    const int tid = threadIdx.x;
    const int lane = tid & 63;
    const int row0 = by * 128;   // t
    const int col0 = bx * 128;   // n
    const int wm = ((tid >> 7) & 1) * 64;
    const int wn = ((tid >> 6) & 1) * 64;
    f32x4 acc[4][4];
    zero_acc(acc);

    auto STAGE = [&](int buf, int k0) {
        #pragma unroll
        for (int q = 0; q < 2; ++q) {
            int o = (tid + (q << 8)) << 4;
            int s = o >> 11;
            int r = (o & 2047) >> 4;
            gload16(A + (size_t)(row0 + r) * DD + k0 + s * 8, (char*)&sA[buf][0] + o);
            gload16(Bb + (size_t)(col0 + r) * DD + k0 + s * 8, (char*)&sB[buf][0] + o);
        }
    };

    STAGE(0, 0);
    STAGE(1, 32);
    #pragma unroll
    for (int s = 0; s < 14; ++s) {
        asm volatile("s_waitcnt vmcnt(4)" ::: "memory");
        __builtin_amdgcn_s_barrier();
        __builtin_amdgcn_sched_barrier(0);
        STAGE((s + 2) % 3, (s + 2) * 32);
        frag_step_f16(&sA[s % 3][0], &sB[s % 3][0], lane, wm, wn, acc);
    }
    asm volatile("s_waitcnt vmcnt(4)" ::: "memory");
    __builtin_amdgcn_s_barrier();
    __builtin_amdgcn_sched_barrier(0);
    frag_step_f16(&sA[2][0], &sB[2][0], lane, wm, wn, acc);
    asm volatile("s_waitcnt vmcnt(0)" ::: "memory");
    __builtin_amdgcn_s_barrier();
    __builtin_amdgcn_sched_barrier(0);
    frag_step_f16(&sA[0][0], &sB[0][0], lane, wm, wn, acc);

    // epilogue: E stores (scattered, R12-proven) + per-lane colsum
    float csum[4] = {0.f, 0.f, 0.f, 0.f};
    #pragma unroll
    for (int i = 0; i < 4; ++i)
        #pragma unroll
        for (int j = 0; j < 4; ++j) {
            int colg = col0 + wn + j * 16 + (lane & 15);
            float k2v = k2b[colg];
            int rowb = row0 + wm + i * 16 + ((lane >> 4) << 2);
            #pragma unroll
            for (int r = 0; r < 4; ++r) {
                float sq = q2[rowb + r] + k2v - 2.f * acc[i][j][r];
                float dist = sqrtf(fmaxf(sq, 0.f));
                float e = fminf(__expf(CC - dist), 60000.f);
                csum[j] += e;
                Cb[(size_t)(rowb + r) * NP + colg] = (_Float16)e;
            }
        }
    // reduce the 4 lanes (lane>>4 groups) sharing each column
    #pragma unroll
    for (int j = 0; j < 4; ++j) {
        float s = csum[j];
        s += __shfl_down(s, 32, 64);
        s += __shfl_down(s, 16, 64);
        if (lane < 16)
            colbuf[wm >> 6][wn + j * 16 + lane] = s;
    }
    __syncthreads();
    if (tid < 128)
        ps16[((size_t)b * 16 + by) * NP + col0 + tid] =
            colbuf[0][tid] + colbuf[1][tid];
}

// ---------------------------------------------------------------------------
// Fused Sinkhorn pass: block = 32 rows x 2048 cols. Per 8-row group:
// S_t = sum E*U -> Y = E30/S (in-kernel), then colsum E*Y -> ps[b][chunk][n].
// Grid (TT/32, BB) = 512 blocks, 64 chunks.
// ---------------------------------------------------------------------------
__global__ __launch_bounds__(256) void sink_fused(
    const _Float16* __restrict__ E, const float* __restrict__ U,
    float* __restrict__ ps)
{
    const int b = blockIdx.y;
    const int t0 = blockIdx.x * 32;
    const int tid = threadIdx.x;
    const int n0 = tid * 8;
    const _Float16* Eb = E + ((size_t)b * TT + t0) * NP;

    float u8[8];
    {
        float4 a = *(const float4*)(U + (size_t)b * NP + n0);
        float4 c = *(const float4*)(U + (size_t)b * NP + n0 + 4);
        u8[0] = a.x; u8[1] = a.y; u8[2] = a.z; u8[3] = a.w;
        u8[4] = c.x; u8[5] = c.y; u8[6] = c.z; u8[7] = c.w;
    }

    float cs[8] = {0.f, 0.f, 0.f, 0.f, 0.f, 0.f, 0.f, 0.f};
    __shared__ float red[8][256];
    __shared__ float yy[8];

    #pragma unroll
    for (int g = 0; g < 4; ++g) {
        uint4 ev[8];
        #pragma unroll
        for (int r = 0; r < 8; ++r)
            ev[r] = *(const uint4*)(Eb + (size_t)(g * 8 + r) * NP + n0);

        #pragma unroll
        for (int r = 0; r < 8; ++r) {
            float d = 0.f;
            d = fmaf(f16u2f((unsigned short)(ev[r].x & 0xFFFFu)), u8[0], d);
            d = fmaf(f16u2f((unsigned short)(ev[r].x >> 16)),     u8[1], d);
            d = fmaf(f16u2f((unsigned short)(ev[r].y & 0xFFFFu)), u8[2], d);
            d = fmaf(f16u2f((unsigned short)(ev[r].y >> 16)),     u8[3], d);
            d = fmaf(f16u2f((unsigned short)(ev[r].z & 0xFFFFu)), u8[4], d);
            d = fmaf(f16u2f((unsigned short)(ev[r].z >> 16)),     u8[5], d);
            d = fmaf(f16u2f((unsigned short)(ev[r].w & 0xFFFFu)), u8[6], d);
            d = fmaf(f16u2f((unsigned short)(ev[r].w >> 16)),     u8[7], d);
            red[r][tid] = d;
        }
        __syncthreads();
        {
            int w = tid >> 6, lane = tid & 63;
            #pragma unroll
            for (int rr = 0; rr < 2; ++rr) {
                int r = w * 2 + rr;
                float s = red[r][lane] + red[r][lane + 64] +
                          red[r][lane + 128] + red[r][lane + 192];
                #pragma unroll
                for (int off = 32; off; off >>= 1)
                    s += __shfl_down(s, off, 64);
                if (lane == 0) yy[r] = E30 / s;
            }
        }
        __syncthreads();
        #pragma unroll
        for (int r = 0; r < 8; ++r) {
            float yv = yy[r];
            cs[0] = fmaf(f16u2f((unsigned short)(ev[r].x & 0xFFFFu)), yv, cs[0]);
            cs[1] = fmaf(f16u2f((unsigned short)(ev[r].x >> 16)),     yv, cs[1]);
            cs[2] = fmaf(f16u2f((unsigned short)(ev[r].y & 0xFFFFu)), yv, cs[2]);
            cs[3] = fmaf(f16u2f((unsigned short)(ev[r].y >> 16)),     yv, cs[3]);
            cs[4] = fmaf(f16u2f((unsigned short)(ev[r].z & 0xFFFFu)), yv, cs[4]);
            cs[5] = fmaf(f16u2f((unsigned short)(ev[r].z >> 16)),     yv, cs[5]);
            cs[6] = fmaf(f16u2f((unsigned short)(ev[r].w & 0xFFFFu)), yv, cs[6]);
            cs[7] = fmaf(f16u2f((unsigned short)(ev[r].w >> 16)),     yv, cs[7]);
        }
        __syncthreads();
    }

    size_t o = ((size_t)b * 64 + blockIdx.x) * NP + n0;
    *(float4*)(ps + o)     = make_float4(cs[0], cs[1], cs[2], cs[3]);
    *(float4*)(ps + o + 4) = make_float4(cs[4], cs[5], cs[6], cs[7]);
}

// ---------------------------------------------------------------------------
// u combine: U[b,n] = K0U / sum_chunks ps. NCH = 16 (from cost) or 64.
// ---------------------------------------------------------------------------
template<int NCH>
__global__ __launch_bounds__(256) void u_combine(
    const float* __restrict__ ps, float* __restrict__ U)
{
    int gid = blockIdx.x * 256 + threadIdx.x;     // over BB*NP
    int b = gid >> 11;
    int n = gid & (NP - 1);
    float S = 0.f;
    #pragma unroll 8
    for (int c = 0; c < NCH; ++c)
        S += ps[((size_t)b * NCH + c) * NP + n];
    U[gid] = K0U / S;
}

// ---------------------------------------------------------------------------
// Final v pass: S_t = sum_n E*U;  P[t,n] = E*U/S as f16. One block per row.
// ---------------------------------------------------------------------------
__global__ __launch_bounds__(256) void v_final(
    const _Float16* __restrict__ E, const float* __restrict__ U,
    _Float16* __restrict__ P)
{
    const int b = blockIdx.y;
    const int t = blockIdx.x;
    const uint4* Eb = (const uint4*)(E + ((size_t)b * TT + t) * NP);
    const float* Ub = U + (size_t)b * NP;
    const int tid = threadIdx.x;

    uint4 w = Eb[tid];
    const int n0 = tid * 8;
    float4 u0 = *(const float4*)(Ub + n0);
    float4 u1 = *(const float4*)(Ub + n0 + 4);
    float ev[8];
    ev[0] = f16u2f((unsigned short)(w.x & 0xFFFFu));
    ev[1] = f16u2f((unsigned short)(w.x >> 16));
    ev[2] = f16u2f((unsigned short)(w.y & 0xFFFFu));
    ev[3] = f16u2f((unsigned short)(w.y >> 16));
    ev[4] = f16u2f((unsigned short)(w.z & 0xFFFFu));
    ev[5] = f16u2f((unsigned short)(w.z >> 16));
    ev[6] = f16u2f((unsigned short)(w.w & 0xFFFFu));
    ev[7] = f16u2f((unsigned short)(w.w >> 16));
    float uv[8] = {u0.x, u0.y, u0.z, u0.w, u1.x, u1.y, u1.z, u1.w};

    float s = 0.f;
    #pragma unroll
    for (int j = 0; j < 8; ++j) s = fmaf(ev[j], uv[j], s);
    #pragma unroll
    for (int off = 32; off; off >>= 1) s += __shfl_down(s, off, 64);

    __shared__ float sw[4];
    __shared__ float Sall;
    if ((tid & 63) == 0) sw[tid >> 6] = s;
    __syncthreads();
    if (tid == 0) Sall = sw[0] + sw[1] + sw[2] + sw[3];
    __syncthreads();
    float invS = 1.0f / Sall;
    _Float16 hp[8];
    #pragma unroll
    for (int j = 0; j < 8; ++j)
        hp[j] = (_Float16)(ev[j] * uv[j] * invS);
    *(f16x8*)(P + ((size_t)b * TT + t) * NP + n0) = *(f16x8*)hp;
}

// ---------------------------------------------------------------------------
// pi GEMM (NT, pure fp16, 3-buffer counted-vmcnt pipeline, 64 K-steps):
//   out[b,t,d] = sum_n P[b,t,n] * vpT[b,d,n]
// 1-D grid, XCD-chunked swizzle (one batch per XCD).
// ---------------------------------------------------------------------------
__global__ __launch_bounds__(256) void gemm_pi_f16(
    const _Float16* __restrict__ P, const _Float16* __restrict__ B,
    float* __restrict__ out)
{
    const int bid = blockIdx.x;
    const int sid = ((bid & 7) << 6) | (bid >> 3);   // 512 blocks, 64/XCD
    const int b  = sid >> 6;
    const int by = (sid >> 2) & 15;
    const int bx = sid & 3;

    const _Float16* Pb = P + (size_t)b * TT * NP;
    const _Float16* Bb = B + (size_t)b * DD * NP;
    float* Cb = out + (size_t)b * TT * DD;

    __shared__ __attribute__((aligned(16))) _Float16 sA[3][4096], sB[3][4096];
    const int tid = threadIdx.x;
    const int lane = tid & 63;
    const int row0 = by * 128;   // t
    const int col0 = bx * 128;   // d
    const int wm = ((tid >> 7) & 1) * 64;
    const int wn = ((tid >> 6) & 1) * 64;
    f32x4 acc[4][4];
    zero_acc(acc);

    auto STAGE = [&](int buf, int k0) {
        #pragma unroll
        for (int q = 0; q < 2; ++q) {
            int o = (tid + (q << 8)) << 4;
            int s = o >> 11;
            int r = (o & 2047) >> 4;
            gload16(Pb + (size_t)(row0 + r) * NP + k0 + s * 8, (char*)&sA[buf][0] + o);
            gload16(Bb + (size_t)(col0 + r) * NP + k0 + s * 8, (char*)&sB[buf][0] + o);
        }
    };

    #define PI_STEP(BUFC, BUFS, KS)                               \
        asm volatile("s_waitcnt vmcnt(4)" ::: "memory");          \
        __builtin_amdgcn_s_barrier();                             \
        __builtin_amdgcn_sched_barrier(0);                        \
        STAGE(BUFS, (KS) * 32);                                   \
        frag_step_f16(&sA[BUFC][0], &sB[BUFC][0], lane, wm, wn, acc);

    STAGE(0, 0);
    STAGE(1, 32);
    for (int s3 = 0; s3 < 60; s3 += 3) {
        PI_STEP(0, 2, s3 + 2)
        PI_STEP(1, 0, s3 + 3)
        PI_STEP(2, 1, s3 + 4)
    }
    PI_STEP(0, 2, 62)      // s = 60
    PI_STEP(1, 0, 63)      // s = 61
    // s = 62: consume buf2 (63-tile still in flight)
    asm volatile("s_waitcnt vmcnt(4)" ::: "memory");
    __builtin_amdgcn_s_barrier();
    __builtin_amdgcn_sched_barrier(0);
    frag_step_f16(&sA[2][0], &sB[2][0], lane, wm, wn, acc);
    // s = 63: drain
    asm volatile("s_waitcnt vmcnt(0)" ::: "memory");
    __builtin_amdgcn_s_barrier();
    __builtin_amdgcn_sched_barrier(0);
    frag_step_f16(&sA[0][0], &sB[0][0], lane, wm, wn, acc);
    #undef PI_STEP

    store_plain(Cb, DD, row0, col0, lane, wm, wn, acc);
}

// ---------------------------------------------------------------------------
extern "C" void kernel_launch(void* const* d_in, const int* in_sizes, int n_in,
                              void* d_out, int out_size, void* d_ws, size_t ws_size,
                              hipStream_t stream)
{
    const float* q  = (const float*)d_in[0];
    const float* k  = (const float*)d_in[1];
    const float* v  = (const float*)d_in[2];
    const float* Qw = (const float*)d_in[3];
    const float* Kw = (const float*)d_in[4];
    const float* Vw = (const float*)d_in[5];
    float* out = (float*)d_out;

    // ---- workspace: ~135 MiB ----
    char* base = (char*)d_ws;
    _Float16* E16 = (_Float16*)base;                                // 64 MiB @ 0
    char* p2 = base + (size_t)BB * TT * NP * 2;
    _Float16* P   = (_Float16*)p2; p2 += (size_t)BB * TT * NP * 2;  // 32 MiB
    _Float16* qpf = (_Float16*)p2; p2 += (size_t)TT * DD * 2;       //  2 MiB
    _Float16* kpf = (_Float16*)p2; p2 += (size_t)BB * NP * DD * 2;  // 16 MiB
    _Float16* vpt = (_Float16*)p2; p2 += (size_t)BB * DD * NP * 2;  // 16 MiB (vpT)
    float* q2 = (float*)p2; p2 += (size_t)TT * 4;
    float* k2 = (float*)p2; p2 += (size_t)BB * NP * 4;
    float* U  = (float*)p2; p2 += (size_t)BB * NP * 4;
    float* ps = (float*)p2; p2 += (size_t)BB * 64 * NP * 4;         // 4 MiB

    // weight f16 temporaries aliased INSIDE E16 (dead before E16 is written):
    _Float16* wq = (_Float16*)base;                 // 3 x 512 KiB
    _Float16* wk = wq + 262144;
    _Float16* wv = wk + 262144;

    dim3 blk(256);

    // Weights: transpose to f16, single launch
    transpose3_f16<<<dim3(8, 8, 3), blk, 0, stream>>>(Qw, Kw, Vw, wq, wk, wv);

    // Projections: q+k merged; v -> vpT direct
    gemm_projqk_f16<<<dim3(4, 144, 1), blk, 0, stream>>>(q, k, wq, wk, qpf);
    gemm_projv_f16<<<dim3(4, 128, 1), blk, 0, stream>>>(v, wv, vpt);

    // Squared norms, merged
    rownorm_f16<<<dim3((TT + BB * NP) / 4), blk, 0, stream>>>(qpf, q2, TT + BB * NP);

    // Cost matrix -> E16 + fused first-u colsum (ps16, Y0 = 1)
    gemm_cost_f16<<<dim3(2048), blk, 0, stream>>>(qpf, kpf, q2, k2, E16, ps);

    // Sinkhorn: 5 E-passes total (colsum fused in cost, 4 fused v+u, final v+P)
    u_combine<16><<<dim3(BB * NP / 256), blk, 0, stream>>>(ps, U);
    for (int it = 0; it < 4; ++it) {
        sink_fused<<<dim3(TT / 32, BB), blk, 0, stream>>>(E16, U, ps);
        u_combine<64><<<dim3(BB * NP / 256), blk, 0, stream>>>(ps, U);
    }
    v_final<<<dim3(TT, BB), blk, 0, stream>>>(E16, U, P);

    // out = P @ vp (pure fp16 MFMA, counted-vmcnt pipeline)
    gemm_pi_f16<<<dim3(512), blk, 0, stream>>>(P, vpt, out);
}

// Round 16
// 379.402 us; speedup vs baseline: 4.4338x; 1.0124x over previous
//
#include <hip/hip_runtime.h>
#include <math.h>

#define TT 2048   // tokens
#define NP 2048   // num params (N)
#define BB 8      // batch
#define DD 512    // d_model = kdim = vdim

#define LOG_A (-7.6246189861593985f)  // -log(2048)
#define CC 30.0f                       // E = exp(CC - dist) shift
#define E30 1.0686475e13f              // exp(30)
#define K0U 5.2180055e9f               // exp(30)/2048

typedef __attribute__((ext_vector_type(8))) _Float16 f16x8;
typedef __attribute__((ext_vector_type(4))) _Float16 f16x4;
typedef __attribute__((ext_vector_type(4))) float f32x4;

#define MFMA_F16(a, b, c)  __builtin_amdgcn_mfma_f32_16x16x32_f16((a), (b), (c), 0, 0, 0)

// ---------------------------------------------------------------------------
// helpers
// ---------------------------------------------------------------------------
__device__ __forceinline__ float f16u2f(unsigned short u) {
    union { unsigned short s; _Float16 h; } v; v.s = u;
    return (float)v.h;
}

// async global->LDS, 16B per lane (wave-uniform LDS base + lane*16, per-lane src)
__device__ __forceinline__ void gload16(const void* g, void* l) {
    __builtin_amdgcn_global_load_lds(
        (const __attribute__((address_space(1))) void*)g,
        (__attribute__((address_space(3))) void*)l, 16, 0, 0);
}

// ---------------------------------------------------------------------------
// LDS tile layout, "k-group-major": tile[s][r][8 elems], s = k-subgroup
// (0..3 => BK=32), r = row (0..127). Byte off = s*2048 + r*16.
// A-frag (16x16x32): lane holds A[m=lane%16][k=(lane/16)*8+j]
// B-frag:            lane holds B[k=(lane/16)*8+j][n=lane%16]  (B stored [N][K])
// C/D:               col=lane&15, row=(lane>>4)*4+reg   [m89-verified]
// ---------------------------------------------------------------------------
__device__ __forceinline__ void frag_step_f16(
    const _Float16* sA, const _Float16* sB,
    int lane, int wm, int wn, f32x4 acc[4][4])
{
    const int sb = (lane >> 4) << 11;
    const int rl = (lane & 15) << 4;
    f16x8 a[4], b[4];
    #pragma unroll
    for (int i = 0; i < 4; ++i) {
        a[i] = *(const f16x8*)((const char*)sA + sb + ((wm + i * 16) << 4) + rl);
        b[i] = *(const f16x8*)((const char*)sB + sb + ((wn + i * 16) << 4) + rl);
    }
    #pragma unroll
    for (int i = 0; i < 4; ++i)
        #pragma unroll
        for (int j = 0; j < 4; ++j)
            acc[i][j] = MFMA_F16(a[i], b[j], acc[i][j]);
}

__device__ __forceinline__ void zero_acc(f32x4 acc[4][4]) {
    #pragma unroll
    for (int i = 0; i < 4; ++i)
        #pragma unroll
        for (int j = 0; j < 4; ++j)
            acc[i][j] = (f32x4){0.f, 0.f, 0.f, 0.f};
}

__device__ __forceinline__ void store_plain(
    float* C, int N, int row0, int col0, int lane, int wm, int wn, f32x4 acc[4][4])
{
    #pragma unroll
    for (int i = 0; i < 4; ++i)
        #pragma unroll
        for (int j = 0; j < 4; ++j) {
            int colg = col0 + wn + j * 16 + (lane & 15);
            int rowb = row0 + wm + i * 16 + ((lane >> 4) << 2);
            #pragma unroll
            for (int r = 0; r < 4; ++r)
                C[(size_t)(rowb + r) * N + colg] = acc[i][j][r];
        }
}

// ---------------------------------------------------------------------------
// Transpose 3 weights to fp16 in ONE launch. Grid (8,8,3).
// ---------------------------------------------------------------------------
__global__ __launch_bounds__(256) void transpose3_f16(
    const float* __restrict__ X0, const float* __restrict__ X1,
    const float* __restrict__ X2, _Float16* __restrict__ o0,
    _Float16* __restrict__ o1, _Float16* __restrict__ o2)
{
    const int z = blockIdx.z;
    const float* Xb = (z == 0) ? X0 : (z == 1) ? X1 : X2;
    _Float16* ob = (z == 0) ? o0 : (z == 1) ? o1 : o2;
    __shared__ float t[64][65];
    const int bx = blockIdx.x * 64;
    const int by = blockIdx.y * 64;
    const int tx = threadIdx.x & 63, ty = threadIdx.x >> 6;
    #pragma unroll
    for (int r = ty; r < 64; r += 4)
        t[r][tx] = Xb[(size_t)(by + r) * 512 + bx + tx];
    __syncthreads();
    #pragma unroll
    for (int r = ty; r < 64; r += 4)
        ob[(size_t)(bx + r) * 512 + by + tx] = (_Float16)t[tx][r];
}

// ---------------------------------------------------------------------------
// Merged q+k projection GEMM (NT, fp16), 2-phase dbuf prefetch. Grid (4,144).
// ---------------------------------------------------------------------------
__global__ __launch_bounds__(256) void gemm_projqk_f16(
    const float* __restrict__ Aq, const float* __restrict__ Ak,
    const _Float16* __restrict__ Btq, const _Float16* __restrict__ Btk,
    _Float16* __restrict__ C)
{
    const int by = blockIdx.y;
    const bool isq = (by < 16);
    const float* A = isq ? Aq : Ak;
    const _Float16* Bt = isq ? Btq : Btk;
    const int arow0 = isq ? by * 128 : (by - 16) * 128;
    const int crow0 = by * 128;
    const int col0 = blockIdx.x * 128;

    __shared__ __attribute__((aligned(16))) _Float16 sA[2][4096], sB[2][4096];
    const int tid = threadIdx.x;
    const int lane = tid & 63;
    const int wm = ((tid >> 7) & 1) * 64;
    const int wn = ((tid >> 6) & 1) * 64;
    f32x4 acc[4][4];
    zero_acc(acc);

    auto STAGE = [&](int buf, int k0) {
        #pragma unroll
        for (int q = 0; q < 2; ++q) {
            int o = (tid + (q << 8)) << 4;
            int s = o >> 11;
            int r = (o & 2047) >> 4;
            gload16(Bt + (size_t)(col0 + r) * DD + k0 + s * 8, (char*)&sB[buf][0] + o);
            const float* src = A + (size_t)(arow0 + r) * DD + k0 + s * 8;
            float4 f0 = *(const float4*)src;
            float4 f1 = *(const float4*)(src + 4);
            _Float16 hs[8] = {(_Float16)f0.x, (_Float16)f0.y,
                              (_Float16)f0.z, (_Float16)f0.w,
                              (_Float16)f1.x, (_Float16)f1.y,
                              (_Float16)f1.z, (_Float16)f1.w};
            *(f16x8*)((char*)&sA[buf][0] + o) = *(f16x8*)hs;
        }
    };

    STAGE(0, 0);
    __syncthreads();
    int cur = 0;
    for (int k0 = 0; k0 < DD; k0 += 32) {
        if (k0 + 32 < DD) STAGE(cur ^ 1, k0 + 32);
        frag_step_f16(&sA[cur][0], &sB[cur][0], lane, wm, wn, acc);
        __syncthreads();
        cur ^= 1;
    }
    #pragma unroll
    for (int i = 0; i < 4; ++i)
        #pragma unroll
        for (int j = 0; j < 4; ++j) {
            int colg = col0 + wn + j * 16 + (lane & 15);
            int rowb = crow0 + wm + i * 16 + ((lane >> 4) << 2);
            #pragma unroll
            for (int r = 0; r < 4; ++r)
                C[(size_t)(rowb + r) * DD + colg] = (_Float16)acc[i][j][r];
        }
}

// ---------------------------------------------------------------------------
// v projection GEMM (NT, fp16), 2-phase dbuf prefetch: writes vpT directly.
// ---------------------------------------------------------------------------
__global__ __launch_bounds__(256) void gemm_projv_f16(
    const float* __restrict__ A, const _Float16* __restrict__ Bt,
    _Float16* __restrict__ C)
{
    __shared__ __attribute__((aligned(16))) _Float16 sA[2][4096], sB[2][4096];
    const int tid = threadIdx.x;
    const int lane = tid & 63;
    const int row0 = blockIdx.y * 128;
    const int col0 = blockIdx.x * 128;
    const int wm = ((tid >> 7) & 1) * 64;
    const int wn = ((tid >> 6) & 1) * 64;
    f32x4 acc[4][4];
    zero_acc(acc);

    auto STAGE = [&](int buf, int k0) {
        #pragma unroll
        for (int q = 0; q < 2; ++q) {
            int o = (tid + (q << 8)) << 4;
            int s = o >> 11;
            int r = (o & 2047) >> 4;
            gload16(Bt + (size_t)(col0 + r) * DD + k0 + s * 8, (char*)&sB[buf][0] + o);
            const float* src = A + (size_t)(row0 + r) * DD + k0 + s * 8;
            float4 f0 = *(const float4*)src;
            float4 f1 = *(const float4*)(src + 4);
            _Float16 hs[8] = {(_Float16)f0.x, (_Float16)f0.y,
                              (_Float16)f0.z, (_Float16)f0.w,
                              (_Float16)f1.x, (_Float16)f1.y,
                              (_Float16)f1.z, (_Float16)f1.w};
            *(f16x8*)((char*)&sA[buf][0] + o) = *(f16x8*)hs;
        }
    };

    STAGE(0, 0);
    __syncthreads();
    int cur = 0;
    for (int k0 = 0; k0 < DD; k0 += 32) {
        if (k0 + 32 < DD) STAGE(cur ^ 1, k0 + 32);
        frag_step_f16(&sA[cur][0], &sB[cur][0], lane, wm, wn, acc);
        __syncthreads();
        cur ^= 1;
    }
    #pragma unroll
    for (int i = 0; i < 4; ++i)
        #pragma unroll
        for (int j = 0; j < 4; ++j) {
            int colg = col0 + wn + j * 16 + (lane & 15);
            int rowb = row0 + wm + i * 16 + ((lane >> 4) << 2);
            int b = rowb >> 11;
            int n0 = rowb & (NP - 1);
            _Float16 h4[4];
            #pragma unroll
            for (int r = 0; r < 4; ++r) h4[r] = (_Float16)acc[i][j][r];
            *(f16x4*)(C + (size_t)b * DD * NP + (size_t)colg * NP + n0) =
                *(f16x4*)h4;
        }
}

// ---------------------------------------------------------------------------
// Row squared-norm from fp16 (merged qp+kp). One wave per row.
// ---------------------------------------------------------------------------
__global__ __launch_bounds__(256) void rownorm_f16(
    const _Float16* __restrict__ X, float* __restrict__ o, int rows)
{
    int w = blockIdx.x * 4 + (threadIdx.x >> 6);
    int lane = threadIdx.x & 63;
    if (w >= rows) return;
    f16x8 v = *(const f16x8*)(X + (size_t)w * DD + lane * 8);
    float s = 0.f;
    #pragma unroll
    for (int j = 0; j < 8; ++j) {
        float x = (float)v[j];
        s = fmaf(x, x, s);
    }
    #pragma unroll
    for (int off = 32; off; off >>= 1) s += __shfl_down(s, off, 64);
    if (lane == 0) o[w] = s;
}

// ---------------------------------------------------------------------------
// Cost GEMM (NT, fp16, 3-buffer counted-vmcnt pipeline) + FUSED first-u
// colsum. Epilogue: dist via v_rsq (skips OCML correctly-rounded-sqrt
// fixup; err ~1e-7 rel, far below f16 E-quantization 5e-4).
// ---------------------------------------------------------------------------
__global__ __launch_bounds__(256) void gemm_cost_f16(
    const _Float16* __restrict__ A, const _Float16* __restrict__ B,
    const float* __restrict__ q2, const float* __restrict__ k2,
    _Float16* __restrict__ E, float* __restrict__ ps16)
{
    const int bid = blockIdx.x;
    const int sid = ((bid & 7) << 8) | (bid >> 3);
    const int b  = sid >> 8;
    const int by = (sid >> 4) & 15;
    const int bx = sid & 15;

    const _Float16* Bb = B + (size_t)b * NP * DD;
    const float* k2b = k2 + (size_t)b * NP;
    _Float16* Cb = E + (size_t)b * TT * NP;

    __shared__ __attribute__((aligned(16))) _Float16 sA[3][4096], sB[3][4096];
    __shared__ float colbuf[2][128];
    const int tid = threadIdx.x;
    const int lane = tid & 63;
    const int row0 = by * 128;   // t
    const int col0 = bx * 128;   // n
    const int wm = ((tid >> 7) & 1) * 64;
    const int wn = ((tid >> 6) & 1) * 64;
    f32x4 acc[4][4];
    zero_acc(acc);

    auto STAGE = [&](int buf, int k0) {
        #pragma unroll
        for (int q = 0; q < 2; ++q) {
            int o = (tid + (q << 8)) << 4;
            int s = o >> 11;
            int r = (o & 2047) >> 4;
            gload16(A + (size_t)(row0 + r) * DD + k0 + s * 8, (char*)&sA[buf][0] + o);
            gload16(Bb + (size_t)(col0 + r) * DD + k0 + s * 8, (char*)&sB[buf][0] + o);
        }
    };

    STAGE(0, 0);
    STAGE(1, 32);
    #pragma unroll
    for (int s = 0; s < 14; ++s) {
        asm volatile("s_waitcnt vmcnt(4)" ::: "memory");
        __builtin_amdgcn_s_barrier();
        __builtin_amdgcn_sched_barrier(0);
        STAGE((s + 2) % 3, (s + 2) * 32);
        frag_step_f16(&sA[s % 3][0], &sB[s % 3][0], lane, wm, wn, acc);
    }
    asm volatile("s_waitcnt vmcnt(4)" ::: "memory");
    __builtin_amdgcn_s_barrier();
    __builtin_amdgcn_sched_barrier(0);
    frag_step_f16(&sA[2][0], &sB[2][0], lane, wm, wn, acc);
    asm volatile("s_waitcnt vmcnt(0)" ::: "memory");
    __builtin_amdgcn_s_barrier();
    __builtin_amdgcn_sched_barrier(0);
    frag_step_f16(&sA[0][0], &sB[0][0], lane, wm, wn, acc);

    // epilogue: E stores (scattered, R12-proven) + per-lane colsum
    float csum[4] = {0.f, 0.f, 0.f, 0.f};
    #pragma unroll
    for (int i = 0; i < 4; ++i)
        #pragma unroll
        for (int j = 0; j < 4; ++j) {
            int colg = col0 + wn + j * 16 + (lane & 15);
            float k2v = k2b[colg];
            int rowb = row0 + wm + i * 16 + ((lane >> 4) << 2);
            #pragma unroll
            for (int r = 0; r < 4; ++r) {
                float sq = fmaxf(q2[rowb + r] + k2v - 2.f * acc[i][j][r], 0.f);
                float dist = sq * __frsqrt_rn(fmaxf(sq, 1e-20f));
                float e = fminf(__expf(CC - dist), 60000.f);
                csum[j] += e;
                Cb[(size_t)(rowb + r) * NP + colg] = (_Float16)e;
            }
        }
    // reduce the 4 lanes (lane>>4 groups) sharing each column
    #pragma unroll
    for (int j = 0; j < 4; ++j) {
        float s = csum[j];
        s += __shfl_down(s, 32, 64);
        s += __shfl_down(s, 16, 64);
        if (lane < 16)
            colbuf[wm >> 6][wn + j * 16 + lane] = s;
    }
    __syncthreads();
    if (tid < 128)
        ps16[((size_t)b * 16 + by) * NP + col0 + tid] =
            colbuf[0][tid] + colbuf[1][tid];
}

// ---------------------------------------------------------------------------
// Fused Sinkhorn pass: block = 32 rows x 2048 cols. Per 8-row group:
// S_t = sum E*U -> Y = E30/S (in-kernel), then colsum E*Y -> ps[b][chunk][n].
// Grid (TT/32, BB) = 512 blocks, 64 chunks.
// ---------------------------------------------------------------------------
__global__ __launch_bounds__(256) void sink_fused(
    const _Float16* __restrict__ E, const float* __restrict__ U,
    float* __restrict__ ps)
{
    const int b = blockIdx.y;
    const int t0 = blockIdx.x * 32;
    const int tid = threadIdx.x;
    const int n0 = tid * 8;
    const _Float16* Eb = E + ((size_t)b * TT + t0) * NP;

    float u8[8];
    {
        float4 a = *(const float4*)(U + (size_t)b * NP + n0);
        float4 c = *(const float4*)(U + (size_t)b * NP + n0 + 4);
        u8[0] = a.x; u8[1] = a.y; u8[2] = a.z; u8[3] = a.w;
        u8[4] = c.x; u8[5] = c.y; u8[6] = c.z; u8[7] = c.w;
    }

    float cs[8] = {0.f, 0.f, 0.f, 0.f, 0.f, 0.f, 0.f, 0.f};
    __shared__ float red[8][256];
    __shared__ float yy[8];

    #pragma unroll
    for (int g = 0; g < 4; ++g) {
        uint4 ev[8];
        #pragma unroll
        for (int r = 0; r < 8; ++r)
            ev[r] = *(const uint4*)(Eb + (size_t)(g * 8 + r) * NP + n0);

        #pragma unroll
        for (int r = 0; r < 8; ++r) {
            float d = 0.f;
            d = fmaf(f16u2f((unsigned short)(ev[r].x & 0xFFFFu)), u8[0], d);
            d = fmaf(f16u2f((unsigned short)(ev[r].x >> 16)),     u8[1], d);
            d = fmaf(f16u2f((unsigned short)(ev[r].y & 0xFFFFu)), u8[2], d);
            d = fmaf(f16u2f((unsigned short)(ev[r].y >> 16)),     u8[3], d);
            d = fmaf(f16u2f((unsigned short)(ev[r].z & 0xFFFFu)), u8[4], d);
            d = fmaf(f16u2f((unsigned short)(ev[r].z >> 16)),     u8[5], d);
            d = fmaf(f16u2f((unsigned short)(ev[r].w & 0xFFFFu)), u8[6], d);
            d = fmaf(f16u2f((unsigned short)(ev[r].w >> 16)),     u8[7], d);
            red[r][tid] = d;
        }
        __syncthreads();
        {
            int w = tid >> 6, lane = tid & 63;
            #pragma unroll
            for (int rr = 0; rr < 2; ++rr) {
                int r = w * 2 + rr;
                float s = red[r][lane] + red[r][lane + 64] +
                          red[r][lane + 128] + red[r][lane + 192];
                #pragma unroll
                for (int off = 32; off; off >>= 1)
                    s += __shfl_down(s, off, 64);
                if (lane == 0) yy[r] = E30 / s;
            }
        }
        __syncthreads();
        #pragma unroll
        for (int r = 0; r < 8; ++r) {
            float yv = yy[r];
            cs[0] = fmaf(f16u2f((unsigned short)(ev[r].x & 0xFFFFu)), yv, cs[0]);
            cs[1] = fmaf(f16u2f((unsigned short)(ev[r].x >> 16)),     yv, cs[1]);
            cs[2] = fmaf(f16u2f((unsigned short)(ev[r].y & 0xFFFFu)), yv, cs[2]);
            cs[3] = fmaf(f16u2f((unsigned short)(ev[r].y >> 16)),     yv, cs[3]);
            cs[4] = fmaf(f16u2f((unsigned short)(ev[r].z & 0xFFFFu)), yv, cs[4]);
            cs[5] = fmaf(f16u2f((unsigned short)(ev[r].z >> 16)),     yv, cs[5]);
            cs[6] = fmaf(f16u2f((unsigned short)(ev[r].w & 0xFFFFu)), yv, cs[6]);
            cs[7] = fmaf(f16u2f((unsigned short)(ev[r].w >> 16)),     yv, cs[7]);
        }
        __syncthreads();
    }

    size_t o = ((size_t)b * 64 + blockIdx.x) * NP + n0;
    *(float4*)(ps + o)     = make_float4(cs[0], cs[1], cs[2], cs[3]);
    *(float4*)(ps + o + 4) = make_float4(cs[4], cs[5], cs[6], cs[7]);
}

// ---------------------------------------------------------------------------
// u combine: U[b,n] = K0U / sum_chunks ps. NCH = 16 (from cost) or 64.
// ---------------------------------------------------------------------------
template<int NCH>
__global__ __launch_bounds__(256) void u_combine(
    const float* __restrict__ ps, float* __restrict__ U)
{
    int gid = blockIdx.x * 256 + threadIdx.x;     // over BB*NP
    int b = gid >> 11;
    int n = gid & (NP - 1);
    float S = 0.f;
    #pragma unroll 8
    for (int c = 0; c < NCH; ++c)
        S += ps[((size_t)b * NCH + c) * NP + n];
    U[gid] = K0U / S;
}

// ---------------------------------------------------------------------------
// Final v pass: S_t = sum_n E*U;  P[t,n] = E*U/S as f16. One block per row.
// ---------------------------------------------------------------------------
__global__ __launch_bounds__(256) void v_final(
    const _Float16* __restrict__ E, const float* __restrict__ U,
    _Float16* __restrict__ P)
{
    const int b = blockIdx.y;
    const int t = blockIdx.x;
    const uint4* Eb = (const uint4*)(E + ((size_t)b * TT + t) * NP);
    const float* Ub = U + (size_t)b * NP;
    const int tid = threadIdx.x;

    uint4 w = Eb[tid];
    const int n0 = tid * 8;
    float4 u0 = *(const float4*)(Ub + n0);
    float4 u1 = *(const float4*)(Ub + n0 + 4);
    float ev[8];
    ev[0] = f16u2f((unsigned short)(w.x & 0xFFFFu));
    ev[1] = f16u2f((unsigned short)(w.x >> 16));
    ev[2] = f16u2f((unsigned short)(w.y & 0xFFFFu));
    ev[3] = f16u2f((unsigned short)(w.y >> 16));
    ev[4] = f16u2f((unsigned short)(w.z & 0xFFFFu));
    ev[5] = f16u2f((unsigned short)(w.z >> 16));
    ev[6] = f16u2f((unsigned short)(w.w & 0xFFFFu));
    ev[7] = f16u2f((unsigned short)(w.w >> 16));
    float uv[8] = {u0.x, u0.y, u0.z, u0.w, u1.x, u1.y, u1.z, u1.w};

    float s = 0.f;
    #pragma unroll
    for (int j = 0; j < 8; ++j) s = fmaf(ev[j], uv[j], s);
    #pragma unroll
    for (int off = 32; off; off >>= 1) s += __shfl_down(s, off, 64);

    __shared__ float sw[4];
    __shared__ float Sall;
    if ((tid & 63) == 0) sw[tid >> 6] = s;
    __syncthreads();
    if (tid == 0) Sall = sw[0] + sw[1] + sw[2] + sw[3];
    __syncthreads();
    float invS = 1.0f / Sall;
    _Float16 hp[8];
    #pragma unroll
    for (int j = 0; j < 8; ++j)
        hp[j] = (_Float16)(ev[j] * uv[j] * invS);
    *(f16x8*)(P + ((size_t)b * TT + t) * NP + n0) = *(f16x8*)hp;
}

// ---------------------------------------------------------------------------
// pi GEMM (NT, pure fp16, 3-buffer counted-vmcnt pipeline, 64 K-steps):
//   out[b,t,d] = sum_n P[b,t,n] * vpT[b,d,n]
// 1-D grid, XCD-chunked swizzle (one batch per XCD).
// ---------------------------------------------------------------------------
__global__ __launch_bounds__(256) void gemm_pi_f16(
    const _Float16* __restrict__ P, const _Float16* __restrict__ B,
    float* __restrict__ out)
{
    const int bid = blockIdx.x;
    const int sid = ((bid & 7) << 6) | (bid >> 3);   // 512 blocks, 64/XCD
    const int b  = sid >> 6;
    const int by = (sid >> 2) & 15;
    const int bx = sid & 3;

    const _Float16* Pb = P + (size_t)b * TT * NP;
    const _Float16* Bb = B + (size_t)b * DD * NP;
    float* Cb = out + (size_t)b * TT * DD;

    __shared__ __attribute__((aligned(16))) _Float16 sA[3][4096], sB[3][4096];
    const int tid = threadIdx.x;
    const int lane = tid & 63;
    const int row0 = by * 128;   // t
    const int col0 = bx * 128;   // d
    const int wm = ((tid >> 7) & 1) * 64;
    const int wn = ((tid >> 6) & 1) * 64;
    f32x4 acc[4][4];
    zero_acc(acc);

    auto STAGE = [&](int buf, int k0) {
        #pragma unroll
        for (int q = 0; q < 2; ++q) {
            int o = (tid + (q << 8)) << 4;
            int s = o >> 11;
            int r = (o & 2047) >> 4;
            gload16(Pb + (size_t)(row0 + r) * NP + k0 + s * 8, (char*)&sA[buf][0] + o);
            gload16(Bb + (size_t)(col0 + r) * NP + k0 + s * 8, (char*)&sB[buf][0] + o);
        }
    };

    #define PI_STEP(BUFC, BUFS, KS)                               \
        asm volatile("s_waitcnt vmcnt(4)" ::: "memory");          \
        __builtin_amdgcn_s_barrier();                             \
        __builtin_amdgcn_sched_barrier(0);                        \
        STAGE(BUFS, (KS) * 32);                                   \
        frag_step_f16(&sA[BUFC][0], &sB[BUFC][0], lane, wm, wn, acc);

    STAGE(0, 0);
    STAGE(1, 32);
    for (int s3 = 0; s3 < 60; s3 += 3) {
        PI_STEP(0, 2, s3 + 2)
        PI_STEP(1, 0, s3 + 3)
        PI_STEP(2, 1, s3 + 4)
    }
    PI_STEP(0, 2, 62)      // s = 60
    PI_STEP(1, 0, 63)      // s = 61
    // s = 62: consume buf2 (63-tile still in flight)
    asm volatile("s_waitcnt vmcnt(4)" ::: "memory");
    __builtin_amdgcn_s_barrier();
    __builtin_amdgcn_sched_barrier(0);
    frag_step_f16(&sA[2][0], &sB[2][0], lane, wm, wn, acc);
    // s = 63: drain
    asm volatile("s_waitcnt vmcnt(0)" ::: "memory");
    __builtin_amdgcn_s_barrier();
    __builtin_amdgcn_sched_barrier(0);
    frag_step_f16(&sA[0][0], &sB[0][0], lane, wm, wn, acc);
    #undef PI_STEP

    store_plain(Cb, DD, row0, col0, lane, wm, wn, acc);
}

// ---------------------------------------------------------------------------
extern "C" void kernel_launch(void* const* d_in, const int* in_sizes, int n_in,
                              void* d_out, int out_size, void* d_ws, size_t ws_size,
                              hipStream_t stream)
{
    const float* q  = (const float*)d_in[0];
    const float* k  = (const float*)d_in[1];
    const float* v  = (const float*)d_in[2];
    const float* Qw = (const float*)d_in[3];
    const float* Kw = (const float*)d_in[4];
    const float* Vw = (const float*)d_in[5];
    float* out = (float*)d_out;

    // ---- workspace: ~135 MiB ----
    char* base = (char*)d_ws;
    _Float16* E16 = (_Float16*)base;                                // 64 MiB @ 0
    char* p2 = base + (size_t)BB * TT * NP * 2;
    _Float16* P   = (_Float16*)p2; p2 += (size_t)BB * TT * NP * 2;  // 32 MiB
    _Float16* qpf = (_Float16*)p2; p2 += (size_t)TT * DD * 2;       //  2 MiB
    _Float16* kpf = (_Float16*)p2; p2 += (size_t)BB * NP * DD * 2;  // 16 MiB
    _Float16* vpt = (_Float16*)p2; p2 += (size_t)BB * DD * NP * 2;  // 16 MiB (vpT)
    float* q2 = (float*)p2; p2 += (size_t)TT * 4;
    float* k2 = (float*)p2; p2 += (size_t)BB * NP * 4;
    float* U  = (float*)p2; p2 += (size_t)BB * NP * 4;
    float* ps = (float*)p2; p2 += (size_t)BB * 64 * NP * 4;         // 4 MiB

    // weight f16 temporaries aliased INSIDE E16 (dead before E16 is written):
    _Float16* wq = (_Float16*)base;                 // 3 x 512 KiB
    _Float16* wk = wq + 262144;
    _Float16* wv = wk + 262144;

    dim3 blk(256);

    // Weights: transpose to f16, single launch
    transpose3_f16<<<dim3(8, 8, 3), blk, 0, stream>>>(Qw, Kw, Vw, wq, wk, wv);

    // Projections: q+k merged; v -> vpT direct (both dbuf-prefetched)
    gemm_projqk_f16<<<dim3(4, 144, 1), blk, 0, stream>>>(q, k, wq, wk, qpf);
    gemm_projv_f16<<<dim3(4, 128, 1), blk, 0, stream>>>(v, wv, vpt);

    // Squared norms, merged
    rownorm_f16<<<dim3((TT + BB * NP) / 4), blk, 0, stream>>>(qpf, q2, TT + BB * NP);

    // Cost matrix -> E16 + fused first-u colsum (ps16, Y0 = 1)
    gemm_cost_f16<<<dim3(2048), blk, 0, stream>>>(qpf, kpf, q2, k2, E16, ps);

    // Sinkhorn: 5 E-passes total (colsum fused in cost, 4 fused v+u, final v+P)
    u_combine<16><<<dim3(BB * NP / 256), blk, 0, stream>>>(ps, U);
    for (int it = 0; it < 4; ++it) {
        sink_fused<<<dim3(TT / 32, BB), blk, 0, stream>>>(E16, U, ps);
        u_combine<64><<<dim3(BB * NP / 256), blk, 0, stream>>>(ps, U);
    }
    v_final<<<dim3(TT, BB), blk, 0, stream>>>(E16, U, P);

    // out = P @ vp (pure fp16 MFMA, counted-vmcnt pipeline)
    gemm_pi_f16<<<dim3(512), blk, 0, stream>>>(P, vpt, out);
}